// Round 8
// baseline (305.682 us; speedup 1.0000x reference)
//
#include <hip/hip_runtime.h>
#include <stdint.h>

typedef unsigned short u16;
typedef __attribute__((ext_vector_type(8))) short bf16x8;
typedef __attribute__((ext_vector_type(4))) float f32x4;

#define S_LEN 4096
#define HID_DIM 2304
#define QKV_N 4096
#define AO_N 2048
#define HD 256
#define WIN 1024
#define QSCALE 0.0625f

static __device__ __forceinline__ u16 f2bf(float f) {
  union { float f; uint32_t u; } v; v.f = f;
  return (u16)((v.u + 0x7FFFu + ((v.u >> 16) & 1u)) >> 16);
}
static __device__ __forceinline__ float bf2f(u16 h) {
  union { uint32_t u; float f; } v; v.u = ((uint32_t)h) << 16;
  return v.f;
}

static __device__ __forceinline__ void gld16(const void* src, void* dst) {
  __builtin_amdgcn_global_load_lds((const __attribute__((address_space(1))) void*)src,
                                   (__attribute__((address_space(3))) void*)dst, 16, 0, 0);
}

#define BAR() __builtin_amdgcn_s_barrier()
#define LG0() asm volatile("s_waitcnt lgkmcnt(0)" ::: "memory")
#define VM4() asm volatile("s_waitcnt vmcnt(4)" ::: "memory")
#define VM2() asm volatile("s_waitcnt vmcnt(2)" ::: "memory")
#define VM0() asm volatile("s_waitcnt vmcnt(0)" ::: "memory")
#define PRIO1() __builtin_amdgcn_s_setprio(1)
#define PRIO0() __builtin_amdgcn_s_setprio(0)

// ---------------- fp32 -> bf16 elementwise ----------------
__global__ __launch_bounds__(256) void k_cvt_bf16(const float* __restrict__ in,
                                                  u16* __restrict__ out, int n) {
  int i = (blockIdx.x * 256 + threadIdx.x) * 4;
  if (i >= n) return;
  float4 v = *(const float4*)(in + i);
  uint64_t p = (uint64_t)f2bf(v.x) | ((uint64_t)f2bf(v.y) << 16)
             | ((uint64_t)f2bf(v.z) << 32) | ((uint64_t)f2bf(v.w) << 48);
  *(uint64_t*)(out + i) = p;
}

// in: fp32 [R][C] row-major; out bf16: out[(row_off + c)*out_stride + r] = in[r][c]
__global__ __launch_bounds__(256) void k_transpose_cvt(const float* __restrict__ in, int C,
                                                       u16* __restrict__ out, int out_stride,
                                                       int row_off) {
  __shared__ float tile[32][33];
  int c0 = blockIdx.x * 32, r0 = blockIdx.y * 32;
  int tx = threadIdx.x & 31, ty = threadIdx.x >> 5;
#pragma unroll
  for (int i = 0; i < 4; i++)
    tile[ty + i * 8][tx] = in[(size_t)(r0 + ty + i * 8) * C + c0 + tx];
  __syncthreads();
#pragma unroll
  for (int i = 0; i < 4; i++)
    out[(size_t)(row_off + c0 + ty + i * 8) * out_stride + r0 + tx] = f2bf(tile[tx][ty + i * 8]);
}

// ---------------- merged wq/wk/wv transpose-convert into stacked wT [4096][2304] ---------
__global__ __launch_bounds__(256) void k_transpose_w(const float* __restrict__ wq,
                                                     const float* __restrict__ wk,
                                                     const float* __restrict__ wv,
                                                     u16* __restrict__ out) {
  int ct = blockIdx.x;       // 0..127 -> out rows ct*32..+31
  int r0 = blockIdx.y * 32;  // over 2304
  const float* src;
  int C, c0;
  if (ct < 64) {
    src = wq; C = 2048; c0 = ct * 32;
  } else if (ct < 96) {
    src = wk; C = 1024; c0 = (ct - 64) * 32;
  } else {
    src = wv; C = 1024; c0 = (ct - 96) * 32;
  }
  __shared__ float tile[32][33];
  int tx = threadIdx.x & 31, ty = threadIdx.x >> 5;
#pragma unroll
  for (int i = 0; i < 4; i++)
    tile[ty + i * 8][tx] = src[(size_t)(r0 + ty + i * 8) * C + c0 + tx];
  __syncthreads();
#pragma unroll
  for (int i = 0; i < 4; i++)
    out[(size_t)(ct * 32 + ty + i * 8) * HID_DIM + r0 + tx] = f2bf(tile[tx][ty + i * 8]);
}

// ---------------- bf16 transpose of V block of qkv -> vt[kv*256 + d][s] ----------------
__global__ __launch_bounds__(256) void k_vtrans(const u16* __restrict__ qkv,
                                                u16* __restrict__ vtout) {
  __shared__ u16 tile[32][33];
  int c0 = blockIdx.x * 32, s0 = blockIdx.y * 32;
  int tx = threadIdx.x & 31, ty = threadIdx.x >> 5;
#pragma unroll
  for (int i = 0; i < 4; i++)
    tile[ty + i * 8][tx] = qkv[(size_t)(s0 + ty + i * 8) * QKV_N + 3072 + c0 + tx];
  __syncthreads();
#pragma unroll
  for (int i = 0; i < 4; i++)
    vtout[(size_t)(c0 + ty + i * 8) * S_LEN + s0 + tx] = tile[tx][ty + i * 8];
}

// ---------------- bf16 GEMM: 256x256, BK=64, 4-phase pipelined (R7-proven loop) ----------
// MODE 0: C fp32 plain.  MODE 1: qkv output with fused epilogue — bn<12 (q/k heads):
// RMSNorm + RoPE + scale applied per 32-row slab via LDS before the bf16 store; bn>=12
// (v heads): plain bf16. Epilogue only; main loop identical to R7 (900 TF, 0 conflicts).
template <int MODE>
__global__ __launch_bounds__(512, 2) void k_gemm8p(const u16* __restrict__ A,
                                                   const u16* __restrict__ Bt,
                                                   void* __restrict__ Cout,
                                                   int M, int N, int K,
                                                   const int* __restrict__ pos_ids,
                                                   const float* __restrict__ qnw,
                                                   const float* __restrict__ knw) {
  __shared__ u16 sA[2][256 * 64];
  __shared__ u16 sB[2][256 * 64];
  const int t = threadIdx.x, lane = t & 63, wave = t >> 6;
  const int wr = wave >> 2, wc = wave & 3;
  const int l15 = lane & 15, l4 = lane >> 4;
  const int nbn = N >> 8;
  const int cpx = gridDim.x >> 3;
  const int wg = ((int)blockIdx.x & 7) * cpx + ((int)blockIdx.x >> 3);  // bijective XCD swz
  const int bm = wg / nbn, bn = wg % nbn;
  const int NT = K >> 6;
  const int srow = lane >> 3;
  const int sslot = ((lane & 7) ^ srow) * 8;
  const u16* Abase = A + (size_t)(bm * 256) * K;
  const u16* Bbase = Bt + (size_t)(bn * 256) * K;
  f32x4 acc[8][4] = {};
  bf16x8 aF[4][2], b01[2][2], b23[2][2];

#define STG_A(BUF, HALF, KT) do {                                                 \
    _Pragma("unroll")                                                             \
    for (int c_ = 0; c_ < 2; c_++) {                                              \
      int rb_ = (HALF) * 128 + (wave * 2 + c_) * 8;                               \
      gld16(Abase + (size_t)(rb_ + srow) * K + ((KT) << 6) + sslot,               \
            &sA[BUF][rb_ * 64]);                                                  \
    }                                                                             \
  } while (0)
#define STG_B(BUF, HALF, KT) do {                                                 \
    _Pragma("unroll")                                                             \
    for (int c_ = 0; c_ < 2; c_++) {                                              \
      int rb_ = (HALF) * 128 + (wave * 2 + c_) * 8;                               \
      gld16(Bbase + (size_t)(rb_ + srow) * K + ((KT) << 6) + sslot,               \
            &sB[BUF][rb_ * 64]);                                                  \
    }                                                                             \
  } while (0)
#define LDA(BUF, M_, KK)                                                          \
  (*(const bf16x8*)&sA[BUF][((M_) * 32 + wr * 16 + l15) * 64 +                    \
                            ((((KK) << 2) + l4) ^ (l15 & 7)) * 8])
#define LDB(BUF, N_, KK)                                                          \
  (*(const bf16x8*)&sB[BUF][((N_) * 64 + wc * 16 + l15) * 64 +                    \
                            ((((KK) << 2) + l4) ^ (l15 & 7)) * 8])

#define P1_LOADS(b_) do {                                                         \
    _Pragma("unroll") for (int m_ = 0; m_ < 4; m_++)                              \
      _Pragma("unroll") for (int k_ = 0; k_ < 2; k_++)                            \
        aF[m_][k_] = LDA(b_, m_, k_);                                             \
    _Pragma("unroll") for (int n_ = 0; n_ < 2; n_++)                              \
      _Pragma("unroll") for (int k_ = 0; k_ < 2; k_++)                            \
        b01[n_][k_] = LDB(b_, n_, k_);                                            \
  } while (0)
#define P2_LOADS(b_) do {                                                         \
    _Pragma("unroll") for (int n_ = 0; n_ < 2; n_++)                              \
      _Pragma("unroll") for (int k_ = 0; k_ < 2; k_++)                            \
        b23[n_][k_] = LDB(b_, n_ + 2, k_);                                        \
  } while (0)
#define P3_LOADS(b_) do {                                                         \
    _Pragma("unroll") for (int m_ = 0; m_ < 4; m_++)                              \
      _Pragma("unroll") for (int k_ = 0; k_ < 2; k_++)                            \
        aF[m_][k_] = LDA(b_, m_ + 4, k_);                                         \
  } while (0)
#define MFMA16(MOFF, NOFF, BREG) do {                                             \
    _Pragma("unroll") for (int m_ = 0; m_ < 4; m_++)                              \
      _Pragma("unroll") for (int n_ = 0; n_ < 2; n_++)                            \
        _Pragma("unroll") for (int k_ = 0; k_ < 2; k_++)                          \
          acc[m_ + MOFF][n_ + NOFF] = __builtin_amdgcn_mfma_f32_16x16x32_bf16(    \
              aF[m_][k_], BREG[n_][k_], acc[m_ + MOFF][n_ + NOFF], 0, 0, 0);      \
  } while (0)

  STG_A(0, 0, 0);
  STG_B(0, 0, 0);
  STG_B(0, 1, 0);
  STG_A(0, 1, 0);
  VM4();
  BAR();

  for (int tt = 0; tt < NT - 1; ++tt) {
    const int b = tt & 1, nb = b ^ 1;
    P1_LOADS(b);
    STG_A(nb, 0, tt + 1);
    BAR(); LG0(); PRIO1(); MFMA16(0, 0, b01); PRIO0();
    VM4();
    BAR();
    P2_LOADS(b);
    STG_B(nb, 0, tt + 1);
    BAR(); LG0(); PRIO1(); MFMA16(0, 2, b23); PRIO0();
    VM4();
    BAR();
    P3_LOADS(b);
    STG_B(nb, 1, tt + 1);
    BAR(); LG0(); PRIO1(); MFMA16(4, 0, b01); PRIO0();
    BAR();
    STG_A(nb, 1, tt + 1);
    BAR(); PRIO1(); MFMA16(4, 2, b23); PRIO0();
    VM4();
    BAR();
  }
  {
    const int b = (NT - 1) & 1;
    P1_LOADS(b);
    BAR(); LG0(); PRIO1(); MFMA16(0, 0, b01); PRIO0();
    VM2();
    BAR();
    P2_LOADS(b);
    BAR(); LG0(); PRIO1(); MFMA16(0, 2, b23); PRIO0();
    VM0();
    BAR();
    P3_LOADS(b);
    BAR(); LG0(); PRIO1(); MFMA16(4, 0, b01); PRIO0();
    BAR();
    PRIO1(); MFMA16(4, 2, b23); PRIO0();
  }

  if (MODE == 1 && bn < 12) {
    // fused RMSNorm + RoPE + scale: this block's 256 cols = one head's full D.
    const float* wvec = (bn < 8) ? qnw : knw;
    const float scl = (bn < 8) ? QSCALE : 1.0f;
    float* slab = (float*)&sA[0][0];  // [32][264] fp32 = 33.8KB (sA is dead)
    __syncthreads();                  // all waves done reading sA/sB
#pragma unroll
    for (int m = 0; m < 8; m++) {
#pragma unroll
      for (int n = 0; n < 4; n++)
#pragma unroll
        for (int r = 0; r < 4; r++)
          slab[(wr * 16 + l4 * 4 + r) * 264 + n * 64 + wc * 16 + l15] = acc[m][n][r];
      __syncthreads();
      // wave handles rows wave*4 .. wave*4+3 of the 32-row slab
#pragma unroll
      for (int rr = 0; rr < 4; rr++) {
        int lrow = wave * 4 + rr;
        int grow = bm * 256 + m * 32 + lrow;
        f32x4 v = *(const f32x4*)&slab[lrow * 264 + lane * 4];
        float ss = v[0] * v[0] + v[1] * v[1] + v[2] * v[2] + v[3] * v[3];
#pragma unroll
        for (int off = 1; off < 64; off <<= 1) ss += __shfl_xor(ss, off);
        float rms = rsqrtf(ss * (1.0f / 256.0f) + 1e-6f);
        f32x4 wv4 = *(const f32x4*)&wvec[lane * 4];
        float y[4], yo[4];
#pragma unroll
        for (int j = 0; j < 4; j++) y[j] = v[j] * rms * (1.0f + wv4[j]);
#pragma unroll
        for (int j = 0; j < 4; j++) yo[j] = __shfl_xor(y[j], 32);
        int pos = pos_ids[grow];
        uint64_t pk = 0;
#pragma unroll
        for (int j = 0; j < 4; j++) {
          int jj = (lane & 31) * 4 + j;
          float ang = (float)pos * exp2f((float)jj * (-13.287712379549449f / 128.0f));
          float sn, cs;
          sincosf(ang, &sn, &cs);
          float o = (lane < 32) ? (y[j] * cs - yo[j] * sn) : (yo[j] * sn + y[j] * cs);
          pk |= (uint64_t)f2bf(o * scl) << (16 * j);
        }
        *(uint64_t*)&((u16*)Cout)[(size_t)grow * N + bn * 256 + lane * 4] = pk;
      }
      __syncthreads();
    }
  } else {
#pragma unroll
    for (int m = 0; m < 8; m++)
#pragma unroll
      for (int n = 0; n < 4; n++)
#pragma unroll
        for (int r = 0; r < 4; r++) {
          size_t row = bm * 256 + m * 32 + wr * 16 + l4 * 4 + r;
          size_t col = bn * 256 + n * 64 + wc * 16 + l15;
          if (MODE == 1)
            ((u16*)Cout)[row * N + col] = f2bf(acc[m][n][r]);
          else
            ((float*)Cout)[row * N + col] = acc[m][n][r];
        }
  }
#undef STG_A
#undef STG_B
#undef LDA
#undef LDB
#undef P1_LOADS
#undef P2_LOADS
#undef P3_LOADS
#undef MFMA16
}

// ---------------- flash attention (R5-proven): sliding window, GQA-shared K/V ----------
__global__ __launch_bounds__(256, 2) void k_attn(const u16* __restrict__ qkv,
                                                 const u16* __restrict__ vt,
                                                 const int* __restrict__ pos_ids,
                                                 u16* __restrict__ aout) {
  __shared__ u16 lK[64 * 256];   // [key][d], rows 512B, swizzled
  __shared__ u16 lV[256 * 64];   // [d][key], rows 128B, swizzled
  __shared__ u16 lP[4][16 * 64]; // per-wave P, rows 128B, swizzled
  const int bid = blockIdx.x;
  const int wg = (bid & 7) * 64 + (bid >> 3);
  const int kvh = wg >> 7;
  const int q0 = (wg & 127) * 32;
  const int t = threadIdx.x, lane = t & 63, wave = t >> 6;
  const int l15 = lane & 15, l4 = lane >> 4;
  const int head = kvh * 2 + (wave >> 1);
  const int qw = q0 + (wave & 1) * 16;

  bf16x8 qfr[8];
  {
    const u16* qptr = qkv + (size_t)(qw + l15) * QKV_N + head * HD + l4 * 8;
#pragma unroll
    for (int kc = 0; kc < 8; kc++) qfr[kc] = *(const bf16x8*)(qptr + kc * 32);
  }
  f32x4 acc[16] = {};
  float mrow[4], lrow[4];
#pragma unroll
  for (int r = 0; r < 4; r++) { mrow[r] = -1e30f; lrow[r] = 0.0f; }
  int qi[4];
#pragma unroll
  for (int r = 0; r < 4; r++) qi[r] = pos_ids[qw + l4 * 4 + r];

  const int krw = lane >> 5, kcl = lane & 31;
  const int vrw = lane >> 3, vcl = lane & 7;
  const u16* kgb = qkv + 2048 + kvh * HD;
  const u16* vgb = vt + (size_t)kvh * HD * S_LEN;

  int start = q0 - (WIN - 1);
  if (start < 0) start = 0;
  start &= ~63;

#define STAGE_KV(T0) do {                                                             \
    _Pragma("unroll")                                                                 \
    for (int i_ = 0; i_ < 8; i_++) {                                                  \
      int ch_ = wave * 8 + i_;                                                        \
      int kr_ = ch_ * 2 + krw;                                                        \
      gld16(kgb + (size_t)((T0) + kr_) * QKV_N + ((kcl ^ (kr_ & 7)) * 8),             \
            &lK[ch_ * 512]);                                                          \
      int vr_ = ch_ * 8 + vrw;                                                        \
      gld16(vgb + (size_t)vr_ * S_LEN + (T0) + ((vcl ^ (vr_ & 7)) * 8),               \
            &lV[ch_ * 512]);                                                          \
    }                                                                                 \
  } while (0)

  for (int t0 = start; t0 <= q0 + 31; t0 += 64) {
    STAGE_KV(t0);
    int kp[4];
#pragma unroll
    for (int kb = 0; kb < 4; kb++) kp[kb] = pos_ids[t0 + kb * 16 + l15];
    __syncthreads();
    f32x4 sv[4] = {};
    PRIO1();
#pragma unroll
    for (int kb = 0; kb < 4; kb++) {
      const char* krow = (const char*)&lK[(kb * 16 + l15) * 256];
      const int sw = ((kb * 16 + l15) & 7) << 4;
#pragma unroll
      for (int kc = 0; kc < 8; kc++) {
        bf16x8 kf = *(const bf16x8*)(krow + ((kc * 64 + l4 * 16) ^ sw));
        sv[kb] = __builtin_amdgcn_mfma_f32_16x16x32_bf16(qfr[kc], kf, sv[kb], 0, 0, 0);
      }
    }
    PRIO0();
    float sloc[4][4], mx[4];
    float need = 0.0f;
#pragma unroll
    for (int r = 0; r < 4; r++) {
      int pi = qi[r];
#pragma unroll
      for (int kb = 0; kb < 4; kb++)
        sloc[r][kb] = ((kp[kb] <= pi) && (pi - kp[kb] < WIN)) ? sv[kb][r] : -__builtin_inff();
      float m_ = fmaxf(fmaxf(sloc[r][0], sloc[r][1]), fmaxf(sloc[r][2], sloc[r][3]));
#pragma unroll
      for (int off = 1; off < 16; off <<= 1) m_ = fmaxf(m_, __shfl_xor(m_, off));
      mx[r] = m_;
      need = fmaxf(need, m_ - mrow[r]);
    }
    bool resc = __any(need > 8.0f);
    if (resc) {
#pragma unroll
      for (int r = 0; r < 4; r++) {
        float nm = fmaxf(mrow[r], mx[r]);
        float al = __expf(mrow[r] - nm);
        mrow[r] = nm;
        lrow[r] *= al;
#pragma unroll
        for (int nd = 0; nd < 16; nd++) acc[nd][r] *= al;
      }
    }
#pragma unroll
    for (int r = 0; r < 4; r++) {
      float nm = mrow[r];
      float e0 = __expf(sloc[r][0] - nm), e1 = __expf(sloc[r][1] - nm);
      float e2 = __expf(sloc[r][2] - nm), e3 = __expf(sloc[r][3] - nm);
      float sum = (e0 + e1) + (e2 + e3);
#pragma unroll
      for (int off = 1; off < 16; off <<= 1) sum += __shfl_xor(sum, off);
      lrow[r] += sum;
      int q = l4 * 4 + r;
      char* lpw = (char*)&lP[wave][0] + q * 128;
      int swp = (q & 7) << 4;
      *(u16*)(lpw + ((l15 * 2) ^ swp)) = f2bf(e0);
      *(u16*)(lpw + ((32 + l15 * 2) ^ swp)) = f2bf(e1);
      *(u16*)(lpw + ((64 + l15 * 2) ^ swp)) = f2bf(e2);
      *(u16*)(lpw + ((96 + l15 * 2) ^ swp)) = f2bf(e3);
    }
#pragma unroll
    for (int kc2 = 0; kc2 < 2; kc2++) {
      int q = l15;
      bf16x8 pa = *(const bf16x8*)((const char*)&lP[wave][0] + q * 128 +
                                   ((kc2 * 64 + l4 * 16) ^ ((q & 7) << 4)));
      PRIO1();
#pragma unroll
      for (int nd = 0; nd < 16; nd++) {
        int d = nd * 16 + l15;
        bf16x8 vf = *(const bf16x8*)((const char*)&lV[d * 64] +
                                     ((kc2 * 64 + l4 * 16) ^ ((d & 7) << 4)));
        acc[nd] = __builtin_amdgcn_mfma_f32_16x16x32_bf16(pa, vf, acc[nd], 0, 0, 0);
      }
      PRIO0();
    }
    __syncthreads();
  }
  float rinv[4];
#pragma unroll
  for (int r = 0; r < 4; r++) rinv[r] = 1.0f / lrow[r];
#pragma unroll
  for (int nd = 0; nd < 16; nd++)
#pragma unroll
    for (int r = 0; r < 4; r++) {
      size_t row = qw + l4 * 4 + r;
      aout[row * AO_N + head * HD + nd * 16 + l15] = f2bf(acc[nd][r] * rinv[r]);
    }
#undef STAGE_KV
}

extern "C" void kernel_launch(void* const* d_in, const int* in_sizes, int n_in,
                              void* d_out, int out_size, void* d_ws, size_t ws_size,
                              hipStream_t stream) {
  const float* x = (const float*)d_in[0];
  const int* pos = (const int*)d_in[1];
  const float* wq = (const float*)d_in[2];
  const float* wk = (const float*)d_in[3];
  const float* wv = (const float*)d_in[4];
  const float* wo = (const float*)d_in[5];
  const float* qnw = (const float*)d_in[6];
  const float* knw = (const float*)d_in[7];

  // scratch layout:
  //   d_out: qkv bf16 [4096][4096] (overwritten by final fp32 GEMM)
  //   ws+0        : x bf16 [4096][2304]; later aout bf16 [4096][2048]
  //   ws+18874368 : W^T bf16 (qkv-phase: [4096][2304]; out-phase: wo^T [2304][2048])
  //   ws+28311552 : vt bf16 [4][256][4096]
  u16* qkv = (u16*)d_out;
  u16* xbf = (u16*)d_ws;
  u16* wT = (u16*)((char*)d_ws + 18874368);
  u16* vtb = (u16*)((char*)d_ws + 28311552);
  u16* aout = xbf;

  k_cvt_bf16<<<9216, 256, 0, stream>>>(x, xbf, S_LEN * HID_DIM);
  k_transpose_w<<<dim3(128, 72), 256, 0, stream>>>(wq, wk, wv, wT);
  k_gemm8p<1><<<dim3(256), 512, 0, stream>>>(xbf, wT, qkv, S_LEN, QKV_N, HID_DIM,
                                             pos, qnw, knw);
  k_vtrans<<<dim3(32, 128), 256, 0, stream>>>(qkv, vtb);
  k_transpose_cvt<<<dim3(72, 64), 256, 0, stream>>>(wo, HID_DIM, wT, 2048, 0);
  k_attn<<<dim3(512), 256, 0, stream>>>(qkv, vtb, pos, aout);
  k_gemm8p<0><<<dim3(144), 512, 0, stream>>>(aout, wT, d_out, S_LEN, HID_DIM, 2048,
                                             nullptr, nullptr, nullptr);
}

// Round 9
// 266.142 us; speedup vs baseline: 1.1486x; 1.1486x over previous
//
#include <hip/hip_runtime.h>
#include <stdint.h>

typedef unsigned short u16;
typedef __attribute__((ext_vector_type(8))) short bf16x8;
typedef __attribute__((ext_vector_type(4))) float f32x4;

#define S_LEN 4096
#define HID_DIM 2304
#define QKV_N 4096
#define AO_N 2048
#define HD 256
#define WIN 1024
#define QSCALE 0.0625f

static __device__ __forceinline__ u16 f2bf(float f) {
  union { float f; uint32_t u; } v; v.f = f;
  return (u16)((v.u + 0x7FFFu + ((v.u >> 16) & 1u)) >> 16);
}
static __device__ __forceinline__ float bf2f(u16 h) {
  union { uint32_t u; float f; } v; v.u = ((uint32_t)h) << 16;
  return v.f;
}

static __device__ __forceinline__ void gld16(const void* src, void* dst) {
  __builtin_amdgcn_global_load_lds((const __attribute__((address_space(1))) void*)src,
                                   (__attribute__((address_space(3))) void*)dst, 16, 0, 0);
}

#define BAR() __builtin_amdgcn_s_barrier()
#define LG0() asm volatile("s_waitcnt lgkmcnt(0)" ::: "memory")
#define VM4() asm volatile("s_waitcnt vmcnt(4)" ::: "memory")
#define VM2() asm volatile("s_waitcnt vmcnt(2)" ::: "memory")
#define VM0() asm volatile("s_waitcnt vmcnt(0)" ::: "memory")
#define PRIO1() __builtin_amdgcn_s_setprio(1)
#define PRIO0() __builtin_amdgcn_s_setprio(0)

// ---------------- fp32 -> bf16 elementwise ----------------
__global__ __launch_bounds__(256) void k_cvt_bf16(const float* __restrict__ in,
                                                  u16* __restrict__ out, int n) {
  int i = (blockIdx.x * 256 + threadIdx.x) * 4;
  if (i >= n) return;
  float4 v = *(const float4*)(in + i);
  uint64_t p = (uint64_t)f2bf(v.x) | ((uint64_t)f2bf(v.y) << 16)
             | ((uint64_t)f2bf(v.z) << 32) | ((uint64_t)f2bf(v.w) << 48);
  *(uint64_t*)(out + i) = p;
}

// in: fp32 [R][C] row-major; out bf16: out[(row_off + c)*out_stride + r] = in[r][c]
__global__ __launch_bounds__(256) void k_transpose_cvt(const float* __restrict__ in, int C,
                                                       u16* __restrict__ out, int out_stride,
                                                       int row_off) {
  __shared__ float tile[32][33];
  int c0 = blockIdx.x * 32, r0 = blockIdx.y * 32;
  int tx = threadIdx.x & 31, ty = threadIdx.x >> 5;
#pragma unroll
  for (int i = 0; i < 4; i++)
    tile[ty + i * 8][tx] = in[(size_t)(r0 + ty + i * 8) * C + c0 + tx];
  __syncthreads();
#pragma unroll
  for (int i = 0; i < 4; i++)
    out[(size_t)(row_off + c0 + ty + i * 8) * out_stride + r0 + tx] = f2bf(tile[tx][ty + i * 8]);
}

// ---------------- merged wq/wk/wv transpose-convert into stacked wT [4096][2304] ---------
__global__ __launch_bounds__(256) void k_transpose_w(const float* __restrict__ wq,
                                                     const float* __restrict__ wk,
                                                     const float* __restrict__ wv,
                                                     u16* __restrict__ out) {
  int ct = blockIdx.x;       // 0..127 -> out rows ct*32..+31
  int r0 = blockIdx.y * 32;  // over 2304
  const float* src;
  int C, c0;
  if (ct < 64) {
    src = wq; C = 2048; c0 = ct * 32;
  } else if (ct < 96) {
    src = wk; C = 1024; c0 = (ct - 64) * 32;
  } else {
    src = wv; C = 1024; c0 = (ct - 96) * 32;
  }
  __shared__ float tile[32][33];
  int tx = threadIdx.x & 31, ty = threadIdx.x >> 5;
#pragma unroll
  for (int i = 0; i < 4; i++)
    tile[ty + i * 8][tx] = src[(size_t)(r0 + ty + i * 8) * C + c0 + tx];
  __syncthreads();
#pragma unroll
  for (int i = 0; i < 4; i++)
    out[(size_t)(ct * 32 + ty + i * 8) * HID_DIM + r0 + tx] = f2bf(tile[tx][ty + i * 8]);
}

// ---------------- bf16 transpose of V block of qkv -> vt[kv*256 + d][s] ----------------
__global__ __launch_bounds__(256) void k_vtrans(const u16* __restrict__ qkv,
                                                u16* __restrict__ vtout) {
  __shared__ u16 tile[32][33];
  int c0 = blockIdx.x * 32, s0 = blockIdx.y * 32;
  int tx = threadIdx.x & 31, ty = threadIdx.x >> 5;
#pragma unroll
  for (int i = 0; i < 4; i++)
    tile[ty + i * 8][tx] = qkv[(size_t)(s0 + ty + i * 8) * QKV_N + 3072 + c0 + tx];
  __syncthreads();
#pragma unroll
  for (int i = 0; i < 4; i++)
    vtout[(size_t)(c0 + ty + i * 8) * S_LEN + s0 + tx] = tile[tx][ty + i * 8];
}

// ---------------- bf16 GEMM: 256x256, BK=64, 4-phase pipelined (R7-proven) --------------
// OUT_BF16=1: bf16 store; OUT_BF16=0: fp32 store. Plain epilogue (R8's fused norm/rope
// regressed -69us: 128 sincosf/thread in a 192-block tail; trig belongs in normrope).
template <int OUT_BF16>
__global__ __launch_bounds__(512, 2) void k_gemm8p(const u16* __restrict__ A,
                                                   const u16* __restrict__ Bt,
                                                   void* __restrict__ Cout,
                                                   int M, int N, int K) {
  __shared__ u16 sA[2][256 * 64];
  __shared__ u16 sB[2][256 * 64];
  const int t = threadIdx.x, lane = t & 63, wave = t >> 6;
  const int wr = wave >> 2, wc = wave & 3;
  const int l15 = lane & 15, l4 = lane >> 4;
  const int nbn = N >> 8;
  const int cpx = gridDim.x >> 3;
  const int wg = ((int)blockIdx.x & 7) * cpx + ((int)blockIdx.x >> 3);  // bijective XCD swz
  const int bm = wg / nbn, bn = wg % nbn;
  const int NT = K >> 6;
  const int srow = lane >> 3;
  const int sslot = ((lane & 7) ^ srow) * 8;
  const u16* Abase = A + (size_t)(bm * 256) * K;
  const u16* Bbase = Bt + (size_t)(bn * 256) * K;
  f32x4 acc[8][4] = {};
  bf16x8 aF[4][2], b01[2][2], b23[2][2];

#define STG_A(BUF, HALF, KT) do {                                                 \
    _Pragma("unroll")                                                             \
    for (int c_ = 0; c_ < 2; c_++) {                                              \
      int rb_ = (HALF) * 128 + (wave * 2 + c_) * 8;                               \
      gld16(Abase + (size_t)(rb_ + srow) * K + ((KT) << 6) + sslot,               \
            &sA[BUF][rb_ * 64]);                                                  \
    }                                                                             \
  } while (0)
#define STG_B(BUF, HALF, KT) do {                                                 \
    _Pragma("unroll")                                                             \
    for (int c_ = 0; c_ < 2; c_++) {                                              \
      int rb_ = (HALF) * 128 + (wave * 2 + c_) * 8;                               \
      gld16(Bbase + (size_t)(rb_ + srow) * K + ((KT) << 6) + sslot,               \
            &sB[BUF][rb_ * 64]);                                                  \
    }                                                                             \
  } while (0)
#define LDA(BUF, M_, KK)                                                          \
  (*(const bf16x8*)&sA[BUF][((M_) * 32 + wr * 16 + l15) * 64 +                    \
                            ((((KK) << 2) + l4) ^ (l15 & 7)) * 8])
#define LDB(BUF, N_, KK)                                                          \
  (*(const bf16x8*)&sB[BUF][((N_) * 64 + wc * 16 + l15) * 64 +                    \
                            ((((KK) << 2) + l4) ^ (l15 & 7)) * 8])

#define P1_LOADS(b_) do {                                                         \
    _Pragma("unroll") for (int m_ = 0; m_ < 4; m_++)                              \
      _Pragma("unroll") for (int k_ = 0; k_ < 2; k_++)                            \
        aF[m_][k_] = LDA(b_, m_, k_);                                             \
    _Pragma("unroll") for (int n_ = 0; n_ < 2; n_++)                              \
      _Pragma("unroll") for (int k_ = 0; k_ < 2; k_++)                            \
        b01[n_][k_] = LDB(b_, n_, k_);                                            \
  } while (0)
#define P2_LOADS(b_) do {                                                         \
    _Pragma("unroll") for (int n_ = 0; n_ < 2; n_++)                              \
      _Pragma("unroll") for (int k_ = 0; k_ < 2; k_++)                            \
        b23[n_][k_] = LDB(b_, n_ + 2, k_);                                        \
  } while (0)
#define P3_LOADS(b_) do {                                                         \
    _Pragma("unroll") for (int m_ = 0; m_ < 4; m_++)                              \
      _Pragma("unroll") for (int k_ = 0; k_ < 2; k_++)                            \
        aF[m_][k_] = LDA(b_, m_ + 4, k_);                                         \
  } while (0)
#define MFMA16(MOFF, NOFF, BREG) do {                                             \
    _Pragma("unroll") for (int m_ = 0; m_ < 4; m_++)                              \
      _Pragma("unroll") for (int n_ = 0; n_ < 2; n_++)                            \
        _Pragma("unroll") for (int k_ = 0; k_ < 2; k_++)                          \
          acc[m_ + MOFF][n_ + NOFF] = __builtin_amdgcn_mfma_f32_16x16x32_bf16(    \
              aF[m_][k_], BREG[n_][k_], acc[m_ + MOFF][n_ + NOFF], 0, 0, 0);      \
  } while (0)

  STG_A(0, 0, 0);
  STG_B(0, 0, 0);
  STG_B(0, 1, 0);
  STG_A(0, 1, 0);
  VM4();
  BAR();

  for (int tt = 0; tt < NT - 1; ++tt) {
    const int b = tt & 1, nb = b ^ 1;
    P1_LOADS(b);
    STG_A(nb, 0, tt + 1);
    BAR(); LG0(); PRIO1(); MFMA16(0, 0, b01); PRIO0();
    VM4();
    BAR();
    P2_LOADS(b);
    STG_B(nb, 0, tt + 1);
    BAR(); LG0(); PRIO1(); MFMA16(0, 2, b23); PRIO0();
    VM4();
    BAR();
    P3_LOADS(b);
    STG_B(nb, 1, tt + 1);
    BAR(); LG0(); PRIO1(); MFMA16(4, 0, b01); PRIO0();
    BAR();
    STG_A(nb, 1, tt + 1);
    BAR(); PRIO1(); MFMA16(4, 2, b23); PRIO0();
    VM4();
    BAR();
  }
  {
    const int b = (NT - 1) & 1;
    P1_LOADS(b);
    BAR(); LG0(); PRIO1(); MFMA16(0, 0, b01); PRIO0();
    VM2();
    BAR();
    P2_LOADS(b);
    BAR(); LG0(); PRIO1(); MFMA16(0, 2, b23); PRIO0();
    VM0();
    BAR();
    P3_LOADS(b);
    BAR(); LG0(); PRIO1(); MFMA16(4, 0, b01); PRIO0();
    BAR();
    PRIO1(); MFMA16(4, 2, b23); PRIO0();
  }

#pragma unroll
  for (int m = 0; m < 8; m++)
#pragma unroll
    for (int n = 0; n < 4; n++)
#pragma unroll
      for (int r = 0; r < 4; r++) {
        size_t row = bm * 256 + m * 32 + wr * 16 + l4 * 4 + r;
        size_t col = bn * 256 + n * 64 + wc * 16 + l15;
        if (OUT_BF16)
          ((u16*)Cout)[row * N + col] = f2bf(acc[m][n][r]);
        else
          ((float*)Cout)[row * N + col] = acc[m][n][r];
      }
#undef STG_A
#undef STG_B
#undef LDA
#undef LDB
#undef P1_LOADS
#undef P2_LOADS
#undef P3_LOADS
#undef MFMA16
}

// ---------------- fused RMSNorm + RoPE + scale, in place on bf16 q/k ----------------
__global__ __launch_bounds__(128) void k_normrope(u16* __restrict__ qkv,
                                                  const int* __restrict__ pos_ids,
                                                  const float* __restrict__ qw,
                                                  const float* __restrict__ kw) {
  __shared__ float cross[2];
  int idx = blockIdx.x;
  int s = idx / 12, r = idx % 12;
  bool is_q = (r < 8);
  u16* p = qkv + (size_t)s * QKV_N + (is_q ? r * HD : 2048 + (r - 8) * HD);
  const float* w = is_q ? qw : kw;
  int j = threadIdx.x;  // 0..127
  float x1 = bf2f(p[j]), x2 = bf2f(p[j + 128]);
  float ss = x1 * x1 + x2 * x2;
#pragma unroll
  for (int off = 1; off < 64; off <<= 1) ss += __shfl_xor(ss, off);
  if ((threadIdx.x & 63) == 0) cross[threadIdx.x >> 6] = ss;
  __syncthreads();
  float rms = rsqrtf((cross[0] + cross[1]) * (1.0f / 256.0f) + 1e-6f);
  float y1 = x1 * rms * (1.0f + w[j]);
  float y2 = x2 * rms * (1.0f + w[j + 128]);
  float ang = (float)pos_ids[s] * exp2f((float)j * (-13.287712379549449f / 128.0f));
  float sn, c;
  sincosf(ang, &sn, &c);
  float sc = is_q ? QSCALE : 1.0f;
  p[j] = f2bf((y1 * c - y2 * sn) * sc);
  p[j + 128] = f2bf((y1 * sn + y2 * c) * sc);
}

// ---------------- flash attention v6: 64 q/block, GQA-shared K/V ----------------
// block = (64 q x 1 kv-head), 8 waves: wave w -> head kvh*2+(w>>2), rows q0+(w&3)*16.
// Halves K/V staging per q-row vs 32q blocks. launch_bounds(512,2): 256-VGPR cap (R6's
// (512,4) clamped to 64 VGPR -> spill disaster). LDS 80KB -> 2 blocks/CU capacity.
__global__ __launch_bounds__(512, 2) void k_attn(const u16* __restrict__ qkv,
                                                 const u16* __restrict__ vt,
                                                 const int* __restrict__ pos_ids,
                                                 u16* __restrict__ aout) {
  __shared__ u16 lK[64 * 256];   // [key][d], rows 512B, swizzled
  __shared__ u16 lV[256 * 64];   // [d][key], rows 128B, swizzled
  __shared__ u16 lP[8][16 * 64]; // per-wave P, rows 128B, swizzled
  const int bid = blockIdx.x;    // 256 blocks
  const int wg = (bid & 7) * 32 + (bid >> 3);  // bijective XCD swizzle
  const int kvh = wg >> 6;                     // 0..3
  const int q0 = (wg & 63) * 64;               // 0..4032
  const int t = threadIdx.x, lane = t & 63, wave = t >> 6;
  const int l15 = lane & 15, l4 = lane >> 4;
  const int head = kvh * 2 + (wave >> 2);
  const int qw = q0 + (wave & 3) * 16;

  bf16x8 qfr[8];
  {
    const u16* qptr = qkv + (size_t)(qw + l15) * QKV_N + head * HD + l4 * 8;
#pragma unroll
    for (int kc = 0; kc < 8; kc++) qfr[kc] = *(const bf16x8*)(qptr + kc * 32);
  }
  f32x4 acc[16] = {};
  float mrow[4], lrow[4];
#pragma unroll
  for (int r = 0; r < 4; r++) { mrow[r] = -1e30f; lrow[r] = 0.0f; }
  int qi[4];
#pragma unroll
  for (int r = 0; r < 4; r++) qi[r] = pos_ids[qw + l4 * 4 + r];

  // staging: K chunk=1KB=2 rows x 512B; V chunk=1KB=8 rows x 128B; 4 of each per wave
  const int krw = lane >> 5, kcl = lane & 31;
  const int vrw = lane >> 3, vcl = lane & 7;
  const u16* kgb = qkv + 2048 + kvh * HD;
  const u16* vgb = vt + (size_t)kvh * HD * S_LEN;

  int start = q0 - (WIN - 1);
  if (start < 0) start = 0;
  start &= ~63;

#define STAGE_KV(T0) do {                                                             \
    _Pragma("unroll")                                                                 \
    for (int i_ = 0; i_ < 4; i_++) {                                                  \
      int ch_ = wave * 4 + i_;                                                        \
      int kr_ = ch_ * 2 + krw;                                                        \
      gld16(kgb + (size_t)((T0) + kr_) * QKV_N + ((kcl ^ (kr_ & 7)) * 8),             \
            &lK[ch_ * 512]);                                                          \
      int vr_ = ch_ * 8 + vrw;                                                        \
      gld16(vgb + (size_t)vr_ * S_LEN + (T0) + ((vcl ^ (vr_ & 7)) * 8),               \
            &lV[ch_ * 512]);                                                          \
    }                                                                                 \
  } while (0)

  for (int t0 = start; t0 <= q0 + 63; t0 += 64) {
    STAGE_KV(t0);
    int kp[4];
#pragma unroll
    for (int kb = 0; kb < 4; kb++) kp[kb] = pos_ids[t0 + kb * 16 + l15];
    __syncthreads();
    f32x4 sv[4] = {};
    PRIO1();
#pragma unroll
    for (int kb = 0; kb < 4; kb++) {
      const char* krow = (const char*)&lK[(kb * 16 + l15) * 256];
      const int sw = ((kb * 16 + l15) & 7) << 4;
#pragma unroll
      for (int kc = 0; kc < 8; kc++) {
        bf16x8 kf = *(const bf16x8*)(krow + ((kc * 64 + l4 * 16) ^ sw));
        sv[kb] = __builtin_amdgcn_mfma_f32_16x16x32_bf16(qfr[kc], kf, sv[kb], 0, 0, 0);
      }
    }
    PRIO0();
    float sloc[4][4], mx[4];
    float need = 0.0f;
#pragma unroll
    for (int r = 0; r < 4; r++) {
      int pi = qi[r];
#pragma unroll
      for (int kb = 0; kb < 4; kb++)
        sloc[r][kb] = ((kp[kb] <= pi) && (pi - kp[kb] < WIN)) ? sv[kb][r] : -__builtin_inff();
      float m_ = fmaxf(fmaxf(sloc[r][0], sloc[r][1]), fmaxf(sloc[r][2], sloc[r][3]));
#pragma unroll
      for (int off = 1; off < 16; off <<= 1) m_ = fmaxf(m_, __shfl_xor(m_, off));
      mx[r] = m_;
      need = fmaxf(need, m_ - mrow[r]);
    }
    bool resc = __any(need > 8.0f);
    if (resc) {
#pragma unroll
      for (int r = 0; r < 4; r++) {
        float nm = fmaxf(mrow[r], mx[r]);
        float al = __expf(mrow[r] - nm);
        mrow[r] = nm;
        lrow[r] *= al;
#pragma unroll
        for (int nd = 0; nd < 16; nd++) acc[nd][r] *= al;
      }
    }
#pragma unroll
    for (int r = 0; r < 4; r++) {
      float nm = mrow[r];
      float e0 = __expf(sloc[r][0] - nm), e1 = __expf(sloc[r][1] - nm);
      float e2 = __expf(sloc[r][2] - nm), e3 = __expf(sloc[r][3] - nm);
      float sum = (e0 + e1) + (e2 + e3);
#pragma unroll
      for (int off = 1; off < 16; off <<= 1) sum += __shfl_xor(sum, off);
      lrow[r] += sum;
      int q = l4 * 4 + r;
      char* lpw = (char*)&lP[wave][0] + q * 128;
      int swp = (q & 7) << 4;
      *(u16*)(lpw + ((l15 * 2) ^ swp)) = f2bf(e0);
      *(u16*)(lpw + ((32 + l15 * 2) ^ swp)) = f2bf(e1);
      *(u16*)(lpw + ((64 + l15 * 2) ^ swp)) = f2bf(e2);
      *(u16*)(lpw + ((96 + l15 * 2) ^ swp)) = f2bf(e3);
    }
#pragma unroll
    for (int kc2 = 0; kc2 < 2; kc2++) {
      int q = l15;
      bf16x8 pa = *(const bf16x8*)((const char*)&lP[wave][0] + q * 128 +
                                   ((kc2 * 64 + l4 * 16) ^ ((q & 7) << 4)));
      PRIO1();
#pragma unroll
      for (int nd = 0; nd < 16; nd++) {
        int d = nd * 16 + l15;
        bf16x8 vf = *(const bf16x8*)((const char*)&lV[d * 64] +
                                     ((kc2 * 64 + l4 * 16) ^ ((d & 7) << 4)));
        acc[nd] = __builtin_amdgcn_mfma_f32_16x16x32_bf16(pa, vf, acc[nd], 0, 0, 0);
      }
      PRIO0();
    }
    __syncthreads();
  }
  float rinv[4];
#pragma unroll
  for (int r = 0; r < 4; r++) rinv[r] = 1.0f / lrow[r];
#pragma unroll
  for (int nd = 0; nd < 16; nd++)
#pragma unroll
    for (int r = 0; r < 4; r++) {
      size_t row = qw + l4 * 4 + r;
      aout[row * AO_N + head * HD + nd * 16 + l15] = f2bf(acc[nd][r] * rinv[r]);
    }
#undef STAGE_KV
}

extern "C" void kernel_launch(void* const* d_in, const int* in_sizes, int n_in,
                              void* d_out, int out_size, void* d_ws, size_t ws_size,
                              hipStream_t stream) {
  const float* x = (const float*)d_in[0];
  const int* pos = (const int*)d_in[1];
  const float* wq = (const float*)d_in[2];
  const float* wk = (const float*)d_in[3];
  const float* wv = (const float*)d_in[4];
  const float* wo = (const float*)d_in[5];
  const float* qnw = (const float*)d_in[6];
  const float* knw = (const float*)d_in[7];

  // scratch layout:
  //   d_out: qkv bf16 [4096][4096] (overwritten by final fp32 GEMM)
  //   ws+0        : x bf16 [4096][2304]; later aout bf16 [4096][2048]
  //   ws+18874368 : W^T bf16 (qkv-phase: [4096][2304]; out-phase: wo^T [2304][2048])
  //   ws+28311552 : vt bf16 [4][256][4096]
  u16* qkv = (u16*)d_out;
  u16* xbf = (u16*)d_ws;
  u16* wT = (u16*)((char*)d_ws + 18874368);
  u16* vtb = (u16*)((char*)d_ws + 28311552);
  u16* aout = xbf;

  k_cvt_bf16<<<9216, 256, 0, stream>>>(x, xbf, S_LEN * HID_DIM);
  k_transpose_w<<<dim3(128, 72), 256, 0, stream>>>(wq, wk, wv, wT);
  k_gemm8p<1><<<dim3(256), 512, 0, stream>>>(xbf, wT, qkv, S_LEN, QKV_N, HID_DIM);
  k_vtrans<<<dim3(32, 128), 256, 0, stream>>>(qkv, vtb);
  k_normrope<<<S_LEN * 12, 128, 0, stream>>>(qkv, pos, qnw, knw);
  k_transpose_cvt<<<dim3(72, 64), 256, 0, stream>>>(wo, HID_DIM, wT, 2048, 0);
  k_attn<<<dim3(256), 512, 0, stream>>>(qkv, vtb, pos, aout);
  k_gemm8p<0><<<dim3(144), 512, 0, stream>>>(aout, wT, d_out, S_LEN, HID_DIM, 2048);
}

// Round 10
// 260.272 us; speedup vs baseline: 1.1745x; 1.0226x over previous
//
#include <hip/hip_runtime.h>
#include <stdint.h>

typedef unsigned short u16;
typedef __attribute__((ext_vector_type(8))) short bf16x8;
typedef __attribute__((ext_vector_type(4))) float f32x4;

#define S_LEN 4096
#define HID_DIM 2304
#define QKV_N 4096
#define AO_N 2048
#define HD 256
#define WIN 1024
#define QSCALE 0.0625f

static __device__ __forceinline__ u16 f2bf(float f) {
  union { float f; uint32_t u; } v; v.f = f;
  return (u16)((v.u + 0x7FFFu + ((v.u >> 16) & 1u)) >> 16);
}
static __device__ __forceinline__ float bf2f(u16 h) {
  union { uint32_t u; float f; } v; v.u = ((uint32_t)h) << 16;
  return v.f;
}

static __device__ __forceinline__ void gld16(const void* src, void* dst) {
  __builtin_amdgcn_global_load_lds((const __attribute__((address_space(1))) void*)src,
                                   (__attribute__((address_space(3))) void*)dst, 16, 0, 0);
}

#define BAR() __builtin_amdgcn_s_barrier()
#define LG0() asm volatile("s_waitcnt lgkmcnt(0)" ::: "memory")
#define VM4() asm volatile("s_waitcnt vmcnt(4)" ::: "memory")
#define VM3() asm volatile("s_waitcnt vmcnt(3)" ::: "memory")
#define VM2() asm volatile("s_waitcnt vmcnt(2)" ::: "memory")
#define VM0() asm volatile("s_waitcnt vmcnt(0)" ::: "memory")
#define PRIO1() __builtin_amdgcn_s_setprio(1)
#define PRIO0() __builtin_amdgcn_s_setprio(0)

// ---------------- fp32 -> bf16 elementwise ----------------
__global__ __launch_bounds__(256) void k_cvt_bf16(const float* __restrict__ in,
                                                  u16* __restrict__ out, int n) {
  int i = (blockIdx.x * 256 + threadIdx.x) * 4;
  if (i >= n) return;
  float4 v = *(const float4*)(in + i);
  uint64_t p = (uint64_t)f2bf(v.x) | ((uint64_t)f2bf(v.y) << 16)
             | ((uint64_t)f2bf(v.z) << 32) | ((uint64_t)f2bf(v.w) << 48);
  *(uint64_t*)(out + i) = p;
}

// in: fp32 [R][C] row-major; out bf16: out[(row_off + c)*out_stride + r] = in[r][c]
__global__ __launch_bounds__(256) void k_transpose_cvt(const float* __restrict__ in, int C,
                                                       u16* __restrict__ out, int out_stride,
                                                       int row_off) {
  __shared__ float tile[32][33];
  int c0 = blockIdx.x * 32, r0 = blockIdx.y * 32;
  int tx = threadIdx.x & 31, ty = threadIdx.x >> 5;
#pragma unroll
  for (int i = 0; i < 4; i++)
    tile[ty + i * 8][tx] = in[(size_t)(r0 + ty + i * 8) * C + c0 + tx];
  __syncthreads();
#pragma unroll
  for (int i = 0; i < 4; i++)
    out[(size_t)(row_off + c0 + ty + i * 8) * out_stride + r0 + tx] = f2bf(tile[tx][ty + i * 8]);
}

// ---------------- merged wq/wk/wv transpose-convert into stacked wT [4096][2304] ---------
__global__ __launch_bounds__(256) void k_transpose_w(const float* __restrict__ wq,
                                                     const float* __restrict__ wk,
                                                     const float* __restrict__ wv,
                                                     u16* __restrict__ out) {
  int ct = blockIdx.x;       // 0..127 -> out rows ct*32..+31
  int r0 = blockIdx.y * 32;  // over 2304
  const float* src;
  int C, c0;
  if (ct < 64) {
    src = wq; C = 2048; c0 = ct * 32;
  } else if (ct < 96) {
    src = wk; C = 1024; c0 = (ct - 64) * 32;
  } else {
    src = wv; C = 1024; c0 = (ct - 96) * 32;
  }
  __shared__ float tile[32][33];
  int tx = threadIdx.x & 31, ty = threadIdx.x >> 5;
#pragma unroll
  for (int i = 0; i < 4; i++)
    tile[ty + i * 8][tx] = src[(size_t)(r0 + ty + i * 8) * C + c0 + tx];
  __syncthreads();
#pragma unroll
  for (int i = 0; i < 4; i++)
    out[(size_t)(ct * 32 + ty + i * 8) * HID_DIM + r0 + tx] = f2bf(tile[tx][ty + i * 8]);
}

// ---------------- bf16 transpose of V block of qkv -> vt[kv*256 + d][s] ----------------
__global__ __launch_bounds__(256) void k_vtrans(const u16* __restrict__ qkv,
                                                u16* __restrict__ vtout) {
  __shared__ u16 tile[32][33];
  int c0 = blockIdx.x * 32, s0 = blockIdx.y * 32;
  int tx = threadIdx.x & 31, ty = threadIdx.x >> 5;
#pragma unroll
  for (int i = 0; i < 4; i++)
    tile[ty + i * 8][tx] = qkv[(size_t)(s0 + ty + i * 8) * QKV_N + 3072 + c0 + tx];
  __syncthreads();
#pragma unroll
  for (int i = 0; i < 4; i++)
    vtout[(size_t)(c0 + ty + i * 8) * S_LEN + s0 + tx] = tile[tx][ty + i * 8];
}

// ---------------- bf16 GEMM: 256x256, BK=64, 4-phase pipelined (R7-proven) --------------
template <int OUT_BF16>
__global__ __launch_bounds__(512, 2) void k_gemm8p(const u16* __restrict__ A,
                                                   const u16* __restrict__ Bt,
                                                   void* __restrict__ Cout,
                                                   int M, int N, int K) {
  __shared__ u16 sA[2][256 * 64];
  __shared__ u16 sB[2][256 * 64];
  const int t = threadIdx.x, lane = t & 63, wave = t >> 6;
  const int wr = wave >> 2, wc = wave & 3;
  const int l15 = lane & 15, l4 = lane >> 4;
  const int nbn = N >> 8;
  const int cpx = gridDim.x >> 3;
  const int wg = ((int)blockIdx.x & 7) * cpx + ((int)blockIdx.x >> 3);  // bijective XCD swz
  const int bm = wg / nbn, bn = wg % nbn;
  const int NT = K >> 6;
  const int srow = lane >> 3;
  const int sslot = ((lane & 7) ^ srow) * 8;
  const u16* Abase = A + (size_t)(bm * 256) * K;
  const u16* Bbase = Bt + (size_t)(bn * 256) * K;
  f32x4 acc[8][4] = {};
  bf16x8 aF[4][2], b01[2][2], b23[2][2];

#define STG_A(BUF, HALF, KT) do {                                                 \
    _Pragma("unroll")                                                             \
    for (int c_ = 0; c_ < 2; c_++) {                                              \
      int rb_ = (HALF) * 128 + (wave * 2 + c_) * 8;                               \
      gld16(Abase + (size_t)(rb_ + srow) * K + ((KT) << 6) + sslot,               \
            &sA[BUF][rb_ * 64]);                                                  \
    }                                                                             \
  } while (0)
#define STG_B(BUF, HALF, KT) do {                                                 \
    _Pragma("unroll")                                                             \
    for (int c_ = 0; c_ < 2; c_++) {                                              \
      int rb_ = (HALF) * 128 + (wave * 2 + c_) * 8;                               \
      gld16(Bbase + (size_t)(rb_ + srow) * K + ((KT) << 6) + sslot,               \
            &sB[BUF][rb_ * 64]);                                                  \
    }                                                                             \
  } while (0)
#define LDA(BUF, M_, KK)                                                          \
  (*(const bf16x8*)&sA[BUF][((M_) * 32 + wr * 16 + l15) * 64 +                    \
                            ((((KK) << 2) + l4) ^ (l15 & 7)) * 8])
#define LDB(BUF, N_, KK)                                                          \
  (*(const bf16x8*)&sB[BUF][((N_) * 64 + wc * 16 + l15) * 64 +                    \
                            ((((KK) << 2) + l4) ^ (l15 & 7)) * 8])

#define P1_LOADS(b_) do {                                                         \
    _Pragma("unroll") for (int m_ = 0; m_ < 4; m_++)                              \
      _Pragma("unroll") for (int k_ = 0; k_ < 2; k_++)                            \
        aF[m_][k_] = LDA(b_, m_, k_);                                             \
    _Pragma("unroll") for (int n_ = 0; n_ < 2; n_++)                              \
      _Pragma("unroll") for (int k_ = 0; k_ < 2; k_++)                            \
        b01[n_][k_] = LDB(b_, n_, k_);                                            \
  } while (0)
#define P2_LOADS(b_) do {                                                         \
    _Pragma("unroll") for (int n_ = 0; n_ < 2; n_++)                              \
      _Pragma("unroll") for (int k_ = 0; k_ < 2; k_++)                            \
        b23[n_][k_] = LDB(b_, n_ + 2, k_);                                        \
  } while (0)
#define P3_LOADS(b_) do {                                                         \
    _Pragma("unroll") for (int m_ = 0; m_ < 4; m_++)                              \
      _Pragma("unroll") for (int k_ = 0; k_ < 2; k_++)                            \
        aF[m_][k_] = LDA(b_, m_ + 4, k_);                                         \
  } while (0)
#define MFMA16(MOFF, NOFF, BREG) do {                                             \
    _Pragma("unroll") for (int m_ = 0; m_ < 4; m_++)                              \
      _Pragma("unroll") for (int n_ = 0; n_ < 2; n_++)                            \
        _Pragma("unroll") for (int k_ = 0; k_ < 2; k_++)                          \
          acc[m_ + MOFF][n_ + NOFF] = __builtin_amdgcn_mfma_f32_16x16x32_bf16(    \
              aF[m_][k_], BREG[n_][k_], acc[m_ + MOFF][n_ + NOFF], 0, 0, 0);      \
  } while (0)

  STG_A(0, 0, 0);
  STG_B(0, 0, 0);
  STG_B(0, 1, 0);
  STG_A(0, 1, 0);
  VM4();
  BAR();

  for (int tt = 0; tt < NT - 1; ++tt) {
    const int b = tt & 1, nb = b ^ 1;
    P1_LOADS(b);
    STG_A(nb, 0, tt + 1);
    BAR(); LG0(); PRIO1(); MFMA16(0, 0, b01); PRIO0();
    VM4();
    BAR();
    P2_LOADS(b);
    STG_B(nb, 0, tt + 1);
    BAR(); LG0(); PRIO1(); MFMA16(0, 2, b23); PRIO0();
    VM4();
    BAR();
    P3_LOADS(b);
    STG_B(nb, 1, tt + 1);
    BAR(); LG0(); PRIO1(); MFMA16(4, 0, b01); PRIO0();
    BAR();
    STG_A(nb, 1, tt + 1);
    BAR(); PRIO1(); MFMA16(4, 2, b23); PRIO0();
    VM4();
    BAR();
  }
  {
    const int b = (NT - 1) & 1;
    P1_LOADS(b);
    BAR(); LG0(); PRIO1(); MFMA16(0, 0, b01); PRIO0();
    VM2();
    BAR();
    P2_LOADS(b);
    BAR(); LG0(); PRIO1(); MFMA16(0, 2, b23); PRIO0();
    VM0();
    BAR();
    P3_LOADS(b);
    BAR(); LG0(); PRIO1(); MFMA16(4, 0, b01); PRIO0();
    BAR();
    PRIO1(); MFMA16(4, 2, b23); PRIO0();
  }

#pragma unroll
  for (int m = 0; m < 8; m++)
#pragma unroll
    for (int n = 0; n < 4; n++)
#pragma unroll
      for (int r = 0; r < 4; r++) {
        size_t row = bm * 256 + m * 32 + wr * 16 + l4 * 4 + r;
        size_t col = bn * 256 + n * 64 + wc * 16 + l15;
        if (OUT_BF16)
          ((u16*)Cout)[row * N + col] = f2bf(acc[m][n][r]);
        else
          ((float*)Cout)[row * N + col] = acc[m][n][r];
      }
#undef STG_A
#undef STG_B
#undef LDA
#undef LDB
#undef P1_LOADS
#undef P2_LOADS
#undef P3_LOADS
#undef MFMA16
}

// ---------------- bf16 GEMM 256x192 (out-proj): same 4-phase engine, 192 blocks ----------
// N=2304 -> 12 bn-tiles of 192; grid 192 (%8==0), all blocks co-resident (75% CU util vs
// 56% at 144). Wave tile 128x48 (acc[8][3]). Phases: P1 m0-3 x n01, P2 m0-3 x n2,
// P3 m4-7 x n01, P4 m4-7 x n2. Stage order (tile t+1): Ah0 | Bc0,Bc1 | Bc2 | Ah1 (7 loads).
// Waits (in-order VMEM retirement): P1-end VM4 (Bc2 landed), P2-end VM4 (Ah1), P4-end VM3
// (Ah0+Bc01 of next tile). fp32 out.
__global__ __launch_bounds__(512, 2) void k_gemm192(const u16* __restrict__ A,
                                                    const u16* __restrict__ Bt,
                                                    float* __restrict__ Cout,
                                                    int M, int N, int K) {
  __shared__ u16 sA[2][256 * 64];
  __shared__ u16 sB[2][192 * 64];
  const int t = threadIdx.x, lane = t & 63, wave = t >> 6;
  const int wr = wave >> 2, wc = wave & 3;
  const int l15 = lane & 15, l4 = lane >> 4;
  const int nbn = N / 192;  // 12
  const int cpx = gridDim.x >> 3;
  const int wg = ((int)blockIdx.x & 7) * cpx + ((int)blockIdx.x >> 3);
  const int bm = wg / nbn, bn = wg % nbn;
  const int NT = K >> 6;
  const int srow = lane >> 3;
  const int sslot = ((lane & 7) ^ srow) * 8;
  const u16* Abase = A + (size_t)(bm * 256) * K;
  const u16* Bbase = Bt + (size_t)(bn * 192) * K;
  f32x4 acc[8][3] = {};
  bf16x8 aF[4][2], b01[2][2], b2[2];

#define GA_STG_A(BUF, HALF, KT) do {                                              \
    _Pragma("unroll")                                                             \
    for (int c_ = 0; c_ < 2; c_++) {                                              \
      int rb_ = (HALF) * 128 + (wave * 2 + c_) * 8;                               \
      gld16(Abase + (size_t)(rb_ + srow) * K + ((KT) << 6) + sslot,               \
            &sA[BUF][rb_ * 64]);                                                  \
    }                                                                             \
  } while (0)
#define GA_STG_BC(BUF, CH, KT) do {                                               \
    int rb_ = (CH) * 64 + wave * 8;                                               \
    gld16(Bbase + (size_t)(rb_ + srow) * K + ((KT) << 6) + sslot,                 \
          &sB[BUF][rb_ * 64]);                                                    \
  } while (0)
#define GA_LDA(BUF, M_, KK)                                                       \
  (*(const bf16x8*)&sA[BUF][((M_) * 32 + wr * 16 + l15) * 64 +                    \
                            ((((KK) << 2) + l4) ^ (l15 & 7)) * 8])
#define GA_LDB(BUF, N_, KK)                                                       \
  (*(const bf16x8*)&sB[BUF][((N_) * 64 + wc * 16 + l15) * 64 +                    \
                            ((((KK) << 2) + l4) ^ (l15 & 7)) * 8])
#define GA_P1_LOADS(b_) do {                                                      \
    _Pragma("unroll") for (int m_ = 0; m_ < 4; m_++)                              \
      _Pragma("unroll") for (int k_ = 0; k_ < 2; k_++)                            \
        aF[m_][k_] = GA_LDA(b_, m_, k_);                                          \
    _Pragma("unroll") for (int n_ = 0; n_ < 2; n_++)                              \
      _Pragma("unroll") for (int k_ = 0; k_ < 2; k_++)                            \
        b01[n_][k_] = GA_LDB(b_, n_, k_);                                         \
  } while (0)
#define GA_P2_LOADS(b_) do {                                                      \
    _Pragma("unroll") for (int k_ = 0; k_ < 2; k_++)                              \
      b2[k_] = GA_LDB(b_, 2, k_);                                                 \
  } while (0)
#define GA_P3_LOADS(b_) do {                                                      \
    _Pragma("unroll") for (int m_ = 0; m_ < 4; m_++)                              \
      _Pragma("unroll") for (int k_ = 0; k_ < 2; k_++)                            \
        aF[m_][k_] = GA_LDA(b_, m_ + 4, k_);                                      \
  } while (0)
#define GA_MFMA_N01(MOFF) do {                                                    \
    _Pragma("unroll") for (int m_ = 0; m_ < 4; m_++)                              \
      _Pragma("unroll") for (int n_ = 0; n_ < 2; n_++)                            \
        _Pragma("unroll") for (int k_ = 0; k_ < 2; k_++)                          \
          acc[m_ + MOFF][n_] = __builtin_amdgcn_mfma_f32_16x16x32_bf16(           \
              aF[m_][k_], b01[n_][k_], acc[m_ + MOFF][n_], 0, 0, 0);              \
  } while (0)
#define GA_MFMA_N2(MOFF) do {                                                     \
    _Pragma("unroll") for (int m_ = 0; m_ < 4; m_++)                              \
      _Pragma("unroll") for (int k_ = 0; k_ < 2; k_++)                            \
        acc[m_ + MOFF][2] = __builtin_amdgcn_mfma_f32_16x16x32_bf16(              \
            aF[m_][k_], b2[k_], acc[m_ + MOFF][2], 0, 0, 0);                      \
  } while (0)

  // prologue: stage tile 0 in consumption order; leave {Bc2, Ah1} in flight
  GA_STG_A(0, 0, 0);
  GA_STG_BC(0, 0, 0);
  GA_STG_BC(0, 1, 0);
  GA_STG_BC(0, 2, 0);
  GA_STG_A(0, 1, 0);
  VM3();
  BAR();

  for (int tt = 0; tt < NT - 1; ++tt) {
    const int b = tt & 1, nb = b ^ 1;
    // P1: m0-3 x n01 (Ah0,Bc01 of tt landed via prev VM3)
    GA_P1_LOADS(b);
    GA_STG_A(nb, 0, tt + 1);
    BAR(); LG0(); PRIO1(); GA_MFMA_N01(0); PRIO0();
    VM4();  // Bc2(tt) landed for P2
    BAR();
    // P2: m0-3 x n2
    GA_P2_LOADS(b);
    GA_STG_BC(nb, 0, tt + 1);
    GA_STG_BC(nb, 1, tt + 1);
    BAR(); LG0(); PRIO1(); GA_MFMA_N2(0); PRIO0();
    VM4();  // Ah1(tt) landed for P3
    BAR();
    // P3: m4-7 x n01
    GA_P3_LOADS(b);
    GA_STG_BC(nb, 2, tt + 1);
    BAR(); LG0(); PRIO1(); GA_MFMA_N01(4); PRIO0();
    BAR();
    // P4: m4-7 x n2 (regs only)
    GA_STG_A(nb, 1, tt + 1);
    BAR(); PRIO1(); GA_MFMA_N2(4); PRIO0();
    VM3();  // Ah0+Bc01 of tt+1 landed for next P1; leaves {Bc2, Ah1}
    BAR();
  }
  {  // last tile: no staging; drain with counted waits
    const int b = (NT - 1) & 1;
    GA_P1_LOADS(b);
    BAR(); LG0(); PRIO1(); GA_MFMA_N01(0); PRIO0();
    VM2();  // Bc2 landed
    BAR();
    GA_P2_LOADS(b);
    BAR(); LG0(); PRIO1(); GA_MFMA_N2(0); PRIO0();
    VM0();  // Ah1 landed
    BAR();
    GA_P3_LOADS(b);
    BAR(); LG0(); PRIO1(); GA_MFMA_N01(4); PRIO0();
    BAR();
    PRIO1(); GA_MFMA_N2(4); PRIO0();
  }

#pragma unroll
  for (int m = 0; m < 8; m++)
#pragma unroll
    for (int n = 0; n < 3; n++)
#pragma unroll
      for (int r = 0; r < 4; r++) {
        size_t row = bm * 256 + m * 32 + wr * 16 + l4 * 4 + r;
        size_t col = bn * 192 + n * 64 + wc * 16 + l15;
        Cout[row * N + col] = acc[m][n][r];
      }
#undef GA_STG_A
#undef GA_STG_BC
#undef GA_LDA
#undef GA_LDB
#undef GA_P1_LOADS
#undef GA_P2_LOADS
#undef GA_P3_LOADS
#undef GA_MFMA_N01
#undef GA_MFMA_N2
}

// ---------------- fused RMSNorm + RoPE + scale, in place on bf16 q/k ----------------
__global__ __launch_bounds__(128) void k_normrope(u16* __restrict__ qkv,
                                                  const int* __restrict__ pos_ids,
                                                  const float* __restrict__ qw,
                                                  const float* __restrict__ kw) {
  __shared__ float cross[2];
  int idx = blockIdx.x;
  int s = idx / 12, r = idx % 12;
  bool is_q = (r < 8);
  u16* p = qkv + (size_t)s * QKV_N + (is_q ? r * HD : 2048 + (r - 8) * HD);
  const float* w = is_q ? qw : kw;
  int j = threadIdx.x;  // 0..127
  float x1 = bf2f(p[j]), x2 = bf2f(p[j + 128]);
  float ss = x1 * x1 + x2 * x2;
#pragma unroll
  for (int off = 1; off < 64; off <<= 1) ss += __shfl_xor(ss, off);
  if ((threadIdx.x & 63) == 0) cross[threadIdx.x >> 6] = ss;
  __syncthreads();
  float rms = rsqrtf((cross[0] + cross[1]) * (1.0f / 256.0f) + 1e-6f);
  float y1 = x1 * rms * (1.0f + w[j]);
  float y2 = x2 * rms * (1.0f + w[j + 128]);
  float ang = (float)pos_ids[s] * exp2f((float)j * (-13.287712379549449f / 128.0f));
  float sn, c;
  sincosf(ang, &sn, &c);
  float sc = is_q ? QSCALE : 1.0f;
  p[j] = f2bf((y1 * c - y2 * sn) * sc);
  p[j + 128] = f2bf((y1 * sn + y2 * c) * sc);
}

// ---------------- flash attention v6: 64 q/block, GQA-shared K/V ----------------
__global__ __launch_bounds__(512, 2) void k_attn(const u16* __restrict__ qkv,
                                                 const u16* __restrict__ vt,
                                                 const int* __restrict__ pos_ids,
                                                 u16* __restrict__ aout) {
  __shared__ u16 lK[64 * 256];   // [key][d], rows 512B, swizzled
  __shared__ u16 lV[256 * 64];   // [d][key], rows 128B, swizzled
  __shared__ u16 lP[8][16 * 64]; // per-wave P, rows 128B, swizzled
  const int bid = blockIdx.x;    // 256 blocks
  const int wg = (bid & 7) * 32 + (bid >> 3);  // bijective XCD swizzle
  const int kvh = wg >> 6;                     // 0..3
  const int q0 = (wg & 63) * 64;               // 0..4032
  const int t = threadIdx.x, lane = t & 63, wave = t >> 6;
  const int l15 = lane & 15, l4 = lane >> 4;
  const int head = kvh * 2 + (wave >> 2);
  const int qw = q0 + (wave & 3) * 16;

  bf16x8 qfr[8];
  {
    const u16* qptr = qkv + (size_t)(qw + l15) * QKV_N + head * HD + l4 * 8;
#pragma unroll
    for (int kc = 0; kc < 8; kc++) qfr[kc] = *(const bf16x8*)(qptr + kc * 32);
  }
  f32x4 acc[16] = {};
  float mrow[4], lrow[4];
#pragma unroll
  for (int r = 0; r < 4; r++) { mrow[r] = -1e30f; lrow[r] = 0.0f; }
  int qi[4];
#pragma unroll
  for (int r = 0; r < 4; r++) qi[r] = pos_ids[qw + l4 * 4 + r];

  const int krw = lane >> 5, kcl = lane & 31;
  const int vrw = lane >> 3, vcl = lane & 7;
  const u16* kgb = qkv + 2048 + kvh * HD;
  const u16* vgb = vt + (size_t)kvh * HD * S_LEN;

  int start = q0 - (WIN - 1);
  if (start < 0) start = 0;
  start &= ~63;

#define STAGE_KV(T0) do {                                                             \
    _Pragma("unroll")                                                                 \
    for (int i_ = 0; i_ < 4; i_++) {                                                  \
      int ch_ = wave * 4 + i_;                                                        \
      int kr_ = ch_ * 2 + krw;                                                        \
      gld16(kgb + (size_t)((T0) + kr_) * QKV_N + ((kcl ^ (kr_ & 7)) * 8),             \
            &lK[ch_ * 512]);                                                          \
      int vr_ = ch_ * 8 + vrw;                                                        \
      gld16(vgb + (size_t)vr_ * S_LEN + (T0) + ((vcl ^ (vr_ & 7)) * 8),               \
            &lV[ch_ * 512]);                                                          \
    }                                                                                 \
  } while (0)

  for (int t0 = start; t0 <= q0 + 63; t0 += 64) {
    STAGE_KV(t0);
    int kp[4];
#pragma unroll
    for (int kb = 0; kb < 4; kb++) kp[kb] = pos_ids[t0 + kb * 16 + l15];
    __syncthreads();
    f32x4 sv[4] = {};
    PRIO1();
#pragma unroll
    for (int kb = 0; kb < 4; kb++) {
      const char* krow = (const char*)&lK[(kb * 16 + l15) * 256];
      const int sw = ((kb * 16 + l15) & 7) << 4;
#pragma unroll
      for (int kc = 0; kc < 8; kc++) {
        bf16x8 kf = *(const bf16x8*)(krow + ((kc * 64 + l4 * 16) ^ sw));
        sv[kb] = __builtin_amdgcn_mfma_f32_16x16x32_bf16(qfr[kc], kf, sv[kb], 0, 0, 0);
      }
    }
    PRIO0();
    float sloc[4][4], mx[4];
    float need = 0.0f;
#pragma unroll
    for (int r = 0; r < 4; r++) {
      int pi = qi[r];
#pragma unroll
      for (int kb = 0; kb < 4; kb++)
        sloc[r][kb] = ((kp[kb] <= pi) && (pi - kp[kb] < WIN)) ? sv[kb][r] : -__builtin_inff();
      float m_ = fmaxf(fmaxf(sloc[r][0], sloc[r][1]), fmaxf(sloc[r][2], sloc[r][3]));
#pragma unroll
      for (int off = 1; off < 16; off <<= 1) m_ = fmaxf(m_, __shfl_xor(m_, off));
      mx[r] = m_;
      need = fmaxf(need, m_ - mrow[r]);
    }
    bool resc = __any(need > 8.0f);
    if (resc) {
#pragma unroll
      for (int r = 0; r < 4; r++) {
        float nm = fmaxf(mrow[r], mx[r]);
        float al = __expf(mrow[r] - nm);
        mrow[r] = nm;
        lrow[r] *= al;
#pragma unroll
        for (int nd = 0; nd < 16; nd++) acc[nd][r] *= al;
      }
    }
#pragma unroll
    for (int r = 0; r < 4; r++) {
      float nm = mrow[r];
      float e0 = __expf(sloc[r][0] - nm), e1 = __expf(sloc[r][1] - nm);
      float e2 = __expf(sloc[r][2] - nm), e3 = __expf(sloc[r][3] - nm);
      float sum = (e0 + e1) + (e2 + e3);
#pragma unroll
      for (int off = 1; off < 16; off <<= 1) sum += __shfl_xor(sum, off);
      lrow[r] += sum;
      int q = l4 * 4 + r;
      char* lpw = (char*)&lP[wave][0] + q * 128;
      int swp = (q & 7) << 4;
      *(u16*)(lpw + ((l15 * 2) ^ swp)) = f2bf(e0);
      *(u16*)(lpw + ((32 + l15 * 2) ^ swp)) = f2bf(e1);
      *(u16*)(lpw + ((64 + l15 * 2) ^ swp)) = f2bf(e2);
      *(u16*)(lpw + ((96 + l15 * 2) ^ swp)) = f2bf(e3);
    }
#pragma unroll
    for (int kc2 = 0; kc2 < 2; kc2++) {
      int q = l15;
      bf16x8 pa = *(const bf16x8*)((const char*)&lP[wave][0] + q * 128 +
                                   ((kc2 * 64 + l4 * 16) ^ ((q & 7) << 4)));
      PRIO1();
#pragma unroll
      for (int nd = 0; nd < 16; nd++) {
        int d = nd * 16 + l15;
        bf16x8 vf = *(const bf16x8*)((const char*)&lV[d * 64] +
                                     ((kc2 * 64 + l4 * 16) ^ ((d & 7) << 4)));
        acc[nd] = __builtin_amdgcn_mfma_f32_16x16x32_bf16(pa, vf, acc[nd], 0, 0, 0);
      }
      PRIO0();
    }
    __syncthreads();
  }
  float rinv[4];
#pragma unroll
  for (int r = 0; r < 4; r++) rinv[r] = 1.0f / lrow[r];
#pragma unroll
  for (int nd = 0; nd < 16; nd++)
#pragma unroll
    for (int r = 0; r < 4; r++) {
      size_t row = qw + l4 * 4 + r;
      aout[row * AO_N + head * HD + nd * 16 + l15] = f2bf(acc[nd][r] * rinv[r]);
    }
#undef STAGE_KV
}

extern "C" void kernel_launch(void* const* d_in, const int* in_sizes, int n_in,
                              void* d_out, int out_size, void* d_ws, size_t ws_size,
                              hipStream_t stream) {
  const float* x = (const float*)d_in[0];
  const int* pos = (const int*)d_in[1];
  const float* wq = (const float*)d_in[2];
  const float* wk = (const float*)d_in[3];
  const float* wv = (const float*)d_in[4];
  const float* wo = (const float*)d_in[5];
  const float* qnw = (const float*)d_in[6];
  const float* knw = (const float*)d_in[7];

  // scratch layout:
  //   d_out: qkv bf16 [4096][4096] (overwritten by final fp32 GEMM)
  //   ws+0        : x bf16 [4096][2304]; later aout bf16 [4096][2048]
  //   ws+18874368 : W^T bf16 (qkv-phase: [4096][2304]; out-phase: wo^T [2304][2048])
  //   ws+28311552 : vt bf16 [4][256][4096]
  u16* qkv = (u16*)d_out;
  u16* xbf = (u16*)d_ws;
  u16* wT = (u16*)((char*)d_ws + 18874368);
  u16* vtb = (u16*)((char*)d_ws + 28311552);
  u16* aout = xbf;

  k_cvt_bf16<<<9216, 256, 0, stream>>>(x, xbf, S_LEN * HID_DIM);
  k_transpose_w<<<dim3(128, 72), 256, 0, stream>>>(wq, wk, wv, wT);
  k_gemm8p<1><<<dim3(256), 512, 0, stream>>>(xbf, wT, qkv, S_LEN, QKV_N, HID_DIM);
  k_vtrans<<<dim3(32, 128), 256, 0, stream>>>(qkv, vtb);
  k_normrope<<<S_LEN * 12, 128, 0, stream>>>(qkv, pos, qnw, knw);
  k_transpose_cvt<<<dim3(72, 64), 256, 0, stream>>>(wo, HID_DIM, wT, 2048, 0);
  k_attn<<<dim3(256), 512, 0, stream>>>(qkv, vtb, pos, aout);
  k_gemm192<<<dim3(192), 512, 0, stream>>>(aout, wT, (float*)d_out, S_LEN, HID_DIM, 2048);
}

// Round 11
// 249.410 us; speedup vs baseline: 1.2256x; 1.0436x over previous
//
#include <hip/hip_runtime.h>
#include <stdint.h>

typedef unsigned short u16;
typedef __attribute__((ext_vector_type(8))) short bf16x8;
typedef __attribute__((ext_vector_type(4))) float f32x4;

#define S_LEN 4096
#define HID_DIM 2304
#define QKV_N 4096
#define AO_N 2048
#define HD 256
#define WIN 1024
#define QSCALE 0.0625f

static __device__ __forceinline__ u16 f2bf(float f) {
  union { float f; uint32_t u; } v; v.f = f;
  return (u16)((v.u + 0x7FFFu + ((v.u >> 16) & 1u)) >> 16);
}
static __device__ __forceinline__ float bf2f(u16 h) {
  union { uint32_t u; float f; } v; v.u = ((uint32_t)h) << 16;
  return v.f;
}

static __device__ __forceinline__ void gld16(const void* src, void* dst) {
  __builtin_amdgcn_global_load_lds((const __attribute__((address_space(1))) void*)src,
                                   (__attribute__((address_space(3))) void*)dst, 16, 0, 0);
}

#define BAR() __builtin_amdgcn_s_barrier()
#define LG0() asm volatile("s_waitcnt lgkmcnt(0)" ::: "memory")
#define VM6() asm volatile("s_waitcnt vmcnt(6)" ::: "memory")
#define VM5() asm volatile("s_waitcnt vmcnt(5)" ::: "memory")
#define VM4() asm volatile("s_waitcnt vmcnt(4)" ::: "memory")
#define VM3() asm volatile("s_waitcnt vmcnt(3)" ::: "memory")
#define VM2() asm volatile("s_waitcnt vmcnt(2)" ::: "memory")
#define VM0() asm volatile("s_waitcnt vmcnt(0)" ::: "memory")
#define PRIO1() __builtin_amdgcn_s_setprio(1)
#define PRIO0() __builtin_amdgcn_s_setprio(0)

// ---------------- fp32 -> bf16 elementwise ----------------
__global__ __launch_bounds__(256) void k_cvt_bf16(const float* __restrict__ in,
                                                  u16* __restrict__ out, int n) {
  int i = (blockIdx.x * 256 + threadIdx.x) * 4;
  if (i >= n) return;
  float4 v = *(const float4*)(in + i);
  uint64_t p = (uint64_t)f2bf(v.x) | ((uint64_t)f2bf(v.y) << 16)
             | ((uint64_t)f2bf(v.z) << 32) | ((uint64_t)f2bf(v.w) << 48);
  *(uint64_t*)(out + i) = p;
}

// in: fp32 [R][C] row-major; out bf16: out[(row_off + c)*out_stride + r] = in[r][c]
__global__ __launch_bounds__(256) void k_transpose_cvt(const float* __restrict__ in, int C,
                                                       u16* __restrict__ out, int out_stride,
                                                       int row_off) {
  __shared__ float tile[32][33];
  int c0 = blockIdx.x * 32, r0 = blockIdx.y * 32;
  int tx = threadIdx.x & 31, ty = threadIdx.x >> 5;
#pragma unroll
  for (int i = 0; i < 4; i++)
    tile[ty + i * 8][tx] = in[(size_t)(r0 + ty + i * 8) * C + c0 + tx];
  __syncthreads();
#pragma unroll
  for (int i = 0; i < 4; i++)
    out[(size_t)(row_off + c0 + ty + i * 8) * out_stride + r0 + tx] = f2bf(tile[tx][ty + i * 8]);
}

// ---------------- merged wq/wk/wv transpose-convert into stacked wT [4096][2304] ---------
__global__ __launch_bounds__(256) void k_transpose_w(const float* __restrict__ wq,
                                                     const float* __restrict__ wk,
                                                     const float* __restrict__ wv,
                                                     u16* __restrict__ out) {
  int ct = blockIdx.x;       // 0..127 -> out rows ct*32..+31
  int r0 = blockIdx.y * 32;  // over 2304
  const float* src;
  int C, c0;
  if (ct < 64) {
    src = wq; C = 2048; c0 = ct * 32;
  } else if (ct < 96) {
    src = wk; C = 1024; c0 = (ct - 64) * 32;
  } else {
    src = wv; C = 1024; c0 = (ct - 96) * 32;
  }
  __shared__ float tile[32][33];
  int tx = threadIdx.x & 31, ty = threadIdx.x >> 5;
#pragma unroll
  for (int i = 0; i < 4; i++)
    tile[ty + i * 8][tx] = src[(size_t)(r0 + ty + i * 8) * C + c0 + tx];
  __syncthreads();
#pragma unroll
  for (int i = 0; i < 4; i++)
    out[(size_t)(ct * 32 + ty + i * 8) * HID_DIM + r0 + tx] = f2bf(tile[tx][ty + i * 8]);
}

// ---------------- bf16 transpose of V block of qkv -> vt[kv*256 + d][s] ----------------
__global__ __launch_bounds__(256) void k_vtrans(const u16* __restrict__ qkv,
                                                u16* __restrict__ vtout) {
  __shared__ u16 tile[32][33];
  int c0 = blockIdx.x * 32, s0 = blockIdx.y * 32;
  int tx = threadIdx.x & 31, ty = threadIdx.x >> 5;
#pragma unroll
  for (int i = 0; i < 4; i++)
    tile[ty + i * 8][tx] = qkv[(size_t)(s0 + ty + i * 8) * QKV_N + 3072 + c0 + tx];
  __syncthreads();
#pragma unroll
  for (int i = 0; i < 4; i++)
    vtout[(size_t)(c0 + ty + i * 8) * S_LEN + s0 + tx] = tile[tx][ty + i * 8];
}

// ---------------- bf16 GEMM: 256x256, BK=64, 4-phase, uniform lag-4 staging -------------
// R11: stage order {Ah0,Bh0}@P1, Bh1@P2, Ah1@P3, none@P4 -> every half-tile staged exactly
// 4 phases before its consumption (was lag-3 for 3 of 4). Waits VM6/VM6/-/VM4; in-order
// VMEM retirement. In-flight invariant at P1 entry: {Bh1,Ah1}(t) = 4 loads.
template <int OUT_BF16>
__global__ __launch_bounds__(512, 2) void k_gemm8p(const u16* __restrict__ A,
                                                   const u16* __restrict__ Bt,
                                                   void* __restrict__ Cout,
                                                   int M, int N, int K) {
  __shared__ u16 sA[2][256 * 64];
  __shared__ u16 sB[2][256 * 64];
  const int t = threadIdx.x, lane = t & 63, wave = t >> 6;
  const int wr = wave >> 2, wc = wave & 3;
  const int l15 = lane & 15, l4 = lane >> 4;
  const int nbn = N >> 8;
  const int cpx = gridDim.x >> 3;
  const int wg = ((int)blockIdx.x & 7) * cpx + ((int)blockIdx.x >> 3);  // bijective XCD swz
  const int bm = wg / nbn, bn = wg % nbn;
  const int NT = K >> 6;
  const int srow = lane >> 3;
  const int sslot = ((lane & 7) ^ srow) * 8;
  const u16* Abase = A + (size_t)(bm * 256) * K;
  const u16* Bbase = Bt + (size_t)(bn * 256) * K;
  f32x4 acc[8][4] = {};
  bf16x8 aF[4][2], b01[2][2], b23[2][2];

#define STG_A(BUF, HALF, KT) do {                                                 \
    _Pragma("unroll")                                                             \
    for (int c_ = 0; c_ < 2; c_++) {                                              \
      int rb_ = (HALF) * 128 + (wave * 2 + c_) * 8;                               \
      gld16(Abase + (size_t)(rb_ + srow) * K + ((KT) << 6) + sslot,               \
            &sA[BUF][rb_ * 64]);                                                  \
    }                                                                             \
  } while (0)
#define STG_B(BUF, HALF, KT) do {                                                 \
    _Pragma("unroll")                                                             \
    for (int c_ = 0; c_ < 2; c_++) {                                              \
      int rb_ = (HALF) * 128 + (wave * 2 + c_) * 8;                               \
      gld16(Bbase + (size_t)(rb_ + srow) * K + ((KT) << 6) + sslot,               \
            &sB[BUF][rb_ * 64]);                                                  \
    }                                                                             \
  } while (0)
#define LDA(BUF, M_, KK)                                                          \
  (*(const bf16x8*)&sA[BUF][((M_) * 32 + wr * 16 + l15) * 64 +                    \
                            ((((KK) << 2) + l4) ^ (l15 & 7)) * 8])
#define LDB(BUF, N_, KK)                                                          \
  (*(const bf16x8*)&sB[BUF][((N_) * 64 + wc * 16 + l15) * 64 +                    \
                            ((((KK) << 2) + l4) ^ (l15 & 7)) * 8])

#define P1_LOADS(b_) do {                                                         \
    _Pragma("unroll") for (int m_ = 0; m_ < 4; m_++)                              \
      _Pragma("unroll") for (int k_ = 0; k_ < 2; k_++)                            \
        aF[m_][k_] = LDA(b_, m_, k_);                                             \
    _Pragma("unroll") for (int n_ = 0; n_ < 2; n_++)                              \
      _Pragma("unroll") for (int k_ = 0; k_ < 2; k_++)                            \
        b01[n_][k_] = LDB(b_, n_, k_);                                            \
  } while (0)
#define P2_LOADS(b_) do {                                                         \
    _Pragma("unroll") for (int n_ = 0; n_ < 2; n_++)                              \
      _Pragma("unroll") for (int k_ = 0; k_ < 2; k_++)                            \
        b23[n_][k_] = LDB(b_, n_ + 2, k_);                                        \
  } while (0)
#define P3_LOADS(b_) do {                                                         \
    _Pragma("unroll") for (int m_ = 0; m_ < 4; m_++)                              \
      _Pragma("unroll") for (int k_ = 0; k_ < 2; k_++)                            \
        aF[m_][k_] = LDA(b_, m_ + 4, k_);                                         \
  } while (0)
#define MFMA16(MOFF, NOFF, BREG) do {                                             \
    _Pragma("unroll") for (int m_ = 0; m_ < 4; m_++)                              \
      _Pragma("unroll") for (int n_ = 0; n_ < 2; n_++)                            \
        _Pragma("unroll") for (int k_ = 0; k_ < 2; k_++)                          \
          acc[m_ + MOFF][n_ + NOFF] = __builtin_amdgcn_mfma_f32_16x16x32_bf16(    \
              aF[m_][k_], BREG[n_][k_], acc[m_ + MOFF][n_ + NOFF], 0, 0, 0);      \
  } while (0)

  // prologue: stage tile 0 in consumption order; leaves {Bh1,Ah1} (4) in flight
  STG_A(0, 0, 0);
  STG_B(0, 0, 0);
  STG_B(0, 1, 0);
  STG_A(0, 1, 0);
  VM4();
  BAR();

  for (int tt = 0; tt < NT - 1; ++tt) {
    const int b = tt & 1, nb = b ^ 1;
    // P1: consumes Ah0,Bh0(t) [staged P1(t-1), lag 4]; stages {Ah0,Bh0}(t+1)
    P1_LOADS(b);
    STG_A(nb, 0, tt + 1);
    STG_B(nb, 0, tt + 1);
    BAR(); LG0(); PRIO1(); MFMA16(0, 0, b01); PRIO0();
    VM6();  // Bh1(t) landed for P2; leaves Ah1(t)+AhBh0(t+1) = 6
    BAR();
    // P2: consumes Bh1(t) [lag 4]; stages Bh1(t+1)
    P2_LOADS(b);
    STG_B(nb, 1, tt + 1);
    BAR(); LG0(); PRIO1(); MFMA16(0, 2, b23); PRIO0();
    VM6();  // Ah1(t) landed for P3; leaves AhBh0+Bh1(t+1) = 6
    BAR();
    // P3: consumes Ah1(t) [lag 4]; stages Ah1(t+1)
    P3_LOADS(b);
    STG_A(nb, 1, tt + 1);
    BAR(); LG0(); PRIO1(); MFMA16(4, 0, b01); PRIO0();
    BAR();
    // P4: regs only
    PRIO1(); MFMA16(4, 2, b23); PRIO0();
    VM4();  // Ah0,Bh0(t+1) landed for next P1; leaves {Bh1,Ah1}(t+1) = 4
    BAR();
  }
  {  // last tile: entry in-flight {Bh1,Ah1}(L) = 4; drain with counted waits
    const int b = (NT - 1) & 1;
    P1_LOADS(b);
    BAR(); LG0(); PRIO1(); MFMA16(0, 0, b01); PRIO0();
    VM2();  // Bh1(L) landed
    BAR();
    P2_LOADS(b);
    BAR(); LG0(); PRIO1(); MFMA16(0, 2, b23); PRIO0();
    VM0();  // Ah1(L) landed
    BAR();
    P3_LOADS(b);
    BAR(); LG0(); PRIO1(); MFMA16(4, 0, b01); PRIO0();
    BAR();
    PRIO1(); MFMA16(4, 2, b23); PRIO0();
  }

#pragma unroll
  for (int m = 0; m < 8; m++)
#pragma unroll
    for (int n = 0; n < 4; n++)
#pragma unroll
      for (int r = 0; r < 4; r++) {
        size_t row = bm * 256 + m * 32 + wr * 16 + l4 * 4 + r;
        size_t col = bn * 256 + n * 64 + wc * 16 + l15;
        if (OUT_BF16)
          ((u16*)Cout)[row * N + col] = f2bf(acc[m][n][r]);
        else
          ((float*)Cout)[row * N + col] = acc[m][n][r];
      }
#undef STG_A
#undef STG_B
#undef LDA
#undef LDB
#undef P1_LOADS
#undef P2_LOADS
#undef P3_LOADS
#undef MFMA16
}

// ---------------- bf16 GEMM 256x192 (out-proj): 4-phase, uniform lag-4 staging ----------
// Stage order {Ah0,Bc0,Bc1}@P1, Bc2@P2, Ah1@P3, none@P4; waits VM6/VM5/-/VM3.
// In-flight invariant at P1 entry: {Bc2,Ah1}(t) = 3 loads. Grid 192, fp32 out.
__global__ __launch_bounds__(512, 2) void k_gemm192(const u16* __restrict__ A,
                                                    const u16* __restrict__ Bt,
                                                    float* __restrict__ Cout,
                                                    int M, int N, int K) {
  __shared__ u16 sA[2][256 * 64];
  __shared__ u16 sB[2][192 * 64];
  const int t = threadIdx.x, lane = t & 63, wave = t >> 6;
  const int wr = wave >> 2, wc = wave & 3;
  const int l15 = lane & 15, l4 = lane >> 4;
  const int nbn = N / 192;  // 12
  const int cpx = gridDim.x >> 3;
  const int wg = ((int)blockIdx.x & 7) * cpx + ((int)blockIdx.x >> 3);
  const int bm = wg / nbn, bn = wg % nbn;
  const int NT = K >> 6;
  const int srow = lane >> 3;
  const int sslot = ((lane & 7) ^ srow) * 8;
  const u16* Abase = A + (size_t)(bm * 256) * K;
  const u16* Bbase = Bt + (size_t)(bn * 192) * K;
  f32x4 acc[8][3] = {};
  bf16x8 aF[4][2], b01[2][2], b2[2];

#define GA_STG_A(BUF, HALF, KT) do {                                              \
    _Pragma("unroll")                                                             \
    for (int c_ = 0; c_ < 2; c_++) {                                              \
      int rb_ = (HALF) * 128 + (wave * 2 + c_) * 8;                               \
      gld16(Abase + (size_t)(rb_ + srow) * K + ((KT) << 6) + sslot,               \
            &sA[BUF][rb_ * 64]);                                                  \
    }                                                                             \
  } while (0)
#define GA_STG_BC(BUF, CH, KT) do {                                               \
    int rb_ = (CH) * 64 + wave * 8;                                               \
    gld16(Bbase + (size_t)(rb_ + srow) * K + ((KT) << 6) + sslot,                 \
          &sB[BUF][rb_ * 64]);                                                    \
  } while (0)
#define GA_LDA(BUF, M_, KK)                                                       \
  (*(const bf16x8*)&sA[BUF][((M_) * 32 + wr * 16 + l15) * 64 +                    \
                            ((((KK) << 2) + l4) ^ (l15 & 7)) * 8])
#define GA_LDB(BUF, N_, KK)                                                       \
  (*(const bf16x8*)&sB[BUF][((N_) * 64 + wc * 16 + l15) * 64 +                    \
                            ((((KK) << 2) + l4) ^ (l15 & 7)) * 8])
#define GA_P1_LOADS(b_) do {                                                      \
    _Pragma("unroll") for (int m_ = 0; m_ < 4; m_++)                              \
      _Pragma("unroll") for (int k_ = 0; k_ < 2; k_++)                            \
        aF[m_][k_] = GA_LDA(b_, m_, k_);                                          \
    _Pragma("unroll") for (int n_ = 0; n_ < 2; n_++)                              \
      _Pragma("unroll") for (int k_ = 0; k_ < 2; k_++)                            \
        b01[n_][k_] = GA_LDB(b_, n_, k_);                                         \
  } while (0)
#define GA_P2_LOADS(b_) do {                                                      \
    _Pragma("unroll") for (int k_ = 0; k_ < 2; k_++)                              \
      b2[k_] = GA_LDB(b_, 2, k_);                                                 \
  } while (0)
#define GA_P3_LOADS(b_) do {                                                      \
    _Pragma("unroll") for (int m_ = 0; m_ < 4; m_++)                              \
      _Pragma("unroll") for (int k_ = 0; k_ < 2; k_++)                            \
        aF[m_][k_] = GA_LDA(b_, m_ + 4, k_);                                      \
  } while (0)
#define GA_MFMA_N01(MOFF) do {                                                    \
    _Pragma("unroll") for (int m_ = 0; m_ < 4; m_++)                              \
      _Pragma("unroll") for (int n_ = 0; n_ < 2; n_++)                            \
        _Pragma("unroll") for (int k_ = 0; k_ < 2; k_++)                          \
          acc[m_ + MOFF][n_] = __builtin_amdgcn_mfma_f32_16x16x32_bf16(           \
              aF[m_][k_], b01[n_][k_], acc[m_ + MOFF][n_], 0, 0, 0);              \
  } while (0)
#define GA_MFMA_N2(MOFF) do {                                                     \
    _Pragma("unroll") for (int m_ = 0; m_ < 4; m_++)                              \
      _Pragma("unroll") for (int k_ = 0; k_ < 2; k_++)                            \
        acc[m_ + MOFF][2] = __builtin_amdgcn_mfma_f32_16x16x32_bf16(              \
            aF[m_][k_], b2[k_], acc[m_ + MOFF][2], 0, 0, 0);                      \
  } while (0)

  // prologue: stage tile 0 in consumption order; leaves {Bc2,Ah1} (3) in flight
  GA_STG_A(0, 0, 0);
  GA_STG_BC(0, 0, 0);
  GA_STG_BC(0, 1, 0);
  GA_STG_BC(0, 2, 0);
  GA_STG_A(0, 1, 0);
  VM3();
  BAR();

  for (int tt = 0; tt < NT - 1; ++tt) {
    const int b = tt & 1, nb = b ^ 1;
    // P1: consumes Ah0,Bc01(t) [lag 4]; stages {Ah0,Bc0,Bc1}(t+1)
    GA_P1_LOADS(b);
    GA_STG_A(nb, 0, tt + 1);
    GA_STG_BC(nb, 0, tt + 1);
    GA_STG_BC(nb, 1, tt + 1);
    BAR(); LG0(); PRIO1(); GA_MFMA_N01(0); PRIO0();
    VM6();  // Bc2(t) landed; leaves Ah1(t)2 + new4 = 6
    BAR();
    // P2: consumes Bc2(t) [lag 4]; stages Bc2(t+1)
    GA_P2_LOADS(b);
    GA_STG_BC(nb, 2, tt + 1);
    BAR(); LG0(); PRIO1(); GA_MFMA_N2(0); PRIO0();
    VM5();  // Ah1(t) landed; leaves new4 + Bc2(t+1)1 = 5
    BAR();
    // P3: consumes Ah1(t) [lag 4]; stages Ah1(t+1)
    GA_P3_LOADS(b);
    GA_STG_A(nb, 1, tt + 1);
    BAR(); LG0(); PRIO1(); GA_MFMA_N01(4); PRIO0();
    BAR();
    // P4: regs only
    PRIO1(); GA_MFMA_N2(4); PRIO0();
    VM3();  // Ah0,Bc01(t+1) landed; leaves {Bc2,Ah1}(t+1) = 3
    BAR();
  }
  {  // last tile: entry in-flight {Bc2,Ah1}(L) = 3
    const int b = (NT - 1) & 1;
    GA_P1_LOADS(b);
    BAR(); LG0(); PRIO1(); GA_MFMA_N01(0); PRIO0();
    VM2();  // Bc2(L) landed
    BAR();
    GA_P2_LOADS(b);
    BAR(); LG0(); PRIO1(); GA_MFMA_N2(0); PRIO0();
    VM0();  // Ah1(L) landed
    BAR();
    GA_P3_LOADS(b);
    BAR(); LG0(); PRIO1(); GA_MFMA_N01(4); PRIO0();
    BAR();
    PRIO1(); GA_MFMA_N2(4); PRIO0();
  }

#pragma unroll
  for (int m = 0; m < 8; m++)
#pragma unroll
    for (int n = 0; n < 3; n++)
#pragma unroll
      for (int r = 0; r < 4; r++) {
        size_t row = bm * 256 + m * 32 + wr * 16 + l4 * 4 + r;
        size_t col = bn * 192 + n * 64 + wc * 16 + l15;
        Cout[row * N + col] = acc[m][n][r];
      }
#undef GA_STG_A
#undef GA_STG_BC
#undef GA_LDA
#undef GA_LDB
#undef GA_P1_LOADS
#undef GA_P2_LOADS
#undef GA_P3_LOADS
#undef GA_MFMA_N01
#undef GA_MFMA_N2
}

// ---------------- fused RMSNorm + RoPE + scale, in place on bf16 q/k ----------------
__global__ __launch_bounds__(128) void k_normrope(u16* __restrict__ qkv,
                                                  const int* __restrict__ pos_ids,
                                                  const float* __restrict__ qw,
                                                  const float* __restrict__ kw) {
  __shared__ float cross[2];
  int idx = blockIdx.x;
  int s = idx / 12, r = idx % 12;
  bool is_q = (r < 8);
  u16* p = qkv + (size_t)s * QKV_N + (is_q ? r * HD : 2048 + (r - 8) * HD);
  const float* w = is_q ? qw : kw;
  int j = threadIdx.x;  // 0..127
  float x1 = bf2f(p[j]), x2 = bf2f(p[j + 128]);
  float ss = x1 * x1 + x2 * x2;
#pragma unroll
  for (int off = 1; off < 64; off <<= 1) ss += __shfl_xor(ss, off);
  if ((threadIdx.x & 63) == 0) cross[threadIdx.x >> 6] = ss;
  __syncthreads();
  float rms = rsqrtf((cross[0] + cross[1]) * (1.0f / 256.0f) + 1e-6f);
  float y1 = x1 * rms * (1.0f + w[j]);
  float y2 = x2 * rms * (1.0f + w[j + 128]);
  float ang = (float)pos_ids[s] * exp2f((float)j * (-13.287712379549449f / 128.0f));
  float sn, c;
  sincosf(ang, &sn, &c);
  float sc = is_q ? QSCALE : 1.0f;
  p[j] = f2bf((y1 * c - y2 * sn) * sc);
  p[j + 128] = f2bf((y1 * sn + y2 * c) * sc);
}

// ---------------- flash attention v6: 64 q/block, GQA-shared K/V ----------------
__global__ __launch_bounds__(512, 2) void k_attn(const u16* __restrict__ qkv,
                                                 const u16* __restrict__ vt,
                                                 const int* __restrict__ pos_ids,
                                                 u16* __restrict__ aout) {
  __shared__ u16 lK[64 * 256];   // [key][d], rows 512B, swizzled
  __shared__ u16 lV[256 * 64];   // [d][key], rows 128B, swizzled
  __shared__ u16 lP[8][16 * 64]; // per-wave P, rows 128B, swizzled
  const int bid = blockIdx.x;    // 256 blocks
  const int wg = (bid & 7) * 32 + (bid >> 3);  // bijective XCD swizzle
  const int kvh = wg >> 6;                     // 0..3
  const int q0 = (wg & 63) * 64;               // 0..4032
  const int t = threadIdx.x, lane = t & 63, wave = t >> 6;
  const int l15 = lane & 15, l4 = lane >> 4;
  const int head = kvh * 2 + (wave >> 2);
  const int qw = q0 + (wave & 3) * 16;

  bf16x8 qfr[8];
  {
    const u16* qptr = qkv + (size_t)(qw + l15) * QKV_N + head * HD + l4 * 8;
#pragma unroll
    for (int kc = 0; kc < 8; kc++) qfr[kc] = *(const bf16x8*)(qptr + kc * 32);
  }
  f32x4 acc[16] = {};
  float mrow[4], lrow[4];
#pragma unroll
  for (int r = 0; r < 4; r++) { mrow[r] = -1e30f; lrow[r] = 0.0f; }
  int qi[4];
#pragma unroll
  for (int r = 0; r < 4; r++) qi[r] = pos_ids[qw + l4 * 4 + r];

  const int krw = lane >> 5, kcl = lane & 31;
  const int vrw = lane >> 3, vcl = lane & 7;
  const u16* kgb = qkv + 2048 + kvh * HD;
  const u16* vgb = vt + (size_t)kvh * HD * S_LEN;

  int start = q0 - (WIN - 1);
  if (start < 0) start = 0;
  start &= ~63;

#define STAGE_KV(T0) do {                                                             \
    _Pragma("unroll")                                                                 \
    for (int i_ = 0; i_ < 4; i_++) {                                                  \
      int ch_ = wave * 4 + i_;                                                        \
      int kr_ = ch_ * 2 + krw;                                                        \
      gld16(kgb + (size_t)((T0) + kr_) * QKV_N + ((kcl ^ (kr_ & 7)) * 8),             \
            &lK[ch_ * 512]);                                                          \
      int vr_ = ch_ * 8 + vrw;                                                        \
      gld16(vgb + (size_t)vr_ * S_LEN + (T0) + ((vcl ^ (vr_ & 7)) * 8),               \
            &lV[ch_ * 512]);                                                          \
    }                                                                                 \
  } while (0)

  for (int t0 = start; t0 <= q0 + 63; t0 += 64) {
    STAGE_KV(t0);
    int kp[4];
#pragma unroll
    for (int kb = 0; kb < 4; kb++) kp[kb] = pos_ids[t0 + kb * 16 + l15];
    __syncthreads();
    f32x4 sv[4] = {};
    PRIO1();
#pragma unroll
    for (int kb = 0; kb < 4; kb++) {
      const char* krow = (const char*)&lK[(kb * 16 + l15) * 256];
      const int sw = ((kb * 16 + l15) & 7) << 4;
#pragma unroll
      for (int kc = 0; kc < 8; kc++) {
        bf16x8 kf = *(const bf16x8*)(krow + ((kc * 64 + l4 * 16) ^ sw));
        sv[kb] = __builtin_amdgcn_mfma_f32_16x16x32_bf16(qfr[kc], kf, sv[kb], 0, 0, 0);
      }
    }
    PRIO0();
    float sloc[4][4], mx[4];
    float need = 0.0f;
#pragma unroll
    for (int r = 0; r < 4; r++) {
      int pi = qi[r];
#pragma unroll
      for (int kb = 0; kb < 4; kb++)
        sloc[r][kb] = ((kp[kb] <= pi) && (pi - kp[kb] < WIN)) ? sv[kb][r] : -__builtin_inff();
      float m_ = fmaxf(fmaxf(sloc[r][0], sloc[r][1]), fmaxf(sloc[r][2], sloc[r][3]));
#pragma unroll
      for (int off = 1; off < 16; off <<= 1) m_ = fmaxf(m_, __shfl_xor(m_, off));
      mx[r] = m_;
      need = fmaxf(need, m_ - mrow[r]);
    }
    bool resc = __any(need > 8.0f);
    if (resc) {
#pragma unroll
      for (int r = 0; r < 4; r++) {
        float nm = fmaxf(mrow[r], mx[r]);
        float al = __expf(mrow[r] - nm);
        mrow[r] = nm;
        lrow[r] *= al;
#pragma unroll
        for (int nd = 0; nd < 16; nd++) acc[nd][r] *= al;
      }
    }
#pragma unroll
    for (int r = 0; r < 4; r++) {
      float nm = mrow[r];
      float e0 = __expf(sloc[r][0] - nm), e1 = __expf(sloc[r][1] - nm);
      float e2 = __expf(sloc[r][2] - nm), e3 = __expf(sloc[r][3] - nm);
      float sum = (e0 + e1) + (e2 + e3);
#pragma unroll
      for (int off = 1; off < 16; off <<= 1) sum += __shfl_xor(sum, off);
      lrow[r] += sum;
      int q = l4 * 4 + r;
      char* lpw = (char*)&lP[wave][0] + q * 128;
      int swp = (q & 7) << 4;
      *(u16*)(lpw + ((l15 * 2) ^ swp)) = f2bf(e0);
      *(u16*)(lpw + ((32 + l15 * 2) ^ swp)) = f2bf(e1);
      *(u16*)(lpw + ((64 + l15 * 2) ^ swp)) = f2bf(e2);
      *(u16*)(lpw + ((96 + l15 * 2) ^ swp)) = f2bf(e3);
    }
#pragma unroll
    for (int kc2 = 0; kc2 < 2; kc2++) {
      int q = l15;
      bf16x8 pa = *(const bf16x8*)((const char*)&lP[wave][0] + q * 128 +
                                   ((kc2 * 64 + l4 * 16) ^ ((q & 7) << 4)));
      PRIO1();
#pragma unroll
      for (int nd = 0; nd < 16; nd++) {
        int d = nd * 16 + l15;
        bf16x8 vf = *(const bf16x8*)((const char*)&lV[d * 64] +
                                     ((kc2 * 64 + l4 * 16) ^ ((d & 7) << 4)));
        acc[nd] = __builtin_amdgcn_mfma_f32_16x16x32_bf16(pa, vf, acc[nd], 0, 0, 0);
      }
      PRIO0();
    }
    __syncthreads();
  }
  float rinv[4];
#pragma unroll
  for (int r = 0; r < 4; r++) rinv[r] = 1.0f / lrow[r];
#pragma unroll
  for (int nd = 0; nd < 16; nd++)
#pragma unroll
    for (int r = 0; r < 4; r++) {
      size_t row = qw + l4 * 4 + r;
      aout[row * AO_N + head * HD + nd * 16 + l15] = f2bf(acc[nd][r] * rinv[r]);
    }
#undef STAGE_KV
}

extern "C" void kernel_launch(void* const* d_in, const int* in_sizes, int n_in,
                              void* d_out, int out_size, void* d_ws, size_t ws_size,
                              hipStream_t stream) {
  const float* x = (const float*)d_in[0];
  const int* pos = (const int*)d_in[1];
  const float* wq = (const float*)d_in[2];
  const float* wk = (const float*)d_in[3];
  const float* wv = (const float*)d_in[4];
  const float* wo = (const float*)d_in[5];
  const float* qnw = (const float*)d_in[6];
  const float* knw = (const float*)d_in[7];

  // scratch layout:
  //   d_out: qkv bf16 [4096][4096] (overwritten by final fp32 GEMM)
  //   ws+0        : x bf16 [4096][2304]; later aout bf16 [4096][2048]
  //   ws+18874368 : W^T bf16 (qkv-phase: [4096][2304]; out-phase: wo^T [2304][2048])
  //   ws+28311552 : vt bf16 [4][256][4096]
  u16* qkv = (u16*)d_out;
  u16* xbf = (u16*)d_ws;
  u16* wT = (u16*)((char*)d_ws + 18874368);
  u16* vtb = (u16*)((char*)d_ws + 28311552);
  u16* aout = xbf;

  k_cvt_bf16<<<9216, 256, 0, stream>>>(x, xbf, S_LEN * HID_DIM);
  k_transpose_w<<<dim3(128, 72), 256, 0, stream>>>(wq, wk, wv, wT);
  k_gemm8p<1><<<dim3(256), 512, 0, stream>>>(xbf, wT, qkv, S_LEN, QKV_N, HID_DIM);
  k_vtrans<<<dim3(32, 128), 256, 0, stream>>>(qkv, vtb);
  k_normrope<<<S_LEN * 12, 128, 0, stream>>>(qkv, pos, qnw, knw);
  k_transpose_cvt<<<dim3(72, 64), 256, 0, stream>>>(wo, HID_DIM, wT, 2048, 0);
  k_attn<<<dim3(256), 512, 0, stream>>>(qkv, vtb, pos, aout);
  k_gemm192<<<dim3(192), 512, 0, stream>>>(aout, wT, (float*)d_out, S_LEN, HID_DIM, 2048);
}

// Round 12
// 243.244 us; speedup vs baseline: 1.2567x; 1.0253x over previous
//
#include <hip/hip_runtime.h>
#include <stdint.h>

typedef unsigned short u16;
typedef __attribute__((ext_vector_type(8))) short bf16x8;
typedef __attribute__((ext_vector_type(4))) float f32x4;

#define S_LEN 4096
#define HID_DIM 2304
#define QKV_N 4096
#define AO_N 2048
#define HD 256
#define WIN 1024
#define QSCALE 0.0625f

static __device__ __forceinline__ u16 f2bf(float f) {
  union { float f; uint32_t u; } v; v.f = f;
  return (u16)((v.u + 0x7FFFu + ((v.u >> 16) & 1u)) >> 16);
}
static __device__ __forceinline__ float bf2f(u16 h) {
  union { uint32_t u; float f; } v; v.u = ((uint32_t)h) << 16;
  return v.f;
}

static __device__ __forceinline__ void gld16(const void* src, void* dst) {
  __builtin_amdgcn_global_load_lds((const __attribute__((address_space(1))) void*)src,
                                   (__attribute__((address_space(3))) void*)dst, 16, 0, 0);
}

#define BAR() __builtin_amdgcn_s_barrier()
#define LG0() asm volatile("s_waitcnt lgkmcnt(0)" ::: "memory")
#define VM6() asm volatile("s_waitcnt vmcnt(6)" ::: "memory")
#define VM5() asm volatile("s_waitcnt vmcnt(5)" ::: "memory")
#define VM4() asm volatile("s_waitcnt vmcnt(4)" ::: "memory")
#define VM3() asm volatile("s_waitcnt vmcnt(3)" ::: "memory")
#define VM2() asm volatile("s_waitcnt vmcnt(2)" ::: "memory")
#define VM0() asm volatile("s_waitcnt vmcnt(0)" ::: "memory")
#define PRIO1() __builtin_amdgcn_s_setprio(1)
#define PRIO0() __builtin_amdgcn_s_setprio(0)

// ---------------- fp32 -> bf16 elementwise ----------------
__global__ __launch_bounds__(256) void k_cvt_bf16(const float* __restrict__ in,
                                                  u16* __restrict__ out, int n) {
  int i = (blockIdx.x * 256 + threadIdx.x) * 4;
  if (i >= n) return;
  float4 v = *(const float4*)(in + i);
  uint64_t p = (uint64_t)f2bf(v.x) | ((uint64_t)f2bf(v.y) << 16)
             | ((uint64_t)f2bf(v.z) << 32) | ((uint64_t)f2bf(v.w) << 48);
  *(uint64_t*)(out + i) = p;
}

// in: fp32 [R][C] row-major; out bf16: out[(row_off + c)*out_stride + r] = in[r][c]
__global__ __launch_bounds__(256) void k_transpose_cvt(const float* __restrict__ in, int C,
                                                       u16* __restrict__ out, int out_stride,
                                                       int row_off) {
  __shared__ float tile[32][33];
  int c0 = blockIdx.x * 32, r0 = blockIdx.y * 32;
  int tx = threadIdx.x & 31, ty = threadIdx.x >> 5;
#pragma unroll
  for (int i = 0; i < 4; i++)
    tile[ty + i * 8][tx] = in[(size_t)(r0 + ty + i * 8) * C + c0 + tx];
  __syncthreads();
#pragma unroll
  for (int i = 0; i < 4; i++)
    out[(size_t)(row_off + c0 + ty + i * 8) * out_stride + r0 + tx] = f2bf(tile[tx][ty + i * 8]);
}

// ---------------- merged wq/wk/wv transpose-convert into stacked wT [4096][2304] ---------
__global__ __launch_bounds__(256) void k_transpose_w(const float* __restrict__ wq,
                                                     const float* __restrict__ wk,
                                                     const float* __restrict__ wv,
                                                     u16* __restrict__ out) {
  int ct = blockIdx.x;       // 0..127 -> out rows ct*32..+31
  int r0 = blockIdx.y * 32;  // over 2304
  const float* src;
  int C, c0;
  if (ct < 64) {
    src = wq; C = 2048; c0 = ct * 32;
  } else if (ct < 96) {
    src = wk; C = 1024; c0 = (ct - 64) * 32;
  } else {
    src = wv; C = 1024; c0 = (ct - 96) * 32;
  }
  __shared__ float tile[32][33];
  int tx = threadIdx.x & 31, ty = threadIdx.x >> 5;
#pragma unroll
  for (int i = 0; i < 4; i++)
    tile[ty + i * 8][tx] = src[(size_t)(r0 + ty + i * 8) * C + c0 + tx];
  __syncthreads();
#pragma unroll
  for (int i = 0; i < 4; i++)
    out[(size_t)(ct * 32 + ty + i * 8) * HID_DIM + r0 + tx] = f2bf(tile[tx][ty + i * 8]);
}

// ---------------- bf16 transpose of V block of qkv -> vt[kv*256 + d][s] ----------------
__global__ __launch_bounds__(256) void k_vtrans(const u16* __restrict__ qkv,
                                                u16* __restrict__ vtout) {
  __shared__ u16 tile[32][33];
  int c0 = blockIdx.x * 32, s0 = blockIdx.y * 32;
  int tx = threadIdx.x & 31, ty = threadIdx.x >> 5;
#pragma unroll
  for (int i = 0; i < 4; i++)
    tile[ty + i * 8][tx] = qkv[(size_t)(s0 + ty + i * 8) * QKV_N + 3072 + c0 + tx];
  __syncthreads();
#pragma unroll
  for (int i = 0; i < 4; i++)
    vtout[(size_t)(c0 + ty + i * 8) * S_LEN + s0 + tx] = tile[tx][ty + i * 8];
}

// ---------------- bf16 GEMM: 256x256, BK=64, 4-phase, uniform lag-4 staging -------------
template <int OUT_BF16>
__global__ __launch_bounds__(512, 2) void k_gemm8p(const u16* __restrict__ A,
                                                   const u16* __restrict__ Bt,
                                                   void* __restrict__ Cout,
                                                   int M, int N, int K) {
  __shared__ u16 sA[2][256 * 64];
  __shared__ u16 sB[2][256 * 64];
  const int t = threadIdx.x, lane = t & 63, wave = t >> 6;
  const int wr = wave >> 2, wc = wave & 3;
  const int l15 = lane & 15, l4 = lane >> 4;
  const int nbn = N >> 8;
  const int cpx = gridDim.x >> 3;
  const int wg = ((int)blockIdx.x & 7) * cpx + ((int)blockIdx.x >> 3);  // bijective XCD swz
  const int bm = wg / nbn, bn = wg % nbn;
  const int NT = K >> 6;
  const int srow = lane >> 3;
  const int sslot = ((lane & 7) ^ srow) * 8;
  const u16* Abase = A + (size_t)(bm * 256) * K;
  const u16* Bbase = Bt + (size_t)(bn * 256) * K;
  f32x4 acc[8][4] = {};
  bf16x8 aF[4][2], b01[2][2], b23[2][2];

#define STG_A(BUF, HALF, KT) do {                                                 \
    _Pragma("unroll")                                                             \
    for (int c_ = 0; c_ < 2; c_++) {                                              \
      int rb_ = (HALF) * 128 + (wave * 2 + c_) * 8;                               \
      gld16(Abase + (size_t)(rb_ + srow) * K + ((KT) << 6) + sslot,               \
            &sA[BUF][rb_ * 64]);                                                  \
    }                                                                             \
  } while (0)
#define STG_B(BUF, HALF, KT) do {                                                 \
    _Pragma("unroll")                                                             \
    for (int c_ = 0; c_ < 2; c_++) {                                              \
      int rb_ = (HALF) * 128 + (wave * 2 + c_) * 8;                               \
      gld16(Bbase + (size_t)(rb_ + srow) * K + ((KT) << 6) + sslot,               \
            &sB[BUF][rb_ * 64]);                                                  \
    }                                                                             \
  } while (0)
#define LDA(BUF, M_, KK)                                                          \
  (*(const bf16x8*)&sA[BUF][((M_) * 32 + wr * 16 + l15) * 64 +                    \
                            ((((KK) << 2) + l4) ^ (l15 & 7)) * 8])
#define LDB(BUF, N_, KK)                                                          \
  (*(const bf16x8*)&sB[BUF][((N_) * 64 + wc * 16 + l15) * 64 +                    \
                            ((((KK) << 2) + l4) ^ (l15 & 7)) * 8])

#define P1_LOADS(b_) do {                                                         \
    _Pragma("unroll") for (int m_ = 0; m_ < 4; m_++)                              \
      _Pragma("unroll") for (int k_ = 0; k_ < 2; k_++)                            \
        aF[m_][k_] = LDA(b_, m_, k_);                                             \
    _Pragma("unroll") for (int n_ = 0; n_ < 2; n_++)                              \
      _Pragma("unroll") for (int k_ = 0; k_ < 2; k_++)                            \
        b01[n_][k_] = LDB(b_, n_, k_);                                            \
  } while (0)
#define P2_LOADS(b_) do {                                                         \
    _Pragma("unroll") for (int n_ = 0; n_ < 2; n_++)                              \
      _Pragma("unroll") for (int k_ = 0; k_ < 2; k_++)                            \
        b23[n_][k_] = LDB(b_, n_ + 2, k_);                                        \
  } while (0)
#define P3_LOADS(b_) do {                                                         \
    _Pragma("unroll") for (int m_ = 0; m_ < 4; m_++)                              \
      _Pragma("unroll") for (int k_ = 0; k_ < 2; k_++)                            \
        aF[m_][k_] = LDA(b_, m_ + 4, k_);                                         \
  } while (0)
#define MFMA16(MOFF, NOFF, BREG) do {                                             \
    _Pragma("unroll") for (int m_ = 0; m_ < 4; m_++)                              \
      _Pragma("unroll") for (int n_ = 0; n_ < 2; n_++)                            \
        _Pragma("unroll") for (int k_ = 0; k_ < 2; k_++)                          \
          acc[m_ + MOFF][n_ + NOFF] = __builtin_amdgcn_mfma_f32_16x16x32_bf16(    \
              aF[m_][k_], BREG[n_][k_], acc[m_ + MOFF][n_ + NOFF], 0, 0, 0);      \
  } while (0)

  // prologue: stage tile 0 in consumption order; leaves {Bh1,Ah1} (4) in flight
  STG_A(0, 0, 0);
  STG_B(0, 0, 0);
  STG_B(0, 1, 0);
  STG_A(0, 1, 0);
  VM4();
  BAR();

  for (int tt = 0; tt < NT - 1; ++tt) {
    const int b = tt & 1, nb = b ^ 1;
    // P1: consumes Ah0,Bh0(t) [staged P1(t-1), lag 4]; stages {Ah0,Bh0}(t+1)
    P1_LOADS(b);
    STG_A(nb, 0, tt + 1);
    STG_B(nb, 0, tt + 1);
    BAR(); LG0(); PRIO1(); MFMA16(0, 0, b01); PRIO0();
    VM6();  // Bh1(t) landed for P2; leaves Ah1(t)+AhBh0(t+1) = 6
    BAR();
    // P2: consumes Bh1(t) [lag 4]; stages Bh1(t+1)
    P2_LOADS(b);
    STG_B(nb, 1, tt + 1);
    BAR(); LG0(); PRIO1(); MFMA16(0, 2, b23); PRIO0();
    VM6();  // Ah1(t) landed for P3; leaves AhBh0+Bh1(t+1) = 6
    BAR();
    // P3: consumes Ah1(t) [lag 4]; stages Ah1(t+1)
    P3_LOADS(b);
    STG_A(nb, 1, tt + 1);
    BAR(); LG0(); PRIO1(); MFMA16(4, 0, b01); PRIO0();
    BAR();
    // P4: regs only
    PRIO1(); MFMA16(4, 2, b23); PRIO0();
    VM4();  // Ah0,Bh0(t+1) landed for next P1; leaves {Bh1,Ah1}(t+1) = 4
    BAR();
  }
  {  // last tile: entry in-flight {Bh1,Ah1}(L) = 4; drain with counted waits
    const int b = (NT - 1) & 1;
    P1_LOADS(b);
    BAR(); LG0(); PRIO1(); MFMA16(0, 0, b01); PRIO0();
    VM2();  // Bh1(L) landed
    BAR();
    P2_LOADS(b);
    BAR(); LG0(); PRIO1(); MFMA16(0, 2, b23); PRIO0();
    VM0();  // Ah1(L) landed
    BAR();
    P3_LOADS(b);
    BAR(); LG0(); PRIO1(); MFMA16(4, 0, b01); PRIO0();
    BAR();
    PRIO1(); MFMA16(4, 2, b23); PRIO0();
  }

#pragma unroll
  for (int m = 0; m < 8; m++)
#pragma unroll
    for (int n = 0; n < 4; n++)
#pragma unroll
      for (int r = 0; r < 4; r++) {
        size_t row = bm * 256 + m * 32 + wr * 16 + l4 * 4 + r;
        size_t col = bn * 256 + n * 64 + wc * 16 + l15;
        if (OUT_BF16)
          ((u16*)Cout)[row * N + col] = f2bf(acc[m][n][r]);
        else
          ((float*)Cout)[row * N + col] = acc[m][n][r];
      }
#undef STG_A
#undef STG_B
#undef LDA
#undef LDB
#undef P1_LOADS
#undef P2_LOADS
#undef P3_LOADS
#undef MFMA16
}

// ---------------- bf16 GEMM 256x192 (out-proj): 4-phase, uniform lag-4 staging ----------
__global__ __launch_bounds__(512, 2) void k_gemm192(const u16* __restrict__ A,
                                                    const u16* __restrict__ Bt,
                                                    float* __restrict__ Cout,
                                                    int M, int N, int K) {
  __shared__ u16 sA[2][256 * 64];
  __shared__ u16 sB[2][192 * 64];
  const int t = threadIdx.x, lane = t & 63, wave = t >> 6;
  const int wr = wave >> 2, wc = wave & 3;
  const int l15 = lane & 15, l4 = lane >> 4;
  const int nbn = N / 192;  // 12
  const int cpx = gridDim.x >> 3;
  const int wg = ((int)blockIdx.x & 7) * cpx + ((int)blockIdx.x >> 3);
  const int bm = wg / nbn, bn = wg % nbn;
  const int NT = K >> 6;
  const int srow = lane >> 3;
  const int sslot = ((lane & 7) ^ srow) * 8;
  const u16* Abase = A + (size_t)(bm * 256) * K;
  const u16* Bbase = Bt + (size_t)(bn * 192) * K;
  f32x4 acc[8][3] = {};
  bf16x8 aF[4][2], b01[2][2], b2[2];

#define GA_STG_A(BUF, HALF, KT) do {                                              \
    _Pragma("unroll")                                                             \
    for (int c_ = 0; c_ < 2; c_++) {                                              \
      int rb_ = (HALF) * 128 + (wave * 2 + c_) * 8;                               \
      gld16(Abase + (size_t)(rb_ + srow) * K + ((KT) << 6) + sslot,               \
            &sA[BUF][rb_ * 64]);                                                  \
    }                                                                             \
  } while (0)
#define GA_STG_BC(BUF, CH, KT) do {                                               \
    int rb_ = (CH) * 64 + wave * 8;                                               \
    gld16(Bbase + (size_t)(rb_ + srow) * K + ((KT) << 6) + sslot,                 \
          &sB[BUF][rb_ * 64]);                                                    \
  } while (0)
#define GA_LDA(BUF, M_, KK)                                                       \
  (*(const bf16x8*)&sA[BUF][((M_) * 32 + wr * 16 + l15) * 64 +                    \
                            ((((KK) << 2) + l4) ^ (l15 & 7)) * 8])
#define GA_LDB(BUF, N_, KK)                                                       \
  (*(const bf16x8*)&sB[BUF][((N_) * 64 + wc * 16 + l15) * 64 +                    \
                            ((((KK) << 2) + l4) ^ (l15 & 7)) * 8])
#define GA_P1_LOADS(b_) do {                                                      \
    _Pragma("unroll") for (int m_ = 0; m_ < 4; m_++)                              \
      _Pragma("unroll") for (int k_ = 0; k_ < 2; k_++)                            \
        aF[m_][k_] = GA_LDA(b_, m_, k_);                                          \
    _Pragma("unroll") for (int n_ = 0; n_ < 2; n_++)                              \
      _Pragma("unroll") for (int k_ = 0; k_ < 2; k_++)                            \
        b01[n_][k_] = GA_LDB(b_, n_, k_);                                         \
  } while (0)
#define GA_P2_LOADS(b_) do {                                                      \
    _Pragma("unroll") for (int k_ = 0; k_ < 2; k_++)                              \
      b2[k_] = GA_LDB(b_, 2, k_);                                                 \
  } while (0)
#define GA_P3_LOADS(b_) do {                                                      \
    _Pragma("unroll") for (int m_ = 0; m_ < 4; m_++)                              \
      _Pragma("unroll") for (int k_ = 0; k_ < 2; k_++)                            \
        aF[m_][k_] = GA_LDA(b_, m_ + 4, k_);                                      \
  } while (0)
#define GA_MFMA_N01(MOFF) do {                                                    \
    _Pragma("unroll") for (int m_ = 0; m_ < 4; m_++)                              \
      _Pragma("unroll") for (int n_ = 0; n_ < 2; n_++)                            \
        _Pragma("unroll") for (int k_ = 0; k_ < 2; k_++)                          \
          acc[m_ + MOFF][n_] = __builtin_amdgcn_mfma_f32_16x16x32_bf16(           \
              aF[m_][k_], b01[n_][k_], acc[m_ + MOFF][n_], 0, 0, 0);              \
  } while (0)
#define GA_MFMA_N2(MOFF) do {                                                     \
    _Pragma("unroll") for (int m_ = 0; m_ < 4; m_++)                              \
      _Pragma("unroll") for (int k_ = 0; k_ < 2; k_++)                            \
        acc[m_ + MOFF][2] = __builtin_amdgcn_mfma_f32_16x16x32_bf16(              \
            aF[m_][k_], b2[k_], acc[m_ + MOFF][2], 0, 0, 0);                      \
  } while (0)

  // prologue: stage tile 0 in consumption order; leaves {Bc2,Ah1} (3) in flight
  GA_STG_A(0, 0, 0);
  GA_STG_BC(0, 0, 0);
  GA_STG_BC(0, 1, 0);
  GA_STG_BC(0, 2, 0);
  GA_STG_A(0, 1, 0);
  VM3();
  BAR();

  for (int tt = 0; tt < NT - 1; ++tt) {
    const int b = tt & 1, nb = b ^ 1;
    GA_P1_LOADS(b);
    GA_STG_A(nb, 0, tt + 1);
    GA_STG_BC(nb, 0, tt + 1);
    GA_STG_BC(nb, 1, tt + 1);
    BAR(); LG0(); PRIO1(); GA_MFMA_N01(0); PRIO0();
    VM6();
    BAR();
    GA_P2_LOADS(b);
    GA_STG_BC(nb, 2, tt + 1);
    BAR(); LG0(); PRIO1(); GA_MFMA_N2(0); PRIO0();
    VM5();
    BAR();
    GA_P3_LOADS(b);
    GA_STG_A(nb, 1, tt + 1);
    BAR(); LG0(); PRIO1(); GA_MFMA_N01(4); PRIO0();
    BAR();
    PRIO1(); GA_MFMA_N2(4); PRIO0();
    VM3();
    BAR();
  }
  {
    const int b = (NT - 1) & 1;
    GA_P1_LOADS(b);
    BAR(); LG0(); PRIO1(); GA_MFMA_N01(0); PRIO0();
    VM2();
    BAR();
    GA_P2_LOADS(b);
    BAR(); LG0(); PRIO1(); GA_MFMA_N2(0); PRIO0();
    VM0();
    BAR();
    GA_P3_LOADS(b);
    BAR(); LG0(); PRIO1(); GA_MFMA_N01(4); PRIO0();
    BAR();
    PRIO1(); GA_MFMA_N2(4); PRIO0();
  }

#pragma unroll
  for (int m = 0; m < 8; m++)
#pragma unroll
    for (int n = 0; n < 3; n++)
#pragma unroll
      for (int r = 0; r < 4; r++) {
        size_t row = bm * 256 + m * 32 + wr * 16 + l4 * 4 + r;
        size_t col = bn * 192 + n * 64 + wc * 16 + l15;
        Cout[row * N + col] = acc[m][n][r];
      }
#undef GA_STG_A
#undef GA_STG_BC
#undef GA_LDA
#undef GA_LDB
#undef GA_P1_LOADS
#undef GA_P2_LOADS
#undef GA_P3_LOADS
#undef GA_MFMA_N01
#undef GA_MFMA_N2
}

// ---------------- fused RMSNorm + RoPE + scale, in place on bf16 q/k ----------------
__global__ __launch_bounds__(128) void k_normrope(u16* __restrict__ qkv,
                                                  const int* __restrict__ pos_ids,
                                                  const float* __restrict__ qw,
                                                  const float* __restrict__ kw) {
  __shared__ float cross[2];
  int idx = blockIdx.x;
  int s = idx / 12, r = idx % 12;
  bool is_q = (r < 8);
  u16* p = qkv + (size_t)s * QKV_N + (is_q ? r * HD : 2048 + (r - 8) * HD);
  const float* w = is_q ? qw : kw;
  int j = threadIdx.x;  // 0..127
  float x1 = bf2f(p[j]), x2 = bf2f(p[j + 128]);
  float ss = x1 * x1 + x2 * x2;
#pragma unroll
  for (int off = 1; off < 64; off <<= 1) ss += __shfl_xor(ss, off);
  if ((threadIdx.x & 63) == 0) cross[threadIdx.x >> 6] = ss;
  __syncthreads();
  float rms = rsqrtf((cross[0] + cross[1]) * (1.0f / 256.0f) + 1e-6f);
  float y1 = x1 * rms * (1.0f + w[j]);
  float y2 = x2 * rms * (1.0f + w[j + 128]);
  float ang = (float)pos_ids[s] * exp2f((float)j * (-13.287712379549449f / 128.0f));
  float sn, c;
  sincosf(ang, &sn, &c);
  float sc = is_q ? QSCALE : 1.0f;
  p[j] = f2bf((y1 * c - y2 * sn) * sc);
  p[j + 128] = f2bf((y1 * sn + y2 * c) * sc);
}

// ---------------- flash attention v7: 64 q/block, GQA-shared, DOUBLE-BUFFERED K/V -------
// R12: lK/lV doubled (144KB LDS, still 1 block/CU at grid 256). Per tile: stage(next ->
// buf^1) at TOP, compute on buf, syncthreads at bottom (vmcnt drain lands after a full
// tile of compute -> HBM latency hidden; was serially exposed in the single-buffer form).
__global__ __launch_bounds__(512, 2) void k_attn(const u16* __restrict__ qkv,
                                                 const u16* __restrict__ vt,
                                                 const int* __restrict__ pos_ids,
                                                 u16* __restrict__ aout) {
  __shared__ u16 lK[2][64 * 256];  // [key][d], rows 512B, swizzled
  __shared__ u16 lV[2][256 * 64];  // [d][key], rows 128B, swizzled
  __shared__ u16 lP[8][16 * 64];   // per-wave P, rows 128B, swizzled
  const int bid = blockIdx.x;      // 256 blocks
  const int wg = (bid & 7) * 32 + (bid >> 3);  // bijective XCD swizzle
  const int kvh = wg >> 6;                     // 0..3
  const int q0 = (wg & 63) * 64;               // 0..4032
  const int t = threadIdx.x, lane = t & 63, wave = t >> 6;
  const int l15 = lane & 15, l4 = lane >> 4;
  const int head = kvh * 2 + (wave >> 2);
  const int qw = q0 + (wave & 3) * 16;

  bf16x8 qfr[8];
  {
    const u16* qptr = qkv + (size_t)(qw + l15) * QKV_N + head * HD + l4 * 8;
#pragma unroll
    for (int kc = 0; kc < 8; kc++) qfr[kc] = *(const bf16x8*)(qptr + kc * 32);
  }
  f32x4 acc[16] = {};
  float mrow[4], lrow[4];
#pragma unroll
  for (int r = 0; r < 4; r++) { mrow[r] = -1e30f; lrow[r] = 0.0f; }
  int qi[4];
#pragma unroll
  for (int r = 0; r < 4; r++) qi[r] = pos_ids[qw + l4 * 4 + r];

  // staging: K chunk=1KB=2 rows x 512B; V chunk=1KB=8 rows x 128B; 4 of each per wave
  const int krw = lane >> 5, kcl = lane & 31;
  const int vrw = lane >> 3, vcl = lane & 7;
  const u16* kgb = qkv + 2048 + kvh * HD;
  const u16* vgb = vt + (size_t)kvh * HD * S_LEN;

  int start = q0 - (WIN - 1);
  if (start < 0) start = 0;
  start &= ~63;

#define STAGE_KV(B, T0) do {                                                          \
    _Pragma("unroll")                                                                 \
    for (int i_ = 0; i_ < 4; i_++) {                                                  \
      int ch_ = wave * 4 + i_;                                                        \
      int kr_ = ch_ * 2 + krw;                                                        \
      gld16(kgb + (size_t)((T0) + kr_) * QKV_N + ((kcl ^ (kr_ & 7)) * 8),             \
            &lK[B][ch_ * 512]);                                                       \
      int vr_ = ch_ * 8 + vrw;                                                        \
      gld16(vgb + (size_t)vr_ * S_LEN + (T0) + ((vcl ^ (vr_ & 7)) * 8),               \
            &lV[B][ch_ * 512]);                                                       \
    }                                                                                 \
  } while (0)

  STAGE_KV(0, start);
  __syncthreads();  // drain prologue stage
  int buf = 0;
  for (int t0 = start; t0 <= q0 + 63; t0 += 64) {
    if (t0 + 64 <= q0 + 63) STAGE_KV(buf ^ 1, t0 + 64);  // latency hides under compute
    int kp[4];
#pragma unroll
    for (int kb = 0; kb < 4; kb++) kp[kb] = pos_ids[t0 + kb * 16 + l15];
    f32x4 sv[4] = {};
    PRIO1();
#pragma unroll
    for (int kb = 0; kb < 4; kb++) {
      const char* krow = (const char*)&lK[buf][(kb * 16 + l15) * 256];
      const int sw = ((kb * 16 + l15) & 7) << 4;
#pragma unroll
      for (int kc = 0; kc < 8; kc++) {
        bf16x8 kf = *(const bf16x8*)(krow + ((kc * 64 + l4 * 16) ^ sw));
        sv[kb] = __builtin_amdgcn_mfma_f32_16x16x32_bf16(qfr[kc], kf, sv[kb], 0, 0, 0);
      }
    }
    PRIO0();
    float sloc[4][4], mx[4];
    float need = 0.0f;
#pragma unroll
    for (int r = 0; r < 4; r++) {
      int pi = qi[r];
#pragma unroll
      for (int kb = 0; kb < 4; kb++)
        sloc[r][kb] = ((kp[kb] <= pi) && (pi - kp[kb] < WIN)) ? sv[kb][r] : -__builtin_inff();
      float m_ = fmaxf(fmaxf(sloc[r][0], sloc[r][1]), fmaxf(sloc[r][2], sloc[r][3]));
#pragma unroll
      for (int off = 1; off < 16; off <<= 1) m_ = fmaxf(m_, __shfl_xor(m_, off));
      mx[r] = m_;
      need = fmaxf(need, m_ - mrow[r]);
    }
    bool resc = __any(need > 8.0f);
    if (resc) {
#pragma unroll
      for (int r = 0; r < 4; r++) {
        float nm = fmaxf(mrow[r], mx[r]);
        float al = __expf(mrow[r] - nm);
        mrow[r] = nm;
        lrow[r] *= al;
#pragma unroll
        for (int nd = 0; nd < 16; nd++) acc[nd][r] *= al;
      }
    }
#pragma unroll
    for (int r = 0; r < 4; r++) {
      float nm = mrow[r];
      float e0 = __expf(sloc[r][0] - nm), e1 = __expf(sloc[r][1] - nm);
      float e2 = __expf(sloc[r][2] - nm), e3 = __expf(sloc[r][3] - nm);
      float sum = (e0 + e1) + (e2 + e3);
#pragma unroll
      for (int off = 1; off < 16; off <<= 1) sum += __shfl_xor(sum, off);
      lrow[r] += sum;
      int q = l4 * 4 + r;
      char* lpw = (char*)&lP[wave][0] + q * 128;
      int swp = (q & 7) << 4;
      *(u16*)(lpw + ((l15 * 2) ^ swp)) = f2bf(e0);
      *(u16*)(lpw + ((32 + l15 * 2) ^ swp)) = f2bf(e1);
      *(u16*)(lpw + ((64 + l15 * 2) ^ swp)) = f2bf(e2);
      *(u16*)(lpw + ((96 + l15 * 2) ^ swp)) = f2bf(e3);
    }
#pragma unroll
    for (int kc2 = 0; kc2 < 2; kc2++) {
      int q = l15;
      bf16x8 pa = *(const bf16x8*)((const char*)&lP[wave][0] + q * 128 +
                                   ((kc2 * 64 + l4 * 16) ^ ((q & 7) << 4)));
      PRIO1();
#pragma unroll
      for (int nd = 0; nd < 16; nd++) {
        int d = nd * 16 + l15;
        bf16x8 vf = *(const bf16x8*)((const char*)&lV[buf][d * 64] +
                                     ((kc2 * 64 + l4 * 16) ^ ((d & 7) << 4)));
        acc[nd] = __builtin_amdgcn_mfma_f32_16x16x32_bf16(pa, vf, acc[nd], 0, 0, 0);
      }
      PRIO0();
    }
    __syncthreads();  // next-tile stage landed + all reads of buf done
    buf ^= 1;
  }
  float rinv[4];
#pragma unroll
  for (int r = 0; r < 4; r++) rinv[r] = 1.0f / lrow[r];
#pragma unroll
  for (int nd = 0; nd < 16; nd++)
#pragma unroll
    for (int r = 0; r < 4; r++) {
      size_t row = qw + l4 * 4 + r;
      aout[row * AO_N + head * HD + nd * 16 + l15] = f2bf(acc[nd][r] * rinv[r]);
    }
#undef STAGE_KV
}

extern "C" void kernel_launch(void* const* d_in, const int* in_sizes, int n_in,
                              void* d_out, int out_size, void* d_ws, size_t ws_size,
                              hipStream_t stream) {
  const float* x = (const float*)d_in[0];
  const int* pos = (const int*)d_in[1];
  const float* wq = (const float*)d_in[2];
  const float* wk = (const float*)d_in[3];
  const float* wv = (const float*)d_in[4];
  const float* wo = (const float*)d_in[5];
  const float* qnw = (const float*)d_in[6];
  const float* knw = (const float*)d_in[7];

  // scratch layout:
  //   d_out: qkv bf16 [4096][4096] (overwritten by final fp32 GEMM)
  //   ws+0        : x bf16 [4096][2304]; later aout bf16 [4096][2048]
  //   ws+18874368 : W^T bf16 (qkv-phase: [4096][2304]; out-phase: wo^T [2304][2048])
  //   ws+28311552 : vt bf16 [4][256][4096]
  u16* qkv = (u16*)d_out;
  u16* xbf = (u16*)d_ws;
  u16* wT = (u16*)((char*)d_ws + 18874368);
  u16* vtb = (u16*)((char*)d_ws + 28311552);
  u16* aout = xbf;

  k_cvt_bf16<<<9216, 256, 0, stream>>>(x, xbf, S_LEN * HID_DIM);
  k_transpose_w<<<dim3(128, 72), 256, 0, stream>>>(wq, wk, wv, wT);
  k_gemm8p<1><<<dim3(256), 512, 0, stream>>>(xbf, wT, qkv, S_LEN, QKV_N, HID_DIM);
  k_vtrans<<<dim3(32, 128), 256, 0, stream>>>(qkv, vtb);
  k_normrope<<<S_LEN * 12, 128, 0, stream>>>(qkv, pos, qnw, knw);
  k_transpose_cvt<<<dim3(72, 64), 256, 0, stream>>>(wo, HID_DIM, wT, 2048, 0);
  k_attn<<<dim3(256), 512, 0, stream>>>(qkv, vtb, pos, aout);
  k_gemm192<<<dim3(192), 512, 0, stream>>>(aout, wT, (float*)d_out, S_LEN, HID_DIM, 2048);
}

// Round 13
// 229.908 us; speedup vs baseline: 1.3296x; 1.0580x over previous
//
#include <hip/hip_runtime.h>
#include <stdint.h>

typedef unsigned short u16;
typedef __attribute__((ext_vector_type(8))) short bf16x8;
typedef __attribute__((ext_vector_type(4))) float f32x4;

#define S_LEN 4096
#define HID_DIM 2304
#define QKV_N 4096
#define AO_N 2048
#define HD 256
#define WIN 1024
#define QSCALE 0.0625f

static __device__ __forceinline__ u16 f2bf(float f) {
  union { float f; uint32_t u; } v; v.f = f;
  return (u16)((v.u + 0x7FFFu + ((v.u >> 16) & 1u)) >> 16);
}
static __device__ __forceinline__ float bf2f(u16 h) {
  union { uint32_t u; float f; } v; v.u = ((uint32_t)h) << 16;
  return v.f;
}

static __device__ __forceinline__ void gld16(const void* src, void* dst) {
  __builtin_amdgcn_global_load_lds((const __attribute__((address_space(1))) void*)src,
                                   (__attribute__((address_space(3))) void*)dst, 16, 0, 0);
}

#define BAR() __builtin_amdgcn_s_barrier()
#define LG0() asm volatile("s_waitcnt lgkmcnt(0)" ::: "memory")
#define VM6() asm volatile("s_waitcnt vmcnt(6)" ::: "memory")
#define VM5() asm volatile("s_waitcnt vmcnt(5)" ::: "memory")
#define VM4() asm volatile("s_waitcnt vmcnt(4)" ::: "memory")
#define VM3() asm volatile("s_waitcnt vmcnt(3)" ::: "memory")
#define VM2() asm volatile("s_waitcnt vmcnt(2)" ::: "memory")
#define VM0() asm volatile("s_waitcnt vmcnt(0)" ::: "memory")
#define PRIO1() __builtin_amdgcn_s_setprio(1)
#define PRIO0() __builtin_amdgcn_s_setprio(0)

// ---------------- fp32 -> bf16 elementwise ----------------
__global__ __launch_bounds__(256) void k_cvt_bf16(const float* __restrict__ in,
                                                  u16* __restrict__ out, int n) {
  int i = (blockIdx.x * 256 + threadIdx.x) * 4;
  if (i >= n) return;
  float4 v = *(const float4*)(in + i);
  uint64_t p = (uint64_t)f2bf(v.x) | ((uint64_t)f2bf(v.y) << 16)
             | ((uint64_t)f2bf(v.z) << 32) | ((uint64_t)f2bf(v.w) << 48);
  *(uint64_t*)(out + i) = p;
}

// ---------------- RoPE cos/sin tables [4096][128] f32 (trig OFF the GEMM tail) ----------
__global__ __launch_bounds__(256) void k_sincos(const int* __restrict__ pos_ids,
                                                float* __restrict__ ctab,
                                                float* __restrict__ stab) {
  int idx = blockIdx.x * 256 + threadIdx.x;  // 4096*128
  int s = idx >> 7, j = idx & 127;
  float ang = (float)pos_ids[s] * exp2f((float)j * (-13.287712379549449f / 128.0f));
  float sn, c;
  sincosf(ang, &sn, &c);
  ctab[idx] = c;
  stab[idx] = sn;
}

// in: fp32 [R][C] row-major; out bf16: out[(row_off + c)*out_stride + r] = in[r][c]
__global__ __launch_bounds__(256) void k_transpose_cvt(const float* __restrict__ in, int C,
                                                       u16* __restrict__ out, int out_stride,
                                                       int row_off) {
  __shared__ float tile[32][33];
  int c0 = blockIdx.x * 32, r0 = blockIdx.y * 32;
  int tx = threadIdx.x & 31, ty = threadIdx.x >> 5;
#pragma unroll
  for (int i = 0; i < 4; i++)
    tile[ty + i * 8][tx] = in[(size_t)(r0 + ty + i * 8) * C + c0 + tx];
  __syncthreads();
#pragma unroll
  for (int i = 0; i < 4; i++)
    out[(size_t)(row_off + c0 + ty + i * 8) * out_stride + r0 + tx] = f2bf(tile[tx][ty + i * 8]);
}

// ---------------- merged wq/wk/wv transpose-convert into stacked wT [4096][2304] ---------
__global__ __launch_bounds__(256) void k_transpose_w(const float* __restrict__ wq,
                                                     const float* __restrict__ wk,
                                                     const float* __restrict__ wv,
                                                     u16* __restrict__ out) {
  int ct = blockIdx.x;       // 0..127 -> out rows ct*32..+31
  int r0 = blockIdx.y * 32;  // over 2304
  const float* src;
  int C, c0;
  if (ct < 64) {
    src = wq; C = 2048; c0 = ct * 32;
  } else if (ct < 96) {
    src = wk; C = 1024; c0 = (ct - 64) * 32;
  } else {
    src = wv; C = 1024; c0 = (ct - 96) * 32;
  }
  __shared__ float tile[32][33];
  int tx = threadIdx.x & 31, ty = threadIdx.x >> 5;
#pragma unroll
  for (int i = 0; i < 4; i++)
    tile[ty + i * 8][tx] = src[(size_t)(r0 + ty + i * 8) * C + c0 + tx];
  __syncthreads();
#pragma unroll
  for (int i = 0; i < 4; i++)
    out[(size_t)(ct * 32 + ty + i * 8) * HID_DIM + r0 + tx] = f2bf(tile[tx][ty + i * 8]);
}

// ---------------- bf16 GEMM: 256x256, BK=64, 4-phase, uniform lag-4 staging -------------
// MODE 1 fused epilogue: bn<12 (q/k) -> RMSNorm+RoPE (table-based, no transcendentals)
// then bf16 store to qkv; bn>=12 (v) -> transpose via LDS slab, write vt directly.
// MODE 0: plain fp32 store. Main loop identical to R12 (78us, MfmaUtil 40%, 0 conflicts).
template <int MODE>
__global__ __launch_bounds__(512, 2) void k_gemm8p(const u16* __restrict__ A,
                                                   const u16* __restrict__ Bt,
                                                   void* __restrict__ Cout,
                                                   int M, int N, int K,
                                                   const float* __restrict__ ctab,
                                                   const float* __restrict__ stab,
                                                   const float* __restrict__ qnw,
                                                   const float* __restrict__ knw,
                                                   u16* __restrict__ vtb) {
  __shared__ u16 sA[2][256 * 64];
  __shared__ u16 sB[2][256 * 64];
  const int t = threadIdx.x, lane = t & 63, wave = t >> 6;
  const int wr = wave >> 2, wc = wave & 3;
  const int l15 = lane & 15, l4 = lane >> 4;
  const int nbn = N >> 8;
  const int cpx = gridDim.x >> 3;
  const int wg = ((int)blockIdx.x & 7) * cpx + ((int)blockIdx.x >> 3);  // bijective XCD swz
  const int bm = wg / nbn, bn = wg % nbn;
  const int NT = K >> 6;
  const int srow = lane >> 3;
  const int sslot = ((lane & 7) ^ srow) * 8;
  const u16* Abase = A + (size_t)(bm * 256) * K;
  const u16* Bbase = Bt + (size_t)(bn * 256) * K;
  f32x4 acc[8][4] = {};
  bf16x8 aF[4][2], b01[2][2], b23[2][2];

#define STG_A(BUF, HALF, KT) do {                                                 \
    _Pragma("unroll")                                                             \
    for (int c_ = 0; c_ < 2; c_++) {                                              \
      int rb_ = (HALF) * 128 + (wave * 2 + c_) * 8;                               \
      gld16(Abase + (size_t)(rb_ + srow) * K + ((KT) << 6) + sslot,               \
            &sA[BUF][rb_ * 64]);                                                  \
    }                                                                             \
  } while (0)
#define STG_B(BUF, HALF, KT) do {                                                 \
    _Pragma("unroll")                                                             \
    for (int c_ = 0; c_ < 2; c_++) {                                              \
      int rb_ = (HALF) * 128 + (wave * 2 + c_) * 8;                               \
      gld16(Bbase + (size_t)(rb_ + srow) * K + ((KT) << 6) + sslot,               \
            &sB[BUF][rb_ * 64]);                                                  \
    }                                                                             \
  } while (0)
#define LDA(BUF, M_, KK)                                                          \
  (*(const bf16x8*)&sA[BUF][((M_) * 32 + wr * 16 + l15) * 64 +                    \
                            ((((KK) << 2) + l4) ^ (l15 & 7)) * 8])
#define LDB(BUF, N_, KK)                                                          \
  (*(const bf16x8*)&sB[BUF][((N_) * 64 + wc * 16 + l15) * 64 +                    \
                            ((((KK) << 2) + l4) ^ (l15 & 7)) * 8])

#define P1_LOADS(b_) do {                                                         \
    _Pragma("unroll") for (int m_ = 0; m_ < 4; m_++)                              \
      _Pragma("unroll") for (int k_ = 0; k_ < 2; k_++)                            \
        aF[m_][k_] = LDA(b_, m_, k_);                                             \
    _Pragma("unroll") for (int n_ = 0; n_ < 2; n_++)                              \
      _Pragma("unroll") for (int k_ = 0; k_ < 2; k_++)                            \
        b01[n_][k_] = LDB(b_, n_, k_);                                            \
  } while (0)
#define P2_LOADS(b_) do {                                                         \
    _Pragma("unroll") for (int n_ = 0; n_ < 2; n_++)                              \
      _Pragma("unroll") for (int k_ = 0; k_ < 2; k_++)                            \
        b23[n_][k_] = LDB(b_, n_ + 2, k_);                                        \
  } while (0)
#define P3_LOADS(b_) do {                                                         \
    _Pragma("unroll") for (int m_ = 0; m_ < 4; m_++)                              \
      _Pragma("unroll") for (int k_ = 0; k_ < 2; k_++)                            \
        aF[m_][k_] = LDA(b_, m_ + 4, k_);                                         \
  } while (0)
#define MFMA16(MOFF, NOFF, BREG) do {                                             \
    _Pragma("unroll") for (int m_ = 0; m_ < 4; m_++)                              \
      _Pragma("unroll") for (int n_ = 0; n_ < 2; n_++)                            \
        _Pragma("unroll") for (int k_ = 0; k_ < 2; k_++)                          \
          acc[m_ + MOFF][n_ + NOFF] = __builtin_amdgcn_mfma_f32_16x16x32_bf16(    \
              aF[m_][k_], BREG[n_][k_], acc[m_ + MOFF][n_ + NOFF], 0, 0, 0);      \
  } while (0)

  // prologue: stage tile 0 in consumption order; leaves {Bh1,Ah1} (4) in flight
  STG_A(0, 0, 0);
  STG_B(0, 0, 0);
  STG_B(0, 1, 0);
  STG_A(0, 1, 0);
  VM4();
  BAR();

  for (int tt = 0; tt < NT - 1; ++tt) {
    const int b = tt & 1, nb = b ^ 1;
    P1_LOADS(b);
    STG_A(nb, 0, tt + 1);
    STG_B(nb, 0, tt + 1);
    BAR(); LG0(); PRIO1(); MFMA16(0, 0, b01); PRIO0();
    VM6();
    BAR();
    P2_LOADS(b);
    STG_B(nb, 1, tt + 1);
    BAR(); LG0(); PRIO1(); MFMA16(0, 2, b23); PRIO0();
    VM6();
    BAR();
    P3_LOADS(b);
    STG_A(nb, 1, tt + 1);
    BAR(); LG0(); PRIO1(); MFMA16(4, 0, b01); PRIO0();
    BAR();
    PRIO1(); MFMA16(4, 2, b23); PRIO0();
    VM4();
    BAR();
  }
  {
    const int b = (NT - 1) & 1;
    P1_LOADS(b);
    BAR(); LG0(); PRIO1(); MFMA16(0, 0, b01); PRIO0();
    VM2();
    BAR();
    P2_LOADS(b);
    BAR(); LG0(); PRIO1(); MFMA16(0, 2, b23); PRIO0();
    VM0();
    BAR();
    P3_LOADS(b);
    BAR(); LG0(); PRIO1(); MFMA16(4, 0, b01); PRIO0();
    BAR();
    PRIO1(); MFMA16(4, 2, b23); PRIO0();
  }

  if (MODE == 1) {
    __syncthreads();  // all main-loop LDS reads done; sA (64KB) reusable as slab
    float* slab = (float*)&sA[0][0];  // [32][264] f32 = 33.8KB
    if (bn < 12) {
      // fused RMSNorm + RoPE + scale; trig from precomputed tables (L2-resident per bm)
      const float* wvec = (bn < 8) ? qnw : knw;
      const float scl = (bn < 8) ? QSCALE : 1.0f;
      f32x4 wv4 = *(const f32x4*)&wvec[lane * 4];
#pragma unroll
      for (int m = 0; m < 8; m++) {
#pragma unroll
        for (int n = 0; n < 4; n++)
#pragma unroll
          for (int r = 0; r < 4; r++)
            slab[(wr * 16 + l4 * 4 + r) * 264 + n * 64 + wc * 16 + l15] = acc[m][n][r];
        __syncthreads();
#pragma unroll
        for (int rr = 0; rr < 4; rr++) {
          int lrow = wave * 4 + rr;
          int grow = bm * 256 + m * 32 + lrow;
          f32x4 v = *(const f32x4*)&slab[lrow * 264 + lane * 4];
          float ss = v[0] * v[0] + v[1] * v[1] + v[2] * v[2] + v[3] * v[3];
#pragma unroll
          for (int off = 1; off < 64; off <<= 1) ss += __shfl_xor(ss, off);
          float rms = rsqrtf(ss * (1.0f / 256.0f) + 1e-6f);
          float y[4], yo[4];
#pragma unroll
          for (int j = 0; j < 4; j++) y[j] = v[j] * rms * (1.0f + wv4[j]);
#pragma unroll
          for (int j = 0; j < 4; j++) yo[j] = __shfl_xor(y[j], 32);
          f32x4 cv = *(const f32x4*)&ctab[grow * 128 + (lane & 31) * 4];
          f32x4 sv = *(const f32x4*)&stab[grow * 128 + (lane & 31) * 4];
          uint64_t pk = 0;
#pragma unroll
          for (int j = 0; j < 4; j++) {
            float o = (lane < 32) ? (y[j] * cv[j] - yo[j] * sv[j])
                                  : (yo[j] * sv[j] + y[j] * cv[j]);
            pk |= (uint64_t)f2bf(o * scl) << (16 * j);
          }
          *(uint64_t*)&((u16*)Cout)[(size_t)grow * N + bn * 256 + lane * 4] = pk;
        }
        __syncthreads();
      }
    } else {
      // V heads: transpose through slab, write vt[kvh*256+d][s] directly (skip qkv copy)
      const int kvh = bn - 12;
      const int d = t >> 1, sh = (t & 1) * 16;
#pragma unroll
      for (int m = 0; m < 8; m++) {
#pragma unroll
        for (int n = 0; n < 4; n++)
#pragma unroll
          for (int r = 0; r < 4; r++)
            slab[(wr * 16 + l4 * 4 + r) * 264 + n * 64 + wc * 16 + l15] = acc[m][n][r];
        __syncthreads();
        u16* dst = vtb + (size_t)(kvh * 256 + d) * S_LEN + bm * 256 + m * 32 + sh;
#pragma unroll
        for (int g = 0; g < 4; g++) {
          uint64_t pk = 0;
#pragma unroll
          for (int jj = 0; jj < 4; jj++)
            pk |= (uint64_t)f2bf(slab[(sh + g * 4 + jj) * 264 + d]) << (16 * jj);
          *(uint64_t*)(dst + g * 4) = pk;
        }
        __syncthreads();
      }
    }
  } else {
#pragma unroll
    for (int m = 0; m < 8; m++)
#pragma unroll
      for (int n = 0; n < 4; n++)
#pragma unroll
        for (int r = 0; r < 4; r++) {
          size_t row = bm * 256 + m * 32 + wr * 16 + l4 * 4 + r;
          size_t col = bn * 256 + n * 64 + wc * 16 + l15;
          ((float*)Cout)[row * N + col] = acc[m][n][r];
        }
  }
#undef STG_A
#undef STG_B
#undef LDA
#undef LDB
#undef P1_LOADS
#undef P2_LOADS
#undef P3_LOADS
#undef MFMA16
}

// ---------------- bf16 GEMM 256x192 (out-proj): 4-phase, uniform lag-4 staging ----------
__global__ __launch_bounds__(512, 2) void k_gemm192(const u16* __restrict__ A,
                                                    const u16* __restrict__ Bt,
                                                    float* __restrict__ Cout,
                                                    int M, int N, int K) {
  __shared__ u16 sA[2][256 * 64];
  __shared__ u16 sB[2][192 * 64];
  const int t = threadIdx.x, lane = t & 63, wave = t >> 6;
  const int wr = wave >> 2, wc = wave & 3;
  const int l15 = lane & 15, l4 = lane >> 4;
  const int nbn = N / 192;  // 12
  const int cpx = gridDim.x >> 3;
  const int wg = ((int)blockIdx.x & 7) * cpx + ((int)blockIdx.x >> 3);
  const int bm = wg / nbn, bn = wg % nbn;
  const int NT = K >> 6;
  const int srow = lane >> 3;
  const int sslot = ((lane & 7) ^ srow) * 8;
  const u16* Abase = A + (size_t)(bm * 256) * K;
  const u16* Bbase = Bt + (size_t)(bn * 192) * K;
  f32x4 acc[8][3] = {};
  bf16x8 aF[4][2], b01[2][2], b2[2];

#define GA_STG_A(BUF, HALF, KT) do {                                              \
    _Pragma("unroll")                                                             \
    for (int c_ = 0; c_ < 2; c_++) {                                              \
      int rb_ = (HALF) * 128 + (wave * 2 + c_) * 8;                               \
      gld16(Abase + (size_t)(rb_ + srow) * K + ((KT) << 6) + sslot,               \
            &sA[BUF][rb_ * 64]);                                                  \
    }                                                                             \
  } while (0)
#define GA_STG_BC(BUF, CH, KT) do {                                               \
    int rb_ = (CH) * 64 + wave * 8;                                               \
    gld16(Bbase + (size_t)(rb_ + srow) * K + ((KT) << 6) + sslot,                 \
          &sB[BUF][rb_ * 64]);                                                    \
  } while (0)
#define GA_LDA(BUF, M_, KK)                                                       \
  (*(const bf16x8*)&sA[BUF][((M_) * 32 + wr * 16 + l15) * 64 +                    \
                            ((((KK) << 2) + l4) ^ (l15 & 7)) * 8])
#define GA_LDB(BUF, N_, KK)                                                       \
  (*(const bf16x8*)&sB[BUF][((N_) * 64 + wc * 16 + l15) * 64 +                    \
                            ((((KK) << 2) + l4) ^ (l15 & 7)) * 8])
#define GA_P1_LOADS(b_) do {                                                      \
    _Pragma("unroll") for (int m_ = 0; m_ < 4; m_++)                              \
      _Pragma("unroll") for (int k_ = 0; k_ < 2; k_++)                            \
        aF[m_][k_] = GA_LDA(b_, m_, k_);                                          \
    _Pragma("unroll") for (int n_ = 0; n_ < 2; n_++)                              \
      _Pragma("unroll") for (int k_ = 0; k_ < 2; k_++)                            \
        b01[n_][k_] = GA_LDB(b_, n_, k_);                                         \
  } while (0)
#define GA_P2_LOADS(b_) do {                                                      \
    _Pragma("unroll") for (int k_ = 0; k_ < 2; k_++)                              \
      b2[k_] = GA_LDB(b_, 2, k_);                                                 \
  } while (0)
#define GA_P3_LOADS(b_) do {                                                      \
    _Pragma("unroll") for (int m_ = 0; m_ < 4; m_++)                              \
      _Pragma("unroll") for (int k_ = 0; k_ < 2; k_++)                            \
        aF[m_][k_] = GA_LDA(b_, m_ + 4, k_);                                      \
  } while (0)
#define GA_MFMA_N01(MOFF) do {                                                    \
    _Pragma("unroll") for (int m_ = 0; m_ < 4; m_++)                              \
      _Pragma("unroll") for (int n_ = 0; n_ < 2; n_++)                            \
        _Pragma("unroll") for (int k_ = 0; k_ < 2; k_++)                          \
          acc[m_ + MOFF][n_] = __builtin_amdgcn_mfma_f32_16x16x32_bf16(           \
              aF[m_][k_], b01[n_][k_], acc[m_ + MOFF][n_], 0, 0, 0);              \
  } while (0)
#define GA_MFMA_N2(MOFF) do {                                                     \
    _Pragma("unroll") for (int m_ = 0; m_ < 4; m_++)                              \
      _Pragma("unroll") for (int k_ = 0; k_ < 2; k_++)                            \
        acc[m_ + MOFF][2] = __builtin_amdgcn_mfma_f32_16x16x32_bf16(              \
            aF[m_][k_], b2[k_], acc[m_ + MOFF][2], 0, 0, 0);                      \
  } while (0)

  GA_STG_A(0, 0, 0);
  GA_STG_BC(0, 0, 0);
  GA_STG_BC(0, 1, 0);
  GA_STG_BC(0, 2, 0);
  GA_STG_A(0, 1, 0);
  VM3();
  BAR();

  for (int tt = 0; tt < NT - 1; ++tt) {
    const int b = tt & 1, nb = b ^ 1;
    GA_P1_LOADS(b);
    GA_STG_A(nb, 0, tt + 1);
    GA_STG_BC(nb, 0, tt + 1);
    GA_STG_BC(nb, 1, tt + 1);
    BAR(); LG0(); PRIO1(); GA_MFMA_N01(0); PRIO0();
    VM6();
    BAR();
    GA_P2_LOADS(b);
    GA_STG_BC(nb, 2, tt + 1);
    BAR(); LG0(); PRIO1(); GA_MFMA_N2(0); PRIO0();
    VM5();
    BAR();
    GA_P3_LOADS(b);
    GA_STG_A(nb, 1, tt + 1);
    BAR(); LG0(); PRIO1(); GA_MFMA_N01(4); PRIO0();
    BAR();
    PRIO1(); GA_MFMA_N2(4); PRIO0();
    VM3();
    BAR();
  }
  {
    const int b = (NT - 1) & 1;
    GA_P1_LOADS(b);
    BAR(); LG0(); PRIO1(); GA_MFMA_N01(0); PRIO0();
    VM2();
    BAR();
    GA_P2_LOADS(b);
    BAR(); LG0(); PRIO1(); GA_MFMA_N2(0); PRIO0();
    VM0();
    BAR();
    GA_P3_LOADS(b);
    BAR(); LG0(); PRIO1(); GA_MFMA_N01(4); PRIO0();
    BAR();
    PRIO1(); GA_MFMA_N2(4); PRIO0();
  }

#pragma unroll
  for (int m = 0; m < 8; m++)
#pragma unroll
    for (int n = 0; n < 3; n++)
#pragma unroll
      for (int r = 0; r < 4; r++) {
        size_t row = bm * 256 + m * 32 + wr * 16 + l4 * 4 + r;
        size_t col = bn * 192 + n * 64 + wc * 16 + l15;
        Cout[row * N + col] = acc[m][n][r];
      }
#undef GA_STG_A
#undef GA_STG_BC
#undef GA_LDA
#undef GA_LDB
#undef GA_P1_LOADS
#undef GA_P2_LOADS
#undef GA_P3_LOADS
#undef GA_MFMA_N01
#undef GA_MFMA_N2
}

// ---------------- flash attention v7: 64 q/block, GQA-shared, double-buffered K/V -------
__global__ __launch_bounds__(512, 2) void k_attn(const u16* __restrict__ qkv,
                                                 const u16* __restrict__ vt,
                                                 const int* __restrict__ pos_ids,
                                                 u16* __restrict__ aout) {
  __shared__ u16 lK[2][64 * 256];  // [key][d], rows 512B, swizzled
  __shared__ u16 lV[2][256 * 64];  // [d][key], rows 128B, swizzled
  __shared__ u16 lP[8][16 * 64];   // per-wave P, rows 128B, swizzled
  const int bid = blockIdx.x;      // 256 blocks
  const int wg = (bid & 7) * 32 + (bid >> 3);  // bijective XCD swizzle
  const int kvh = wg >> 6;                     // 0..3
  const int q0 = (wg & 63) * 64;               // 0..4032
  const int t = threadIdx.x, lane = t & 63, wave = t >> 6;
  const int l15 = lane & 15, l4 = lane >> 4;
  const int head = kvh * 2 + (wave >> 2);
  const int qw = q0 + (wave & 3) * 16;

  bf16x8 qfr[8];
  {
    const u16* qptr = qkv + (size_t)(qw + l15) * QKV_N + head * HD + l4 * 8;
#pragma unroll
    for (int kc = 0; kc < 8; kc++) qfr[kc] = *(const bf16x8*)(qptr + kc * 32);
  }
  f32x4 acc[16] = {};
  float mrow[4], lrow[4];
#pragma unroll
  for (int r = 0; r < 4; r++) { mrow[r] = -1e30f; lrow[r] = 0.0f; }
  int qi[4];
#pragma unroll
  for (int r = 0; r < 4; r++) qi[r] = pos_ids[qw + l4 * 4 + r];

  const int krw = lane >> 5, kcl = lane & 31;
  const int vrw = lane >> 3, vcl = lane & 7;
  const u16* kgb = qkv + 2048 + kvh * HD;
  const u16* vgb = vt + (size_t)kvh * HD * S_LEN;

  int start = q0 - (WIN - 1);
  if (start < 0) start = 0;
  start &= ~63;

#define STAGE_KV(B, T0) do {                                                          \
    _Pragma("unroll")                                                                 \
    for (int i_ = 0; i_ < 4; i_++) {                                                  \
      int ch_ = wave * 4 + i_;                                                        \
      int kr_ = ch_ * 2 + krw;                                                        \
      gld16(kgb + (size_t)((T0) + kr_) * QKV_N + ((kcl ^ (kr_ & 7)) * 8),             \
            &lK[B][ch_ * 512]);                                                       \
      int vr_ = ch_ * 8 + vrw;                                                        \
      gld16(vgb + (size_t)vr_ * S_LEN + (T0) + ((vcl ^ (vr_ & 7)) * 8),               \
            &lV[B][ch_ * 512]);                                                       \
    }                                                                                 \
  } while (0)

  STAGE_KV(0, start);
  __syncthreads();
  int buf = 0;
  for (int t0 = start; t0 <= q0 + 63; t0 += 64) {
    if (t0 + 64 <= q0 + 63) STAGE_KV(buf ^ 1, t0 + 64);
    int kp[4];
#pragma unroll
    for (int kb = 0; kb < 4; kb++) kp[kb] = pos_ids[t0 + kb * 16 + l15];
    f32x4 sv[4] = {};
    PRIO1();
#pragma unroll
    for (int kb = 0; kb < 4; kb++) {
      const char* krow = (const char*)&lK[buf][(kb * 16 + l15) * 256];
      const int sw = ((kb * 16 + l15) & 7) << 4;
#pragma unroll
      for (int kc = 0; kc < 8; kc++) {
        bf16x8 kf = *(const bf16x8*)(krow + ((kc * 64 + l4 * 16) ^ sw));
        sv[kb] = __builtin_amdgcn_mfma_f32_16x16x32_bf16(qfr[kc], kf, sv[kb], 0, 0, 0);
      }
    }
    PRIO0();
    float sloc[4][4], mx[4];
    float need = 0.0f;
#pragma unroll
    for (int r = 0; r < 4; r++) {
      int pi = qi[r];
#pragma unroll
      for (int kb = 0; kb < 4; kb++)
        sloc[r][kb] = ((kp[kb] <= pi) && (pi - kp[kb] < WIN)) ? sv[kb][r] : -__builtin_inff();
      float m_ = fmaxf(fmaxf(sloc[r][0], sloc[r][1]), fmaxf(sloc[r][2], sloc[r][3]));
#pragma unroll
      for (int off = 1; off < 16; off <<= 1) m_ = fmaxf(m_, __shfl_xor(m_, off));
      mx[r] = m_;
      need = fmaxf(need, m_ - mrow[r]);
    }
    bool resc = __any(need > 8.0f);
    if (resc) {
#pragma unroll
      for (int r = 0; r < 4; r++) {
        float nm = fmaxf(mrow[r], mx[r]);
        float al = __expf(mrow[r] - nm);
        mrow[r] = nm;
        lrow[r] *= al;
#pragma unroll
        for (int nd = 0; nd < 16; nd++) acc[nd][r] *= al;
      }
    }
#pragma unroll
    for (int r = 0; r < 4; r++) {
      float nm = mrow[r];
      float e0 = __expf(sloc[r][0] - nm), e1 = __expf(sloc[r][1] - nm);
      float e2 = __expf(sloc[r][2] - nm), e3 = __expf(sloc[r][3] - nm);
      float sum = (e0 + e1) + (e2 + e3);
#pragma unroll
      for (int off = 1; off < 16; off <<= 1) sum += __shfl_xor(sum, off);
      lrow[r] += sum;
      int q = l4 * 4 + r;
      char* lpw = (char*)&lP[wave][0] + q * 128;
      int swp = (q & 7) << 4;
      *(u16*)(lpw + ((l15 * 2) ^ swp)) = f2bf(e0);
      *(u16*)(lpw + ((32 + l15 * 2) ^ swp)) = f2bf(e1);
      *(u16*)(lpw + ((64 + l15 * 2) ^ swp)) = f2bf(e2);
      *(u16*)(lpw + ((96 + l15 * 2) ^ swp)) = f2bf(e3);
    }
#pragma unroll
    for (int kc2 = 0; kc2 < 2; kc2++) {
      int q = l15;
      bf16x8 pa = *(const bf16x8*)((const char*)&lP[wave][0] + q * 128 +
                                   ((kc2 * 64 + l4 * 16) ^ ((q & 7) << 4)));
      PRIO1();
#pragma unroll
      for (int nd = 0; nd < 16; nd++) {
        int d = nd * 16 + l15;
        bf16x8 vf = *(const bf16x8*)((const char*)&lV[buf][d * 64] +
                                     ((kc2 * 64 + l4 * 16) ^ ((d & 7) << 4)));
        acc[nd] = __builtin_amdgcn_mfma_f32_16x16x32_bf16(pa, vf, acc[nd], 0, 0, 0);
      }
      PRIO0();
    }
    __syncthreads();
    buf ^= 1;
  }
  float rinv[4];
#pragma unroll
  for (int r = 0; r < 4; r++) rinv[r] = 1.0f / lrow[r];
#pragma unroll
  for (int nd = 0; nd < 16; nd++)
#pragma unroll
    for (int r = 0; r < 4; r++) {
      size_t row = qw + l4 * 4 + r;
      aout[row * AO_N + head * HD + nd * 16 + l15] = f2bf(acc[nd][r] * rinv[r]);
    }
#undef STAGE_KV
}

extern "C" void kernel_launch(void* const* d_in, const int* in_sizes, int n_in,
                              void* d_out, int out_size, void* d_ws, size_t ws_size,
                              hipStream_t stream) {
  const float* x = (const float*)d_in[0];
  const int* pos = (const int*)d_in[1];
  const float* wq = (const float*)d_in[2];
  const float* wk = (const float*)d_in[3];
  const float* wv = (const float*)d_in[4];
  const float* wo = (const float*)d_in[5];
  const float* qnw = (const float*)d_in[6];
  const float* knw = (const float*)d_in[7];

  // scratch layout:
  //   d_out [0,33.5MB): qkv bf16 [4096][4096] (V cols unwritten; K/Q written by gemm<1>)
  //   d_out [33.5MB,35.6MB): ctab f32[4096][128]; [35.6MB,37.7MB): stab (dead after
  //     gemm<1>; final gemm192 overwrites all of d_out)
  //   ws+0        : x bf16 [4096][2304]; later aout bf16 [4096][2048]
  //   ws+18874368 : W^T bf16 (qkv-phase: [4096][2304]; out-phase: wo^T [2304][2048])
  //   ws+28311552 : vt bf16 [4][256][4096] (written by gemm<1> V-epilogue)
  u16* qkv = (u16*)d_out;
  float* ctab = (float*)((char*)d_out + 33554432);
  float* stab = (float*)((char*)d_out + 35651584);
  u16* xbf = (u16*)d_ws;
  u16* wT = (u16*)((char*)d_ws + 18874368);
  u16* vtb = (u16*)((char*)d_ws + 28311552);
  u16* aout = xbf;

  k_cvt_bf16<<<9216, 256, 0, stream>>>(x, xbf, S_LEN * HID_DIM);
  k_sincos<<<2048, 256, 0, stream>>>(pos, ctab, stab);
  k_transpose_w<<<dim3(128, 72), 256, 0, stream>>>(wq, wk, wv, wT);
  k_gemm8p<1><<<dim3(256), 512, 0, stream>>>(xbf, wT, qkv, S_LEN, QKV_N, HID_DIM,
                                             ctab, stab, qnw, knw, vtb);
  k_transpose_cvt<<<dim3(72, 64), 256, 0, stream>>>(wo, HID_DIM, wT, 2048, 0);
  k_attn<<<dim3(256), 512, 0, stream>>>(qkv, vtb, pos, aout);
  k_gemm192<<<dim3(192), 512, 0, stream>>>(aout, wT, (float*)d_out, S_LEN, HID_DIM, 2048);
}

// Round 14
// 226.395 us; speedup vs baseline: 1.3502x; 1.0155x over previous
//
#include <hip/hip_runtime.h>
#include <stdint.h>

typedef unsigned short u16;
typedef __attribute__((ext_vector_type(8))) short bf16x8;
typedef __attribute__((ext_vector_type(4))) float f32x4;

#define S_LEN 4096
#define HID_DIM 2304
#define QKV_N 4096
#define AO_N 2048
#define HD 256
#define WIN 1024
#define QSCALE 0.0625f

static __device__ __forceinline__ u16 f2bf(float f) {
  union { float f; uint32_t u; } v; v.f = f;
  return (u16)((v.u + 0x7FFFu + ((v.u >> 16) & 1u)) >> 16);
}
static __device__ __forceinline__ float bf2f(u16 h) {
  union { uint32_t u; float f; } v; v.u = ((uint32_t)h) << 16;
  return v.f;
}

static __device__ __forceinline__ void gld16(const void* src, void* dst) {
  __builtin_amdgcn_global_load_lds((const __attribute__((address_space(1))) void*)src,
                                   (__attribute__((address_space(3))) void*)dst, 16, 0, 0);
}

#define BAR() __builtin_amdgcn_s_barrier()
#define LG0() asm volatile("s_waitcnt lgkmcnt(0)" ::: "memory")
#define VM6() asm volatile("s_waitcnt vmcnt(6)" ::: "memory")
#define VM5() asm volatile("s_waitcnt vmcnt(5)" ::: "memory")
#define VM4() asm volatile("s_waitcnt vmcnt(4)" ::: "memory")
#define VM3() asm volatile("s_waitcnt vmcnt(3)" ::: "memory")
#define VM2() asm volatile("s_waitcnt vmcnt(2)" ::: "memory")
#define VM0() asm volatile("s_waitcnt vmcnt(0)" ::: "memory")
#define PRIO1() __builtin_amdgcn_s_setprio(1)
#define PRIO0() __builtin_amdgcn_s_setprio(0)

// ---------------- fp32 -> bf16 elementwise ----------------
__global__ __launch_bounds__(256) void k_cvt_bf16(const float* __restrict__ in,
                                                  u16* __restrict__ out, int n) {
  int i = (blockIdx.x * 256 + threadIdx.x) * 4;
  if (i >= n) return;
  float4 v = *(const float4*)(in + i);
  uint64_t p = (uint64_t)f2bf(v.x) | ((uint64_t)f2bf(v.y) << 16)
             | ((uint64_t)f2bf(v.z) << 32) | ((uint64_t)f2bf(v.w) << 48);
  *(uint64_t*)(out + i) = p;
}

// ---------------- RoPE cos/sin tables [4096][128] f32 ----------------
__global__ __launch_bounds__(256) void k_sincos(const int* __restrict__ pos_ids,
                                                float* __restrict__ ctab,
                                                float* __restrict__ stab) {
  int idx = blockIdx.x * 256 + threadIdx.x;  // 4096*128
  int s = idx >> 7, j = idx & 127;
  float ang = (float)pos_ids[s] * exp2f((float)j * (-13.287712379549449f / 128.0f));
  float sn, c;
  sincosf(ang, &sn, &c);
  ctab[idx] = c;
  stab[idx] = sn;
}

// in: fp32 [R][C] row-major; out bf16: out[(row_off + c)*out_stride + r] = in[r][c]
__global__ __launch_bounds__(256) void k_transpose_cvt(const float* __restrict__ in, int C,
                                                       u16* __restrict__ out, int out_stride,
                                                       int row_off) {
  __shared__ float tile[32][33];
  int c0 = blockIdx.x * 32, r0 = blockIdx.y * 32;
  int tx = threadIdx.x & 31, ty = threadIdx.x >> 5;
#pragma unroll
  for (int i = 0; i < 4; i++)
    tile[ty + i * 8][tx] = in[(size_t)(r0 + ty + i * 8) * C + c0 + tx];
  __syncthreads();
#pragma unroll
  for (int i = 0; i < 4; i++)
    out[(size_t)(row_off + c0 + ty + i * 8) * out_stride + r0 + tx] = f2bf(tile[tx][ty + i * 8]);
}

// ---------------- merged wq/wk/wv transpose-convert into stacked wT [4096][2304] ---------
__global__ __launch_bounds__(256) void k_transpose_w(const float* __restrict__ wq,
                                                     const float* __restrict__ wk,
                                                     const float* __restrict__ wv,
                                                     u16* __restrict__ out) {
  int ct = blockIdx.x;       // 0..127 -> out rows ct*32..+31
  int r0 = blockIdx.y * 32;  // over 2304
  const float* src;
  int C, c0;
  if (ct < 64) {
    src = wq; C = 2048; c0 = ct * 32;
  } else if (ct < 96) {
    src = wk; C = 1024; c0 = (ct - 64) * 32;
  } else {
    src = wv; C = 1024; c0 = (ct - 96) * 32;
  }
  __shared__ float tile[32][33];
  int tx = threadIdx.x & 31, ty = threadIdx.x >> 5;
#pragma unroll
  for (int i = 0; i < 4; i++)
    tile[ty + i * 8][tx] = src[(size_t)(r0 + ty + i * 8) * C + c0 + tx];
  __syncthreads();
#pragma unroll
  for (int i = 0; i < 4; i++)
    out[(size_t)(ct * 32 + ty + i * 8) * HID_DIM + r0 + tx] = f2bf(tile[tx][ty + i * 8]);
}

// ---------------- bf16 GEMM: 256x256, BK=64, 4-phase, uniform lag-4 staging -------------
// MODE 1 fused epilogue (R14: 2-m slab rounds, 8 barriers; coalesced V stores).
// 2D XCD rect (4bm x 8bn per XCD) for L2 panel reuse.
template <int MODE>
__global__ __launch_bounds__(512, 2) void k_gemm8p(const u16* __restrict__ A,
                                                   const u16* __restrict__ Bt,
                                                   void* __restrict__ Cout,
                                                   int M, int N, int K,
                                                   const float* __restrict__ ctab,
                                                   const float* __restrict__ stab,
                                                   const float* __restrict__ qnw,
                                                   const float* __restrict__ knw,
                                                   u16* __restrict__ vtb) {
  __shared__ u16 sAB[4 * 256 * 64];  // [0,32K)=sA0, [32K.. ) sA1, sB0, sB1 (contiguous)
  const int t = threadIdx.x, lane = t & 63, wave = t >> 6;
  const int wr = wave >> 2, wc = wave & 3;
  const int l15 = lane & 15, l4 = lane >> 4;
  const int nbn = N >> 8;
  int bm, bn;
  {
    const int xcd = (int)blockIdx.x & 7, loc = (int)blockIdx.x >> 3;
    if (nbn == 16) {  // grid 256: 4bm x 8bn rect per XCD
      bm = (xcd >> 1) * 4 + (loc >> 3);
      bn = (xcd & 1) * 8 + (loc & 7);
    } else {
      const int cpx = gridDim.x >> 3;
      const int wg = xcd * cpx + loc;
      bm = wg / nbn;
      bn = wg % nbn;
    }
  }
  const int NT = K >> 6;
  const int srow = lane >> 3;
  const int sslot = ((lane & 7) ^ srow) * 8;
  const u16* Abase = A + (size_t)(bm * 256) * K;
  const u16* Bbase = Bt + (size_t)(bn * 256) * K;
  f32x4 acc[8][4] = {};
  bf16x8 aF[4][2], b01[2][2], b23[2][2];

#define SA_(b) (&sAB[(b) * 16384])
#define SB_(b) (&sAB[32768 + (b) * 16384])
#define STG_A(BUF, HALF, KT) do {                                                 \
    _Pragma("unroll")                                                             \
    for (int c_ = 0; c_ < 2; c_++) {                                              \
      int rb_ = (HALF) * 128 + (wave * 2 + c_) * 8;                               \
      gld16(Abase + (size_t)(rb_ + srow) * K + ((KT) << 6) + sslot,               \
            SA_(BUF) + rb_ * 64);                                                 \
    }                                                                             \
  } while (0)
#define STG_B(BUF, HALF, KT) do {                                                 \
    _Pragma("unroll")                                                             \
    for (int c_ = 0; c_ < 2; c_++) {                                              \
      int rb_ = (HALF) * 128 + (wave * 2 + c_) * 8;                               \
      gld16(Bbase + (size_t)(rb_ + srow) * K + ((KT) << 6) + sslot,               \
            SB_(BUF) + rb_ * 64);                                                 \
    }                                                                             \
  } while (0)
#define LDA(BUF, M_, KK)                                                          \
  (*(const bf16x8*)&SA_(BUF)[((M_) * 32 + wr * 16 + l15) * 64 +                   \
                             ((((KK) << 2) + l4) ^ (l15 & 7)) * 8])
#define LDB(BUF, N_, KK)                                                          \
  (*(const bf16x8*)&SB_(BUF)[((N_) * 64 + wc * 16 + l15) * 64 +                   \
                             ((((KK) << 2) + l4) ^ (l15 & 7)) * 8])

#define P1_LOADS(b_) do {                                                         \
    _Pragma("unroll") for (int m_ = 0; m_ < 4; m_++)                              \
      _Pragma("unroll") for (int k_ = 0; k_ < 2; k_++)                            \
        aF[m_][k_] = LDA(b_, m_, k_);                                             \
    _Pragma("unroll") for (int n_ = 0; n_ < 2; n_++)                              \
      _Pragma("unroll") for (int k_ = 0; k_ < 2; k_++)                            \
        b01[n_][k_] = LDB(b_, n_, k_);                                            \
  } while (0)
#define P2_LOADS(b_) do {                                                         \
    _Pragma("unroll") for (int n_ = 0; n_ < 2; n_++)                              \
      _Pragma("unroll") for (int k_ = 0; k_ < 2; k_++)                            \
        b23[n_][k_] = LDB(b_, n_ + 2, k_);                                        \
  } while (0)
#define P3_LOADS(b_) do {                                                         \
    _Pragma("unroll") for (int m_ = 0; m_ < 4; m_++)                              \
      _Pragma("unroll") for (int k_ = 0; k_ < 2; k_++)                            \
        aF[m_][k_] = LDA(b_, m_ + 4, k_);                                         \
  } while (0)
#define MFMA16(MOFF, NOFF, BREG) do {                                             \
    _Pragma("unroll") for (int m_ = 0; m_ < 4; m_++)                              \
      _Pragma("unroll") for (int n_ = 0; n_ < 2; n_++)                            \
        _Pragma("unroll") for (int k_ = 0; k_ < 2; k_++)                          \
          acc[m_ + MOFF][n_ + NOFF] = __builtin_amdgcn_mfma_f32_16x16x32_bf16(    \
              aF[m_][k_], BREG[n_][k_], acc[m_ + MOFF][n_ + NOFF], 0, 0, 0);      \
  } while (0)

  // prologue: stage tile 0 in consumption order; leaves {Bh1,Ah1} (4) in flight
  STG_A(0, 0, 0);
  STG_B(0, 0, 0);
  STG_B(0, 1, 0);
  STG_A(0, 1, 0);
  VM4();
  BAR();

  for (int tt = 0; tt < NT - 1; ++tt) {
    const int b = tt & 1, nb = b ^ 1;
    P1_LOADS(b);
    STG_A(nb, 0, tt + 1);
    STG_B(nb, 0, tt + 1);
    BAR(); LG0(); PRIO1(); MFMA16(0, 0, b01); PRIO0();
    VM6();
    BAR();
    P2_LOADS(b);
    STG_B(nb, 1, tt + 1);
    BAR(); LG0(); PRIO1(); MFMA16(0, 2, b23); PRIO0();
    VM6();
    BAR();
    P3_LOADS(b);
    STG_A(nb, 1, tt + 1);
    BAR(); LG0(); PRIO1(); MFMA16(4, 0, b01); PRIO0();
    BAR();
    PRIO1(); MFMA16(4, 2, b23); PRIO0();
    VM4();
    BAR();
  }
  {
    const int b = (NT - 1) & 1;
    P1_LOADS(b);
    BAR(); LG0(); PRIO1(); MFMA16(0, 0, b01); PRIO0();
    VM2();
    BAR();
    P2_LOADS(b);
    BAR(); LG0(); PRIO1(); MFMA16(0, 2, b23); PRIO0();
    VM0();
    BAR();
    P3_LOADS(b);
    BAR(); LG0(); PRIO1(); MFMA16(4, 0, b01); PRIO0();
    BAR();
    PRIO1(); MFMA16(4, 2, b23); PRIO0();
  }

  if (MODE == 1) {
    __syncthreads();  // all main-loop LDS reads done; sAB reusable as slab
    float* slab = (float*)sAB;  // [64][264] f32 = 67.6KB (2 m-chunks per round)
    if (bn < 12) {
      // fused RMSNorm + RoPE + scale; trig from precomputed tables
      const float* wvec = (bn < 8) ? qnw : knw;
      const float scl = (bn < 8) ? QSCALE : 1.0f;
      f32x4 wv4 = *(const f32x4*)&wvec[lane * 4];
#pragma unroll
      for (int mp = 0; mp < 4; mp++) {
#pragma unroll
        for (int mh = 0; mh < 2; mh++) {
          int m = mp * 2 + mh;
#pragma unroll
          for (int n = 0; n < 4; n++)
#pragma unroll
            for (int r = 0; r < 4; r++)
              slab[(mh * 32 + wr * 16 + l4 * 4 + r) * 264 + n * 64 + wc * 16 + l15] =
                  acc[m][n][r];
        }
        __syncthreads();
#pragma unroll
        for (int rr = 0; rr < 8; rr++) {
          int lrow = wave * 8 + rr;
          int grow = bm * 256 + mp * 64 + lrow;
          f32x4 v = *(const f32x4*)&slab[lrow * 264 + lane * 4];
          float ss = v[0] * v[0] + v[1] * v[1] + v[2] * v[2] + v[3] * v[3];
#pragma unroll
          for (int off = 1; off < 64; off <<= 1) ss += __shfl_xor(ss, off);
          float rms = rsqrtf(ss * (1.0f / 256.0f) + 1e-6f);
          float y[4], yo[4];
#pragma unroll
          for (int j = 0; j < 4; j++) y[j] = v[j] * rms * (1.0f + wv4[j]);
#pragma unroll
          for (int j = 0; j < 4; j++) yo[j] = __shfl_xor(y[j], 32);
          f32x4 cv = *(const f32x4*)&ctab[grow * 128 + (lane & 31) * 4];
          f32x4 sv = *(const f32x4*)&stab[grow * 128 + (lane & 31) * 4];
          uint64_t pk = 0;
#pragma unroll
          for (int j = 0; j < 4; j++) {
            float o = (lane < 32) ? (y[j] * cv[j] - yo[j] * sv[j])
                                  : (yo[j] * sv[j] + y[j] * cv[j]);
            pk |= (uint64_t)f2bf(o * scl) << (16 * j);
          }
          *(uint64_t*)&((u16*)Cout)[(size_t)grow * N + bn * 256 + lane * 4] = pk;
        }
        __syncthreads();
      }
    } else {
      // V heads: transpose 2 m-chunks per round; each lane owns one d half-row
      // -> 4x16B contiguous stores (lane pairs form 128B runs).
      const int kvh = bn - 12;
      const int dcol = wave * 32 + (lane >> 1);  // 0..255
      const int shalf = (lane & 1) * 32;
#pragma unroll
      for (int mp = 0; mp < 4; mp++) {
#pragma unroll
        for (int mh = 0; mh < 2; mh++) {
          int m = mp * 2 + mh;
#pragma unroll
          for (int n = 0; n < 4; n++)
#pragma unroll
            for (int r = 0; r < 4; r++)
              slab[(mh * 32 + wr * 16 + l4 * 4 + r) * 264 + n * 64 + wc * 16 + l15] =
                  acc[m][n][r];
        }
        __syncthreads();
        u16* dst = vtb + (size_t)(kvh * 256 + dcol) * S_LEN + bm * 256 + mp * 64 + shalf;
#pragma unroll
        for (int g = 0; g < 4; g++) {
          u16 tmp[8];
#pragma unroll
          for (int jj = 0; jj < 8; jj++)
            tmp[jj] = f2bf(slab[(shalf + g * 8 + jj) * 264 + dcol]);
          *(bf16x8*)(dst + g * 8) = *(const bf16x8*)tmp;
        }
        __syncthreads();
      }
    }
  } else {
#pragma unroll
    for (int m = 0; m < 8; m++)
#pragma unroll
      for (int n = 0; n < 4; n++)
#pragma unroll
        for (int r = 0; r < 4; r++) {
          size_t row = bm * 256 + m * 32 + wr * 16 + l4 * 4 + r;
          size_t col = bn * 256 + n * 64 + wc * 16 + l15;
          ((float*)Cout)[row * N + col] = acc[m][n][r];
        }
  }
#undef SA_
#undef SB_
#undef STG_A
#undef STG_B
#undef LDA
#undef LDB
#undef P1_LOADS
#undef P2_LOADS
#undef P3_LOADS
#undef MFMA16
}

// ---------------- bf16 GEMM 256x192 (out-proj): 4-phase, uniform lag-4 staging ----------
// 2D XCD rect: 4bm x 6bn per XCD.
__global__ __launch_bounds__(512, 2) void k_gemm192(const u16* __restrict__ A,
                                                    const u16* __restrict__ Bt,
                                                    float* __restrict__ Cout,
                                                    int M, int N, int K) {
  __shared__ u16 sA[2][256 * 64];
  __shared__ u16 sB[2][192 * 64];
  const int t = threadIdx.x, lane = t & 63, wave = t >> 6;
  const int wr = wave >> 2, wc = wave & 3;
  const int l15 = lane & 15, l4 = lane >> 4;
  const int xcd = (int)blockIdx.x & 7, loc = (int)blockIdx.x >> 3;  // loc 0..23
  const int bm = (xcd >> 1) * 4 + loc / 6;
  const int bn = (xcd & 1) * 6 + loc % 6;
  const int NT = K >> 6;
  const int srow = lane >> 3;
  const int sslot = ((lane & 7) ^ srow) * 8;
  const u16* Abase = A + (size_t)(bm * 256) * K;
  const u16* Bbase = Bt + (size_t)(bn * 192) * K;
  f32x4 acc[8][3] = {};
  bf16x8 aF[4][2], b01[2][2], b2[2];

#define GA_STG_A(BUF, HALF, KT) do {                                              \
    _Pragma("unroll")                                                             \
    for (int c_ = 0; c_ < 2; c_++) {                                              \
      int rb_ = (HALF) * 128 + (wave * 2 + c_) * 8;                               \
      gld16(Abase + (size_t)(rb_ + srow) * K + ((KT) << 6) + sslot,               \
            &sA[BUF][rb_ * 64]);                                                  \
    }                                                                             \
  } while (0)
#define GA_STG_BC(BUF, CH, KT) do {                                               \
    int rb_ = (CH) * 64 + wave * 8;                                               \
    gld16(Bbase + (size_t)(rb_ + srow) * K + ((KT) << 6) + sslot,                 \
          &sB[BUF][rb_ * 64]);                                                    \
  } while (0)
#define GA_LDA(BUF, M_, KK)                                                       \
  (*(const bf16x8*)&sA[BUF][((M_) * 32 + wr * 16 + l15) * 64 +                    \
                            ((((KK) << 2) + l4) ^ (l15 & 7)) * 8])
#define GA_LDB(BUF, N_, KK)                                                       \
  (*(const bf16x8*)&sB[BUF][((N_) * 64 + wc * 16 + l15) * 64 +                    \
                            ((((KK) << 2) + l4) ^ (l15 & 7)) * 8])
#define GA_P1_LOADS(b_) do {                                                      \
    _Pragma("unroll") for (int m_ = 0; m_ < 4; m_++)                              \
      _Pragma("unroll") for (int k_ = 0; k_ < 2; k_++)                            \
        aF[m_][k_] = GA_LDA(b_, m_, k_);                                          \
    _Pragma("unroll") for (int n_ = 0; n_ < 2; n_++)                              \
      _Pragma("unroll") for (int k_ = 0; k_ < 2; k_++)                            \
        b01[n_][k_] = GA_LDB(b_, n_, k_);                                         \
  } while (0)
#define GA_P2_LOADS(b_) do {                                                      \
    _Pragma("unroll") for (int k_ = 0; k_ < 2; k_++)                              \
      b2[k_] = GA_LDB(b_, 2, k_);                                                 \
  } while (0)
#define GA_P3_LOADS(b_) do {                                                      \
    _Pragma("unroll") for (int m_ = 0; m_ < 4; m_++)                              \
      _Pragma("unroll") for (int k_ = 0; k_ < 2; k_++)                            \
        aF[m_][k_] = GA_LDA(b_, m_ + 4, k_);                                      \
  } while (0)
#define GA_MFMA_N01(MOFF) do {                                                    \
    _Pragma("unroll") for (int m_ = 0; m_ < 4; m_++)                              \
      _Pragma("unroll") for (int n_ = 0; n_ < 2; n_++)                            \
        _Pragma("unroll") for (int k_ = 0; k_ < 2; k_++)                          \
          acc[m_ + MOFF][n_] = __builtin_amdgcn_mfma_f32_16x16x32_bf16(           \
              aF[m_][k_], b01[n_][k_], acc[m_ + MOFF][n_], 0, 0, 0);              \
  } while (0)
#define GA_MFMA_N2(MOFF) do {                                                     \
    _Pragma("unroll") for (int m_ = 0; m_ < 4; m_++)                              \
      _Pragma("unroll") for (int k_ = 0; k_ < 2; k_++)                            \
        acc[m_ + MOFF][2] = __builtin_amdgcn_mfma_f32_16x16x32_bf16(              \
            aF[m_][k_], b2[k_], acc[m_ + MOFF][2], 0, 0, 0);                      \
  } while (0)

  GA_STG_A(0, 0, 0);
  GA_STG_BC(0, 0, 0);
  GA_STG_BC(0, 1, 0);
  GA_STG_BC(0, 2, 0);
  GA_STG_A(0, 1, 0);
  VM3();
  BAR();

  for (int tt = 0; tt < NT - 1; ++tt) {
    const int b = tt & 1, nb = b ^ 1;
    GA_P1_LOADS(b);
    GA_STG_A(nb, 0, tt + 1);
    GA_STG_BC(nb, 0, tt + 1);
    GA_STG_BC(nb, 1, tt + 1);
    BAR(); LG0(); PRIO1(); GA_MFMA_N01(0); PRIO0();
    VM6();
    BAR();
    GA_P2_LOADS(b);
    GA_STG_BC(nb, 2, tt + 1);
    BAR(); LG0(); PRIO1(); GA_MFMA_N2(0); PRIO0();
    VM5();
    BAR();
    GA_P3_LOADS(b);
    GA_STG_A(nb, 1, tt + 1);
    BAR(); LG0(); PRIO1(); GA_MFMA_N01(4); PRIO0();
    BAR();
    PRIO1(); GA_MFMA_N2(4); PRIO0();
    VM3();
    BAR();
  }
  {
    const int b = (NT - 1) & 1;
    GA_P1_LOADS(b);
    BAR(); LG0(); PRIO1(); GA_MFMA_N01(0); PRIO0();
    VM2();
    BAR();
    GA_P2_LOADS(b);
    BAR(); LG0(); PRIO1(); GA_MFMA_N2(0); PRIO0();
    VM0();
    BAR();
    GA_P3_LOADS(b);
    BAR(); LG0(); PRIO1(); GA_MFMA_N01(4); PRIO0();
    BAR();
    PRIO1(); GA_MFMA_N2(4); PRIO0();
  }

#pragma unroll
  for (int m = 0; m < 8; m++)
#pragma unroll
    for (int n = 0; n < 3; n++)
#pragma unroll
      for (int r = 0; r < 4; r++) {
        size_t row = bm * 256 + m * 32 + wr * 16 + l4 * 4 + r;
        size_t col = bn * 192 + n * 64 + wc * 16 + l15;
        Cout[row * N + col] = acc[m][n][r];
      }
#undef GA_STG_A
#undef GA_STG_BC
#undef GA_LDA
#undef GA_LDB
#undef GA_P1_LOADS
#undef GA_P2_LOADS
#undef GA_P3_LOADS
#undef GA_MFMA_N01
#undef GA_MFMA_N2
}

// ---------------- flash attention v7: 64 q/block, GQA-shared, double-buffered K/V -------
__global__ __launch_bounds__(512, 2) void k_attn(const u16* __restrict__ qkv,
                                                 const u16* __restrict__ vt,
                                                 const int* __restrict__ pos_ids,
                                                 u16* __restrict__ aout) {
  __shared__ u16 lK[2][64 * 256];  // [key][d], rows 512B, swizzled
  __shared__ u16 lV[2][256 * 64];  // [d][key], rows 128B, swizzled
  __shared__ u16 lP[8][16 * 64];   // per-wave P, rows 128B, swizzled
  const int bid = blockIdx.x;      // 256 blocks
  const int wg = (bid & 7) * 32 + (bid >> 3);  // bijective XCD swizzle
  const int kvh = wg >> 6;                     // 0..3
  const int q0 = (wg & 63) * 64;               // 0..4032
  const int t = threadIdx.x, lane = t & 63, wave = t >> 6;
  const int l15 = lane & 15, l4 = lane >> 4;
  const int head = kvh * 2 + (wave >> 2);
  const int qw = q0 + (wave & 3) * 16;

  bf16x8 qfr[8];
  {
    const u16* qptr = qkv + (size_t)(qw + l15) * QKV_N + head * HD + l4 * 8;
#pragma unroll
    for (int kc = 0; kc < 8; kc++) qfr[kc] = *(const bf16x8*)(qptr + kc * 32);
  }
  f32x4 acc[16] = {};
  float mrow[4], lrow[4];
#pragma unroll
  for (int r = 0; r < 4; r++) { mrow[r] = -1e30f; lrow[r] = 0.0f; }
  int qi[4];
#pragma unroll
  for (int r = 0; r < 4; r++) qi[r] = pos_ids[qw + l4 * 4 + r];

  const int krw = lane >> 5, kcl = lane & 31;
  const int vrw = lane >> 3, vcl = lane & 7;
  const u16* kgb = qkv + 2048 + kvh * HD;
  const u16* vgb = vt + (size_t)kvh * HD * S_LEN;

  int start = q0 - (WIN - 1);
  if (start < 0) start = 0;
  start &= ~63;

#define STAGE_KV(B, T0) do {                                                          \
    _Pragma("unroll")                                                                 \
    for (int i_ = 0; i_ < 4; i_++) {                                                  \
      int ch_ = wave * 4 + i_;                                                        \
      int kr_ = ch_ * 2 + krw;                                                        \
      gld16(kgb + (size_t)((T0) + kr_) * QKV_N + ((kcl ^ (kr_ & 7)) * 8),             \
            &lK[B][ch_ * 512]);                                                       \
      int vr_ = ch_ * 8 + vrw;                                                        \
      gld16(vgb + (size_t)vr_ * S_LEN + (T0) + ((vcl ^ (vr_ & 7)) * 8),               \
            &lV[B][ch_ * 512]);                                                       \
    }                                                                                 \
  } while (0)

  STAGE_KV(0, start);
  __syncthreads();
  int buf = 0;
  for (int t0 = start; t0 <= q0 + 63; t0 += 64) {
    if (t0 + 64 <= q0 + 63) STAGE_KV(buf ^ 1, t0 + 64);
    int kp[4];
#pragma unroll
    for (int kb = 0; kb < 4; kb++) kp[kb] = pos_ids[t0 + kb * 16 + l15];
    f32x4 sv[4] = {};
    PRIO1();
#pragma unroll
    for (int kb = 0; kb < 4; kb++) {
      const char* krow = (const char*)&lK[buf][(kb * 16 + l15) * 256];
      const int sw = ((kb * 16 + l15) & 7) << 4;
#pragma unroll
      for (int kc = 0; kc < 8; kc++) {
        bf16x8 kf = *(const bf16x8*)(krow + ((kc * 64 + l4 * 16) ^ sw));
        sv[kb] = __builtin_amdgcn_mfma_f32_16x16x32_bf16(qfr[kc], kf, sv[kb], 0, 0, 0);
      }
    }
    PRIO0();
    float sloc[4][4], mx[4];
    float need = 0.0f;
#pragma unroll
    for (int r = 0; r < 4; r++) {
      int pi = qi[r];
#pragma unroll
      for (int kb = 0; kb < 4; kb++)
        sloc[r][kb] = ((kp[kb] <= pi) && (pi - kp[kb] < WIN)) ? sv[kb][r] : -__builtin_inff();
      float m_ = fmaxf(fmaxf(sloc[r][0], sloc[r][1]), fmaxf(sloc[r][2], sloc[r][3]));
#pragma unroll
      for (int off = 1; off < 16; off <<= 1) m_ = fmaxf(m_, __shfl_xor(m_, off));
      mx[r] = m_;
      need = fmaxf(need, m_ - mrow[r]);
    }
    bool resc = __any(need > 8.0f);
    if (resc) {
#pragma unroll
      for (int r = 0; r < 4; r++) {
        float nm = fmaxf(mrow[r], mx[r]);
        float al = __expf(mrow[r] - nm);
        mrow[r] = nm;
        lrow[r] *= al;
#pragma unroll
        for (int nd = 0; nd < 16; nd++) acc[nd][r] *= al;
      }
    }
#pragma unroll
    for (int r = 0; r < 4; r++) {
      float nm = mrow[r];
      float e0 = __expf(sloc[r][0] - nm), e1 = __expf(sloc[r][1] - nm);
      float e2 = __expf(sloc[r][2] - nm), e3 = __expf(sloc[r][3] - nm);
      float sum = (e0 + e1) + (e2 + e3);
#pragma unroll
      for (int off = 1; off < 16; off <<= 1) sum += __shfl_xor(sum, off);
      lrow[r] += sum;
      int q = l4 * 4 + r;
      char* lpw = (char*)&lP[wave][0] + q * 128;
      int swp = (q & 7) << 4;
      *(u16*)(lpw + ((l15 * 2) ^ swp)) = f2bf(e0);
      *(u16*)(lpw + ((32 + l15 * 2) ^ swp)) = f2bf(e1);
      *(u16*)(lpw + ((64 + l15 * 2) ^ swp)) = f2bf(e2);
      *(u16*)(lpw + ((96 + l15 * 2) ^ swp)) = f2bf(e3);
    }
#pragma unroll
    for (int kc2 = 0; kc2 < 2; kc2++) {
      int q = l15;
      bf16x8 pa = *(const bf16x8*)((const char*)&lP[wave][0] + q * 128 +
                                   ((kc2 * 64 + l4 * 16) ^ ((q & 7) << 4)));
      PRIO1();
#pragma unroll
      for (int nd = 0; nd < 16; nd++) {
        int d = nd * 16 + l15;
        bf16x8 vf = *(const bf16x8*)((const char*)&lV[buf][d * 64] +
                                     ((kc2 * 64 + l4 * 16) ^ ((d & 7) << 4)));
        acc[nd] = __builtin_amdgcn_mfma_f32_16x16x32_bf16(pa, vf, acc[nd], 0, 0, 0);
      }
      PRIO0();
    }
    __syncthreads();
    buf ^= 1;
  }
  float rinv[4];
#pragma unroll
  for (int r = 0; r < 4; r++) rinv[r] = 1.0f / lrow[r];
#pragma unroll
  for (int nd = 0; nd < 16; nd++)
#pragma unroll
    for (int r = 0; r < 4; r++) {
      size_t row = qw + l4 * 4 + r;
      aout[row * AO_N + head * HD + nd * 16 + l15] = f2bf(acc[nd][r] * rinv[r]);
    }
#undef STAGE_KV
}

extern "C" void kernel_launch(void* const* d_in, const int* in_sizes, int n_in,
                              void* d_out, int out_size, void* d_ws, size_t ws_size,
                              hipStream_t stream) {
  const float* x = (const float*)d_in[0];
  const int* pos = (const int*)d_in[1];
  const float* wq = (const float*)d_in[2];
  const float* wk = (const float*)d_in[3];
  const float* wv = (const float*)d_in[4];
  const float* wo = (const float*)d_in[5];
  const float* qnw = (const float*)d_in[6];
  const float* knw = (const float*)d_in[7];

  // scratch layout:
  //   d_out [0,33.5MB): qkv bf16 [4096][4096] (V cols unwritten; K/Q written by gemm<1>)
  //   d_out [33.5MB,35.6MB): ctab f32[4096][128]; [35.6MB,37.7MB): stab
  //   ws+0        : x bf16 [4096][2304]; later aout bf16 [4096][2048]
  //   ws+18874368 : W^T bf16 (qkv-phase: [4096][2304]; out-phase: wo^T [2304][2048])
  //   ws+28311552 : vt bf16 [4][256][4096] (written by gemm<1> V-epilogue)
  u16* qkv = (u16*)d_out;
  float* ctab = (float*)((char*)d_out + 33554432);
  float* stab = (float*)((char*)d_out + 35651584);
  u16* xbf = (u16*)d_ws;
  u16* wT = (u16*)((char*)d_ws + 18874368);
  u16* vtb = (u16*)((char*)d_ws + 28311552);
  u16* aout = xbf;

  k_cvt_bf16<<<9216, 256, 0, stream>>>(x, xbf, S_LEN * HID_DIM);
  k_sincos<<<2048, 256, 0, stream>>>(pos, ctab, stab);
  k_transpose_w<<<dim3(128, 72), 256, 0, stream>>>(wq, wk, wv, wT);
  k_gemm8p<1><<<dim3(256), 512, 0, stream>>>(xbf, wT, qkv, S_LEN, QKV_N, HID_DIM,
                                             ctab, stab, qnw, knw, vtb);
  k_transpose_cvt<<<dim3(72, 64), 256, 0, stream>>>(wo, HID_DIM, wT, 2048, 0);
  k_attn<<<dim3(256), 512, 0, stream>>>(qkv, vtb, pos, aout);
  k_gemm192<<<dim3(192), 512, 0, stream>>>(aout, wT, (float*)d_out, S_LEN, HID_DIM, 2048);
}